// Round 1
// baseline (712.173 us; speedup 1.0000x reference)
//
#include <hip/hip_runtime.h>
#include <hip/hip_bf16.h>
#include <math.h>

// Problem constants
#define Lseq 2048
#define Dmod 1024
#define DI 2048
#define Nst 16
#define DRr 64
#define Kc 4
#define NCHUNK 16
#define LCHUNK 128   // Lseq / NCHUNK

__device__ __forceinline__ float sigmoidf_(float x) { return 1.f / (1.f + expf(-x)); }
__device__ __forceinline__ float softplusf_(float x) {
    return fmaxf(x, 0.f) + log1pf(expf(-fabsf(x)));
}

// ---------------- RMSNorm: one block per row ----------------
__global__ __launch_bounds__(256) void rmsnorm_k(const float* __restrict__ x,
                                                 const float* __restrict__ w,
                                                 float* __restrict__ xn) {
    int row = blockIdx.x;              // 0..2047
    int tid = threadIdx.x;             // 256 threads, each 4 floats
    const float4* xr = reinterpret_cast<const float4*>(x + (size_t)row * Dmod);
    float4 v = xr[tid];
    float ss = v.x * v.x + v.y * v.y + v.z * v.z + v.w * v.w;
    #pragma unroll
    for (int m = 32; m >= 1; m >>= 1) ss += __shfl_xor(ss, m);
    __shared__ float s4[4];
    if ((tid & 63) == 0) s4[tid >> 6] = ss;
    __syncthreads();
    float tot = s4[0] + s4[1] + s4[2] + s4[3];
    float scale = rsqrtf(tot * (1.0f / Dmod) + 1e-5f);
    const float4* wr = reinterpret_cast<const float4*>(w);
    float4 wv = wr[tid];
    float4 o;
    o.x = v.x * scale * wv.x; o.y = v.y * scale * wv.y;
    o.z = v.z * scale * wv.z; o.w = v.w * scale * wv.w;
    reinterpret_cast<float4*>(xn + (size_t)row * Dmod)[tid] = o;
}

// ---------------- Generic f32 tiled GEMM: C[M,N] = A[M,K]@B[K,N] (+epilogue) ----
// EPI: 0 = plain, 1 = +aux (residual, same layout as C), 2 = softplus(acc + aux[col])
template <int EPI>
__global__ __launch_bounds__(256) void gemm_f32(const float* __restrict__ A, int lda,
                                                const float* __restrict__ B, int ldb,
                                                float* __restrict__ C, int ldc,
                                                int M, int N, int K,
                                                const float* __restrict__ aux) {
    constexpr int BM = 64, BN = 64, BK = 16;
    __shared__ float As[BK][BM + 4];   // stride 68 floats = 272B (16B aligned)
    __shared__ float Bs[BK][BN + 4];
    int bm0 = blockIdx.y * BM, bn0 = blockIdx.x * BN;
    int tid = threadIdx.x;
    int tx = tid & 15, ty = tid >> 4;
    int arow = tid >> 2;            // 0..63
    int ak0 = (tid & 3) * 4;        // 0,4,8,12
    int bkr = tid >> 4;             // 0..15
    int bc0 = (tid & 15) * 4;       // 0..60
    float acc[4][4];
    #pragma unroll
    for (int i = 0; i < 4; i++)
        #pragma unroll
        for (int j = 0; j < 4; j++) acc[i][j] = 0.f;

    for (int k0 = 0; k0 < K; k0 += BK) {
        // A tile (BM x BK), transposed into As[k][m]
        {
            int gr = bm0 + arow, gk = k0 + ak0;
            float4 v = make_float4(0.f, 0.f, 0.f, 0.f);
            if (gr < M) v = *reinterpret_cast<const float4*>(&A[(size_t)gr * lda + gk]);
            As[ak0 + 0][arow] = v.x; As[ak0 + 1][arow] = v.y;
            As[ak0 + 2][arow] = v.z; As[ak0 + 3][arow] = v.w;
        }
        // B tile (BK x BN)
        {
            int gk = k0 + bkr, gc = bn0 + bc0;
            float4 v = make_float4(0.f, 0.f, 0.f, 0.f);
            if (gc + 3 < N) {
                v = *reinterpret_cast<const float4*>(&B[(size_t)gk * ldb + gc]);
            } else {
                float t0 = (gc + 0 < N) ? B[(size_t)gk * ldb + gc + 0] : 0.f;
                float t1 = (gc + 1 < N) ? B[(size_t)gk * ldb + gc + 1] : 0.f;
                float t2 = (gc + 2 < N) ? B[(size_t)gk * ldb + gc + 2] : 0.f;
                float t3 = (gc + 3 < N) ? B[(size_t)gk * ldb + gc + 3] : 0.f;
                v = make_float4(t0, t1, t2, t3);
            }
            *reinterpret_cast<float4*>(&Bs[bkr][bc0]) = v;
        }
        __syncthreads();
        #pragma unroll
        for (int kk = 0; kk < BK; ++kk) {
            float4 a = *reinterpret_cast<const float4*>(&As[kk][ty * 4]);
            float4 b = *reinterpret_cast<const float4*>(&Bs[kk][tx * 4]);
            float ar[4] = {a.x, a.y, a.z, a.w};
            float br[4] = {b.x, b.y, b.z, b.w};
            #pragma unroll
            for (int i = 0; i < 4; i++)
                #pragma unroll
                for (int j = 0; j < 4; j++) acc[i][j] = fmaf(ar[i], br[j], acc[i][j]);
        }
        __syncthreads();
    }
    #pragma unroll
    for (int i = 0; i < 4; i++) {
        int row = bm0 + ty * 4 + i;
        if (row >= M) continue;
        #pragma unroll
        for (int j = 0; j < 4; j++) {
            int col = bn0 + tx * 4 + j;
            if (col >= N) continue;
            float v = acc[i][j];
            if (EPI == 1) v += aux[(size_t)row * ldc + col];
            if (EPI == 2) v = softplusf_(v + aux[col]);
            C[(size_t)row * ldc + col] = v;
        }
    }
}

// ---------------- Conv1d(K=4, causal, per-channel) + SiLU; also gate = silu(res) ----
__global__ __launch_bounds__(256) void conv_silu_k(const float* __restrict__ proj,
                                                   const float* __restrict__ cw,
                                                   const float* __restrict__ cb,
                                                   float* __restrict__ xc,
                                                   float* __restrict__ gate) {
    int d = blockIdx.x * 256 + threadIdx.x;   // 0..2047
    int l = blockIdx.y;                       // 0..2047
    float4 w = reinterpret_cast<const float4*>(cw)[d];
    float wk[4] = {w.x, w.y, w.z, w.w};
    float s = cb[d];
    #pragma unroll
    for (int k = 0; k < 4; k++) {
        int ls = l - 3 + k;
        if (ls >= 0) s = fmaf(proj[(size_t)ls * (2 * DI) + d], wk[k], s);
    }
    float xcv = s * sigmoidf_(s);
    xc[(size_t)l * DI + d] = xcv;
    float r = proj[(size_t)l * (2 * DI) + DI + d];
    gate[(size_t)l * DI + d] = r * sigmoidf_(r);
}

// ---------------- Scan pass 1: per-chunk local scan from h=0; P = prod(a) ----
__global__ __launch_bounds__(256) void scan1_k(const float* __restrict__ delta,
                                               const float* __restrict__ xc,
                                               const float* __restrict__ bcd,
                                               const float* __restrict__ lmA,
                                               float* __restrict__ Pb,
                                               float* __restrict__ Sb) {
    int n = threadIdx.x & 15;
    int dl = threadIdx.x >> 4;
    int d = blockIdx.x * 16 + dl;
    int c = blockIdx.y;
    float negA = -expf(lmA[(size_t)d * Nst + n]);   // A[d,n] (negative)
    float h = 0.f, P = 1.f;
    int l0 = c * LCHUNK;
    for (int l = l0; l < l0 + LCHUNK; ++l) {
        float dv = delta[(size_t)l * DI + d];
        float a = expf(dv * negA);
        float bx = dv * bcd[(size_t)l * 96 + DRr + n] * xc[(size_t)l * DI + d];
        h = fmaf(a, h, bx);
        P *= a;
    }
    size_t idx = ((size_t)c * DI + d) * Nst + n;
    Pb[idx] = P;
    Sb[idx] = h;
}

// ---------------- Scan pass 2: sequential combine over 16 chunks ----
__global__ __launch_bounds__(256) void scan2_k(const float* __restrict__ Pb,
                                               const float* __restrict__ Sb,
                                               float* __restrict__ Hinit) {
    int t = blockIdx.x * 256 + threadIdx.x;   // 0..32767
    int d = t >> 4, n = t & 15;
    float H = 0.f;
    for (int c = 0; c < NCHUNK; c++) {
        size_t idx = ((size_t)c * DI + d) * Nst + n;
        Hinit[idx] = H;
        H = Sb[idx] + Pb[idx] * H;
    }
}

// ---------------- Scan pass 3: rescan with true init, emit gated y ----
__global__ __launch_bounds__(256) void scan3_k(const float* __restrict__ delta,
                                               const float* __restrict__ xc,
                                               const float* __restrict__ bcd,
                                               const float* __restrict__ lmA,
                                               const float* __restrict__ Dp,
                                               const float* __restrict__ gate,
                                               const float* __restrict__ Hinit,
                                               float* __restrict__ y) {
    int n = threadIdx.x & 15;
    int dl = threadIdx.x >> 4;
    int d = blockIdx.x * 16 + dl;
    int c = blockIdx.y;
    float negA = -expf(lmA[(size_t)d * Nst + n]);
    float Dpv = Dp[d];
    float h = Hinit[((size_t)c * DI + d) * Nst + n];
    int l0 = c * LCHUNK;
    for (int l = l0; l < l0 + LCHUNK; ++l) {
        float dv = delta[(size_t)l * DI + d];
        float xcv = xc[(size_t)l * DI + d];
        float a = expf(dv * negA);
        float bx = dv * bcd[(size_t)l * 96 + DRr + n] * xcv;
        h = fmaf(a, h, bx);
        float v = bcd[(size_t)l * 96 + DRr + Nst + n] * h;   // Cm[l,n]*h
        v += __shfl_xor(v, 1);
        v += __shfl_xor(v, 2);
        v += __shfl_xor(v, 4);
        v += __shfl_xor(v, 8);
        if (n == 0) {
            y[(size_t)l * DI + d] = (v + xcv * Dpv) * gate[(size_t)l * DI + d];
        }
    }
}

extern "C" void kernel_launch(void* const* d_in, const int* in_sizes, int n_in,
                              void* d_out, int out_size, void* d_ws, size_t ws_size,
                              hipStream_t stream) {
    const float* x          = (const float*)d_in[0];
    const float* rms_w      = (const float*)d_in[1];
    const float* in_proj_w  = (const float*)d_in[2];   // (1024, 4096)
    const float* conv_w     = (const float*)d_in[3];   // (2048, 4)
    const float* conv_b     = (const float*)d_in[4];   // (2048,)
    const float* bcd_w      = (const float*)d_in[5];   // (2048, 96)
    const float* dup_w      = (const float*)d_in[6];   // (64, 2048)
    const float* dup_b      = (const float*)d_in[7];   // (2048,)
    const float* lmA        = (const float*)d_in[8];   // (2048, 16)
    const float* Dp         = (const float*)d_in[9];   // (2048,)
    const float* out_proj_w = (const float*)d_in[10];  // (2048, 1024)
    float* out = (float*)d_out;
    float* ws  = (float*)d_ws;

    // ws layout (floats); delta & y alias the dead proj region after conv.
    const size_t SZ_XN   = (size_t)Lseq * Dmod;        // 2M
    const size_t SZ_PROJ = (size_t)Lseq * 2 * DI;      // 8M
    const size_t SZ_XC   = (size_t)Lseq * DI;          // 4M
    float* xn    = ws;
    float* proj  = xn + SZ_XN;
    float* xc    = proj + SZ_PROJ;
    float* gate  = xc + SZ_XC;
    float* bcd   = gate + SZ_XC;                       // 2048*96
    float* Pb    = bcd + (size_t)Lseq * 96;
    float* Sb    = Pb + (size_t)NCHUNK * DI * Nst;
    float* Hinit = Sb + (size_t)NCHUNK * DI * Nst;
    float* delta = proj;                               // alias: 4M
    float* y     = proj + SZ_XC;                       // alias: 4M

    // 1. RMSNorm
    rmsnorm_k<<<Lseq, 256, 0, stream>>>(x, rms_w, xn);
    // 2. proj = xn @ in_proj_w
    gemm_f32<0><<<dim3(2 * DI / 64, Lseq / 64), 256, 0, stream>>>(
        xn, Dmod, in_proj_w, 2 * DI, proj, 2 * DI, Lseq, 2 * DI, Dmod, nullptr);
    // 3. xc = silu(conv1d(xs)), gate = silu(res)
    conv_silu_k<<<dim3(DI / 256, Lseq), 256, 0, stream>>>(proj, conv_w, conv_b, xc, gate);
    // 4. bcd = xc @ bcd_w
    gemm_f32<0><<<dim3((96 + 63) / 64, Lseq / 64), 256, 0, stream>>>(
        xc, DI, bcd_w, 96, bcd, 96, Lseq, 96, DI, nullptr);
    // 5. delta = softplus(bcd[:, :64] @ dup_w + dup_b)
    gemm_f32<2><<<dim3(DI / 64, Lseq / 64), 256, 0, stream>>>(
        bcd, 96, dup_w, DI, delta, DI, Lseq, DI, DRr, dup_b);
    // 6-8. chunked selective scan
    scan1_k<<<dim3(DI / 16, NCHUNK), 256, 0, stream>>>(delta, xc, bcd, lmA, Pb, Sb);
    scan2_k<<<dim3(DI * Nst / 256), 256, 0, stream>>>(Pb, Sb, Hinit);
    scan3_k<<<dim3(DI / 16, NCHUNK), 256, 0, stream>>>(delta, xc, bcd, lmA, Dp, gate, Hinit, y);
    // 9. out = y @ out_proj_w + x
    gemm_f32<1><<<dim3(Dmod / 64, Lseq / 64), 256, 0, stream>>>(
        y, DI, out_proj_w, Dmod, out, Dmod, Lseq, Dmod, DI, x);
}

// Round 2
// 488.748 us; speedup vs baseline: 1.4571x; 1.4571x over previous
//
#include <hip/hip_runtime.h>
#include <hip/hip_bf16.h>
#include <math.h>

#define Lseq 2048
#define Dmod 1024
#define DI   2048
#define Nst  16
#define DRr  64
#define NCHUNK 16
#define LCHUNK 128

typedef unsigned short u16;
typedef float  f32x4  __attribute__((ext_vector_type(4)));
typedef short  short8 __attribute__((ext_vector_type(8)));

__device__ __forceinline__ float sigmoidf_(float x) { return 1.f / (1.f + expf(-x)); }
__device__ __forceinline__ float softplusf_(float x) {
    return fmaxf(x, 0.f) + log1pf(expf(-fabsf(x)));
}
__device__ __forceinline__ u16 f2bf(float x) {
    union { float f; unsigned u; } v; v.f = x;
    unsigned r = (v.u + 0x7fffu + ((v.u >> 16) & 1u)) >> 16;
    return (u16)r;
}
__device__ __forceinline__ float bf2f(u16 h) {
    union { unsigned u; float f; } v; v.u = ((unsigned)h) << 16; return v.f;
}
// async global->LDS, 16B per lane; LDS dest = wave-uniform base + lane*16
__device__ __forceinline__ void async16(const void* g, void* l) {
    __builtin_amdgcn_global_load_lds((__attribute__((address_space(1))) void*)g,
                                     (__attribute__((address_space(3))) void*)l, 16, 0, 0);
}

struct __align__(8) u16x4 { u16 x, y, z, w; };

// ---------------- RMSNorm -> split bf16 hi/lo ----------------
__global__ __launch_bounds__(256) void rmsnorm_split_k(const float* __restrict__ x,
                                                       const float* __restrict__ w,
                                                       u16* __restrict__ xh,
                                                       u16* __restrict__ xl) {
    int row = blockIdx.x;
    int tid = threadIdx.x;
    float4 v = reinterpret_cast<const float4*>(x + (size_t)row * Dmod)[tid];
    float ss = v.x * v.x + v.y * v.y + v.z * v.z + v.w * v.w;
    #pragma unroll
    for (int m = 32; m >= 1; m >>= 1) ss += __shfl_xor(ss, m);
    __shared__ float s4[4];
    if ((tid & 63) == 0) s4[tid >> 6] = ss;
    __syncthreads();
    float tot = s4[0] + s4[1] + s4[2] + s4[3];
    float scale = rsqrtf(tot * (1.0f / Dmod) + 1e-5f);
    float4 wv = reinterpret_cast<const float4*>(w)[tid];
    float o[4] = {v.x * scale * wv.x, v.y * scale * wv.y,
                  v.z * scale * wv.z, v.w * scale * wv.w};
    u16x4 H, L;
    u16* hp = &H.x; u16* lp = &L.x;
    #pragma unroll
    for (int q = 0; q < 4; q++) {
        u16 h = f2bf(o[q]); hp[q] = h; lp[q] = f2bf(o[q] - bf2f(h));
    }
    reinterpret_cast<u16x4*>(xh + (size_t)row * Dmod)[tid] = H;
    reinterpret_cast<u16x4*>(xl + (size_t)row * Dmod)[tid] = L;
}

// ---------------- Weight transpose + split: W[R][Cn] -> Th/Tl [Cn][R] ----------------
__global__ __launch_bounds__(256) void wsplitT_k(const float* __restrict__ W, int R, int Cn,
                                                 u16* __restrict__ Th, u16* __restrict__ Tl) {
    __shared__ float t[32][33];
    int r0 = blockIdx.y * 32, c0 = blockIdx.x * 32;
    int tr = threadIdx.x >> 3;            // 0..31
    int tc4 = (threadIdx.x & 7) * 4;      // 0,4,...,28
    float4 v = *reinterpret_cast<const float4*>(&W[(size_t)(r0 + tr) * Cn + c0 + tc4]);
    t[tr][tc4 + 0] = v.x; t[tr][tc4 + 1] = v.y;
    t[tr][tc4 + 2] = v.z; t[tr][tc4 + 3] = v.w;
    __syncthreads();
    u16x4 H, L;
    u16* hp = &H.x; u16* lp = &L.x;
    #pragma unroll
    for (int q = 0; q < 4; q++) {
        float xv = t[tc4 + q][tr];        // = W[r0+tc4+q][c0+tr]
        u16 h = f2bf(xv); hp[q] = h; lp[q] = f2bf(xv - bf2f(h));
    }
    size_t o = (size_t)(c0 + tr) * R + r0 + tc4;
    *reinterpret_cast<u16x4*>(&Th[o]) = H;
    *reinterpret_cast<u16x4*>(&Tl[o]) = L;
}

// ---------------- Split-bf16 MFMA GEMM: C[M][N] = A[M][K] @ Bt[N][K]^T ----------------
// EPI: 0 plain, 1 C=acc+aux (residual, aux layout [M][N]), 4 dual in_proj epilogue:
//      cols < DI -> C (xs), cols >= DI -> C2 = silu(acc) (gate)
template <int BM, int BN, int EPI>
__global__ __launch_bounds__(256) void gemm_mfma3(
    const u16* __restrict__ Ah, const u16* __restrict__ Al,
    const u16* __restrict__ Bh, const u16* __restrict__ Bl,
    float* __restrict__ C, float* __restrict__ C2, const float* __restrict__ aux,
    int M, int N, int K) {
    constexpr int BK = 32;
    constexpr int MF = BM / 32, NF = BN / 32;     // frags per wave (2x2 wave grid)
    constexpr int CH_A = BM / 16, CH_B = BN / 16; // 1KB chunks per tile
    __shared__ u16 AhT[BM][BK], AlT[BM][BK], BhT[BN][BK], BlT[BN][BK];
    const int tid = threadIdx.x, lane = tid & 63, wid = tid >> 6;
    const int wr = wid >> 1, wc = wid & 1;
    const int lr = lane & 15, lk = (lane >> 4) * 8;
    const int bm0 = blockIdx.y * BM, bn0 = blockIdx.x * BN;
    const int srow = lane >> 2, scol = (lane & 3) * 8;

    f32x4 acc[MF][NF];
    #pragma unroll
    for (int i = 0; i < MF; i++)
        #pragma unroll
        for (int j = 0; j < NF; j++) acc[i][j] = (f32x4){0.f, 0.f, 0.f, 0.f};

    for (int k0 = 0; k0 < K; k0 += BK) {
        int ci = 0;
        #pragma unroll
        for (int c = 0; c < CH_A; c++, ci++) if ((ci & 3) == wid) {
            size_t g = (size_t)(bm0 + c * 16 + srow) * K + (k0 + scol);
            async16(Ah + g, (u16*)&AhT[0][0] + c * 512 + lane * 8);
        }
        #pragma unroll
        for (int c = 0; c < CH_A; c++, ci++) if ((ci & 3) == wid) {
            size_t g = (size_t)(bm0 + c * 16 + srow) * K + (k0 + scol);
            async16(Al + g, (u16*)&AlT[0][0] + c * 512 + lane * 8);
        }
        #pragma unroll
        for (int c = 0; c < CH_B; c++, ci++) if ((ci & 3) == wid) {
            size_t g = (size_t)(bn0 + c * 16 + srow) * K + (k0 + scol);
            async16(Bh + g, (u16*)&BhT[0][0] + c * 512 + lane * 8);
        }
        #pragma unroll
        for (int c = 0; c < CH_B; c++, ci++) if ((ci & 3) == wid) {
            size_t g = (size_t)(bn0 + c * 16 + srow) * K + (k0 + scol);
            async16(Bl + g, (u16*)&BlT[0][0] + c * 512 + lane * 8);
        }
        __syncthreads();

        short8 ah[MF], al[MF], bh[NF], bl[NF];
        #pragma unroll
        for (int i = 0; i < MF; i++) {
            int r = wr * (MF * 16) + i * 16 + lr;
            ah[i] = *(const short8*)&AhT[r][lk];
            al[i] = *(const short8*)&AlT[r][lk];
        }
        #pragma unroll
        for (int j = 0; j < NF; j++) {
            int r = wc * (NF * 16) + j * 16 + lr;
            bh[j] = *(const short8*)&BhT[r][lk];
            bl[j] = *(const short8*)&BlT[r][lk];
        }
        #pragma unroll
        for (int i = 0; i < MF; i++)
            #pragma unroll
            for (int j = 0; j < NF; j++) {
                acc[i][j] = __builtin_amdgcn_mfma_f32_16x16x32_bf16(ah[i], bh[j], acc[i][j], 0, 0, 0);
                acc[i][j] = __builtin_amdgcn_mfma_f32_16x16x32_bf16(ah[i], bl[j], acc[i][j], 0, 0, 0);
                acc[i][j] = __builtin_amdgcn_mfma_f32_16x16x32_bf16(al[i], bh[j], acc[i][j], 0, 0, 0);
            }
        __syncthreads();
    }

    #pragma unroll
    for (int i = 0; i < MF; i++)
        #pragma unroll
        for (int j = 0; j < NF; j++) {
            int rowg = bm0 + wr * (MF * 16) + i * 16 + (lane >> 4) * 4;
            int colg = bn0 + wc * (NF * 16) + j * 16 + lr;
            #pragma unroll
            for (int q = 0; q < 4; q++) {
                float v = acc[i][j][q];
                if (EPI == 0) {
                    C[(size_t)(rowg + q) * N + colg] = v;
                } else if (EPI == 1) {
                    size_t idx = (size_t)(rowg + q) * N + colg;
                    C[idx] = v + aux[idx];
                } else if (EPI == 4) {
                    if (colg < DI) C[(size_t)(rowg + q) * DI + colg] = v;
                    else C2[(size_t)(rowg + q) * DI + (colg - DI)] = v * sigmoidf_(v);
                }
            }
        }
}

// ---------------- f32 tiled GEMM (small GEMMs): EPI 0 plain, 2 softplus(acc+aux[col]) ----
template <int EPI>
__global__ __launch_bounds__(256) void gemm_f32(const float* __restrict__ A, int lda,
                                                const float* __restrict__ B, int ldb,
                                                float* __restrict__ C, int ldc,
                                                int M, int N, int K,
                                                const float* __restrict__ aux) {
    constexpr int BM = 64, BN = 64, BK = 16;
    __shared__ float As[BK][BM + 4];
    __shared__ float Bs[BK][BN + 4];
    int bm0 = blockIdx.y * BM, bn0 = blockIdx.x * BN;
    int tid = threadIdx.x;
    int tx = tid & 15, ty = tid >> 4;
    int arow = tid >> 2;
    int ak0 = (tid & 3) * 4;
    int bkr = tid >> 4;
    int bc0 = (tid & 15) * 4;
    float acc[4][4];
    #pragma unroll
    for (int i = 0; i < 4; i++)
        #pragma unroll
        for (int j = 0; j < 4; j++) acc[i][j] = 0.f;

    for (int k0 = 0; k0 < K; k0 += BK) {
        {
            int gr = bm0 + arow, gk = k0 + ak0;
            float4 v = make_float4(0.f, 0.f, 0.f, 0.f);
            if (gr < M) v = *reinterpret_cast<const float4*>(&A[(size_t)gr * lda + gk]);
            As[ak0 + 0][arow] = v.x; As[ak0 + 1][arow] = v.y;
            As[ak0 + 2][arow] = v.z; As[ak0 + 3][arow] = v.w;
        }
        {
            int gk = k0 + bkr, gc = bn0 + bc0;
            float4 v = make_float4(0.f, 0.f, 0.f, 0.f);
            if (gc + 3 < N) {
                v = *reinterpret_cast<const float4*>(&B[(size_t)gk * ldb + gc]);
            } else {
                float t0 = (gc + 0 < N) ? B[(size_t)gk * ldb + gc + 0] : 0.f;
                float t1 = (gc + 1 < N) ? B[(size_t)gk * ldb + gc + 1] : 0.f;
                float t2 = (gc + 2 < N) ? B[(size_t)gk * ldb + gc + 2] : 0.f;
                float t3 = (gc + 3 < N) ? B[(size_t)gk * ldb + gc + 3] : 0.f;
                v = make_float4(t0, t1, t2, t3);
            }
            *reinterpret_cast<float4*>(&Bs[bkr][bc0]) = v;
        }
        __syncthreads();
        #pragma unroll
        for (int kk = 0; kk < BK; ++kk) {
            float4 a = *reinterpret_cast<const float4*>(&As[kk][ty * 4]);
            float4 b = *reinterpret_cast<const float4*>(&Bs[kk][tx * 4]);
            float ar[4] = {a.x, a.y, a.z, a.w};
            float br[4] = {b.x, b.y, b.z, b.w};
            #pragma unroll
            for (int i = 0; i < 4; i++)
                #pragma unroll
                for (int j = 0; j < 4; j++) acc[i][j] = fmaf(ar[i], br[j], acc[i][j]);
        }
        __syncthreads();
    }
    #pragma unroll
    for (int i = 0; i < 4; i++) {
        int row = bm0 + ty * 4 + i;
        if (row >= M) continue;
        #pragma unroll
        for (int j = 0; j < 4; j++) {
            int col = bn0 + tx * 4 + j;
            if (col >= N) continue;
            float v = acc[i][j];
            if (EPI == 2) v = softplusf_(v + aux[col]);
            C[(size_t)row * ldc + col] = v;
        }
    }
}

// ---------------- Conv1d(K=4) + SiLU ----------------
__global__ __launch_bounds__(256) void conv_silu_k(const float* __restrict__ xs,
                                                   const float* __restrict__ cw,
                                                   const float* __restrict__ cb,
                                                   float* __restrict__ xc) {
    int d = blockIdx.x * 256 + threadIdx.x;
    int l = blockIdx.y;
    float4 w = reinterpret_cast<const float4*>(cw)[d];
    float wk[4] = {w.x, w.y, w.z, w.w};
    float s = cb[d];
    #pragma unroll
    for (int k = 0; k < 4; k++) {
        int ls = l - 3 + k;
        if (ls >= 0) s = fmaf(xs[(size_t)ls * DI + d], wk[k], s);
    }
    xc[(size_t)l * DI + d] = s * sigmoidf_(s);
}

// ---------------- Scan pass 1 ----------------
__global__ __launch_bounds__(256) void scan1_k(const float* __restrict__ delta,
                                               const float* __restrict__ xc,
                                               const float* __restrict__ bcd,
                                               const float* __restrict__ lmA,
                                               float* __restrict__ Pb,
                                               float* __restrict__ Sb) {
    int n = threadIdx.x & 15;
    int dl = threadIdx.x >> 4;
    int d = blockIdx.x * 16 + dl;
    int c = blockIdx.y;
    float negA = -expf(lmA[(size_t)d * Nst + n]);
    float h = 0.f, P = 1.f;
    int l0 = c * LCHUNK;
    for (int l = l0; l < l0 + LCHUNK; ++l) {
        float dv = delta[(size_t)l * DI + d];
        float a = expf(dv * negA);
        float bx = dv * bcd[(size_t)l * 96 + DRr + n] * xc[(size_t)l * DI + d];
        h = fmaf(a, h, bx);
        P *= a;
    }
    size_t idx = ((size_t)c * DI + d) * Nst + n;
    Pb[idx] = P;
    Sb[idx] = h;
}

// ---------------- Scan pass 2: combine; Hinit written in place over Pb ----------------
__global__ __launch_bounds__(256) void scan2_k(float* __restrict__ PH,
                                               const float* __restrict__ Sb) {
    int t = blockIdx.x * 256 + threadIdx.x;
    int d = t >> 4, n = t & 15;
    float H = 0.f;
    for (int c = 0; c < NCHUNK; c++) {
        size_t idx = ((size_t)c * DI + d) * Nst + n;
        float P = PH[idx], S = Sb[idx];
        PH[idx] = H;
        H = S + P * H;
    }
}

// ---------------- Scan pass 3: rescan, gate, emit y as split bf16 ----------------
__global__ __launch_bounds__(256) void scan3_k(const float* __restrict__ delta,
                                               const float* __restrict__ xc,
                                               const float* __restrict__ bcd,
                                               const float* __restrict__ lmA,
                                               const float* __restrict__ Dp,
                                               const float* __restrict__ gate,
                                               const float* __restrict__ Hinit,
                                               u16* __restrict__ yH,
                                               u16* __restrict__ yL) {
    int n = threadIdx.x & 15;
    int dl = threadIdx.x >> 4;
    int d = blockIdx.x * 16 + dl;
    int c = blockIdx.y;
    float negA = -expf(lmA[(size_t)d * Nst + n]);
    float Dpv = Dp[d];
    float h = Hinit[((size_t)c * DI + d) * Nst + n];
    int l0 = c * LCHUNK;
    for (int l = l0; l < l0 + LCHUNK; ++l) {
        float dv = delta[(size_t)l * DI + d];
        float xcv = xc[(size_t)l * DI + d];
        float a = expf(dv * negA);
        float bx = dv * bcd[(size_t)l * 96 + DRr + n] * xcv;
        h = fmaf(a, h, bx);
        float v = bcd[(size_t)l * 96 + DRr + Nst + n] * h;
        v += __shfl_xor(v, 1);
        v += __shfl_xor(v, 2);
        v += __shfl_xor(v, 4);
        v += __shfl_xor(v, 8);
        if (n == 0) {
            float yv = (v + xcv * Dpv) * gate[(size_t)l * DI + d];
            size_t o = (size_t)l * DI + d;
            u16 hq = f2bf(yv);
            yH[o] = hq;
            yL[o] = f2bf(yv - bf2f(hq));
        }
    }
}

extern "C" void kernel_launch(void* const* d_in, const int* in_sizes, int n_in,
                              void* d_out, int out_size, void* d_ws, size_t ws_size,
                              hipStream_t stream) {
    const float* x          = (const float*)d_in[0];
    const float* rms_w      = (const float*)d_in[1];
    const float* in_proj_w  = (const float*)d_in[2];   // (1024, 4096)
    const float* conv_w     = (const float*)d_in[3];
    const float* conv_b     = (const float*)d_in[4];
    const float* bcd_w      = (const float*)d_in[5];   // (2048, 96)
    const float* dup_w      = (const float*)d_in[6];   // (64, 2048)
    const float* dup_b      = (const float*)d_in[7];
    const float* lmA        = (const float*)d_in[8];
    const float* Dp         = (const float*)d_in[9];
    const float* out_proj_w = (const float*)d_in[10];  // (2048, 1024)
    float* out = (float*)d_out;
    char*  W   = (char*)d_ws;

    // Arena (77 MB total), with lifetime-based aliasing:
    u16*   WiH  = (u16*)(W + 0);                 // 8MB  [in_proj^T hi]  (dead after in_proj)
    u16*   WiL  = (u16*)(W + (8ull << 20));      // 8MB
    float* delta= (float*)(W + 0);               // 16MB (alias, written after Wi dead)
    float* xs   = (float*)(W + (16ull << 20));   // 16MB (dead after conv)
    u16*   yH   = (u16*)(W + (16ull << 20));     // 8MB  (alias, written by scan3)
    u16*   yL   = (u16*)(W + (24ull << 20));     // 8MB
    float* gate = (float*)(W + (32ull << 20));   // 16MB
    float* xc   = (float*)(W + (48ull << 20));   // 16MB
    u16*   xnH  = (u16*)(W + (64ull << 20));     // 4MB  (dead after in_proj)
    u16*   xnL  = (u16*)(W + (68ull << 20));     // 4MB
    u16*   WoH  = (u16*)(W + (64ull << 20));     // 4MB  (alias, written after in_proj)
    u16*   WoL  = (u16*)(W + (68ull << 20));     // 4MB
    float* bcd  = (float*)(W + (72ull << 20));   // 768KB
    float* Pb   = (float*)(W + (73ull << 20));   // 2MB  (becomes Hinit in place)
    float* Sb   = (float*)(W + (75ull << 20));   // 2MB

    // 1. RMSNorm -> split bf16
    rmsnorm_split_k<<<Lseq, 256, 0, stream>>>(x, rms_w, xnH, xnL);
    // 2. in_proj_w (1024x4096) -> WiT hi/lo (4096x1024)
    wsplitT_k<<<dim3(4096 / 32, 1024 / 32), 256, 0, stream>>>(in_proj_w, 1024, 4096, WiH, WiL);
    // 3. proj: xs = xn@Wi[:, :DI]; gate = silu(xn@Wi[:, DI:])   (dual epilogue)
    gemm_mfma3<128, 128, 4><<<dim3(4096 / 128, Lseq / 128), 256, 0, stream>>>(
        xnH, xnL, WiH, WiL, xs, gate, nullptr, Lseq, 2 * DI, Dmod);
    // 4. xc = silu(conv1d(xs))
    conv_silu_k<<<dim3(DI / 256, Lseq), 256, 0, stream>>>(xs, conv_w, conv_b, xc);
    // 5. out_proj_w (2048x1024) -> WoT hi/lo (1024x2048)  (after xn is dead)
    wsplitT_k<<<dim3(1024 / 32, 2048 / 32), 256, 0, stream>>>(out_proj_w, 2048, 1024, WoH, WoL);
    // 6. bcd = xc @ bcd_w
    gemm_f32<0><<<dim3(2, Lseq / 64), 256, 0, stream>>>(
        xc, DI, bcd_w, 96, bcd, 96, Lseq, 96, DI, nullptr);
    // 7. delta = softplus(bcd[:, :64] @ dup_w + dup_b)   (aliases Wi region)
    gemm_f32<2><<<dim3(DI / 64, Lseq / 64), 256, 0, stream>>>(
        bcd, 96, dup_w, DI, delta, DI, Lseq, DI, DRr, dup_b);
    // 8-10. chunked selective scan
    scan1_k<<<dim3(DI / 16, NCHUNK), 256, 0, stream>>>(delta, xc, bcd, lmA, Pb, Sb);
    scan2_k<<<dim3(DI * Nst / 256), 256, 0, stream>>>(Pb, Sb);
    scan3_k<<<dim3(DI / 16, NCHUNK), 256, 0, stream>>>(delta, xc, bcd, lmA, Dp, gate, Pb, yH, yL);
    // 11. out = y @ out_proj_w + x
    gemm_mfma3<64, 128, 1><<<dim3(Dmod / 128, Lseq / 64), 256, 0, stream>>>(
        yH, yL, WoH, WoL, out, nullptr, x, Lseq, Dmod, DI);
}

// Round 3
// 372.526 us; speedup vs baseline: 1.9117x; 1.3120x over previous
//
#include <hip/hip_runtime.h>
#include <hip/hip_bf16.h>
#include <math.h>

#define Lseq 2048
#define Dmod 1024
#define DI   2048
#define Nst  16
#define DRr  64
#define NCHUNK 16
#define LCHUNK 128
#define SPLITK 16

typedef unsigned short u16;
typedef float  f32x4  __attribute__((ext_vector_type(4)));
typedef short  short8 __attribute__((ext_vector_type(8)));

__device__ __forceinline__ float sigmoidf_(float x) { return 1.f / (1.f + expf(-x)); }
__device__ __forceinline__ float softplusf_(float x) {
    return fmaxf(x, 0.f) + log1pf(expf(-fabsf(x)));
}
__device__ __forceinline__ u16 f2bf(float x) {
    union { float f; unsigned u; } v; v.f = x;
    unsigned r = (v.u + 0x7fffu + ((v.u >> 16) & 1u)) >> 16;
    return (u16)r;
}
__device__ __forceinline__ float bf2f(u16 h) {
    union { unsigned u; float f; } v; v.u = ((unsigned)h) << 16; return v.f;
}
__device__ __forceinline__ void async16(const void* g, void* l) {
    __builtin_amdgcn_global_load_lds((__attribute__((address_space(1))) void*)g,
                                     (__attribute__((address_space(3))) void*)l, 16, 0, 0);
}

struct __align__(8) u16x4 { u16 x, y, z, w; };

// ---------------- RMSNorm -> split bf16 hi/lo ----------------
__global__ __launch_bounds__(256) void rmsnorm_split_k(const float* __restrict__ x,
                                                       const float* __restrict__ w,
                                                       u16* __restrict__ xh,
                                                       u16* __restrict__ xl) {
    int row = blockIdx.x;
    int tid = threadIdx.x;
    float4 v = reinterpret_cast<const float4*>(x + (size_t)row * Dmod)[tid];
    float ss = v.x * v.x + v.y * v.y + v.z * v.z + v.w * v.w;
    #pragma unroll
    for (int m = 32; m >= 1; m >>= 1) ss += __shfl_xor(ss, m);
    __shared__ float s4[4];
    if ((tid & 63) == 0) s4[tid >> 6] = ss;
    __syncthreads();
    float tot = s4[0] + s4[1] + s4[2] + s4[3];
    float scale = rsqrtf(tot * (1.0f / Dmod) + 1e-5f);
    float4 wv = reinterpret_cast<const float4*>(w)[tid];
    float o[4] = {v.x * scale * wv.x, v.y * scale * wv.y,
                  v.z * scale * wv.z, v.w * scale * wv.w};
    u16x4 H, L;
    u16* hp = &H.x; u16* lp = &L.x;
    #pragma unroll
    for (int q = 0; q < 4; q++) {
        u16 h = f2bf(o[q]); hp[q] = h; lp[q] = f2bf(o[q] - bf2f(h));
    }
    reinterpret_cast<u16x4*>(xh + (size_t)row * Dmod)[tid] = H;
    reinterpret_cast<u16x4*>(xl + (size_t)row * Dmod)[tid] = L;
}

// ---------------- Weight transpose + split: W[R][Cn] -> Th/Tl [Cn][R] ----------------
__global__ __launch_bounds__(256) void wsplitT_k(const float* __restrict__ W, int R, int Cn,
                                                 u16* __restrict__ Th, u16* __restrict__ Tl) {
    __shared__ float t[32][33];
    int r0 = blockIdx.y * 32, c0 = blockIdx.x * 32;
    int tr = threadIdx.x >> 3;
    int tc4 = (threadIdx.x & 7) * 4;
    float4 v = *reinterpret_cast<const float4*>(&W[(size_t)(r0 + tr) * Cn + c0 + tc4]);
    t[tr][tc4 + 0] = v.x; t[tr][tc4 + 1] = v.y;
    t[tr][tc4 + 2] = v.z; t[tr][tc4 + 3] = v.w;
    __syncthreads();
    u16x4 H, L;
    u16* hp = &H.x; u16* lp = &L.x;
    #pragma unroll
    for (int q = 0; q < 4; q++) {
        float xv = t[tc4 + q][tr];
        u16 h = f2bf(xv); hp[q] = h; lp[q] = f2bf(xv - bf2f(h));
    }
    size_t o = (size_t)(c0 + tr) * R + r0 + tc4;
    *reinterpret_cast<u16x4*>(&Th[o]) = H;
    *reinterpret_cast<u16x4*>(&Tl[o]) = L;
}

// ---------------- Split-bf16 MFMA GEMM: C[M][N] = A[M][K] @ Bt[N][K]^T ----------------
// EPI: 0 plain; 1 C=acc+aux (aux layout [M][N]); 2 C=softplus(acc+aux[col]);
//      4 dual in_proj (cols<DI -> C, cols>=DI -> C2=silu); 5 split-K partial write.
template <int BM, int BN, int EPI>
__global__ __launch_bounds__(256) void gemm_mfma3(
    const u16* __restrict__ Ah, const u16* __restrict__ Al,
    const u16* __restrict__ Bh, const u16* __restrict__ Bl,
    float* __restrict__ C, float* __restrict__ C2, const float* __restrict__ aux,
    int M, int N, int K) {
    constexpr int BK = 32;
    constexpr int MF = BM / 32, NF = BN / 32;
    constexpr int CH_A = BM / 16, CH_B = BN / 16;
    __shared__ u16 AhT[BM][BK], AlT[BM][BK], BhT[BN][BK], BlT[BN][BK];
    const int tid = threadIdx.x, lane = tid & 63, wid = tid >> 6;
    const int wr = wid >> 1, wc = wid & 1;
    const int lr = lane & 15, lk = (lane >> 4) * 8;
    const int bm0 = blockIdx.y * BM, bn0 = blockIdx.x * BN;
    const int srow = lane >> 2, scol = (lane & 3) * 8;

    int kbeg = 0, kend = K;
    if (EPI == 5) {
        int ks = K / gridDim.z;
        kbeg = blockIdx.z * ks;
        kend = kbeg + ks;
    }

    f32x4 acc[MF][NF];
    #pragma unroll
    for (int i = 0; i < MF; i++)
        #pragma unroll
        for (int j = 0; j < NF; j++) acc[i][j] = (f32x4){0.f, 0.f, 0.f, 0.f};

    for (int k0 = kbeg; k0 < kend; k0 += BK) {
        int ci = 0;
        #pragma unroll
        for (int c = 0; c < CH_A; c++, ci++) if ((ci & 3) == wid) {
            size_t g = (size_t)(bm0 + c * 16 + srow) * K + (k0 + scol);
            async16(Ah + g, (u16*)&AhT[0][0] + c * 512 + lane * 8);
        }
        #pragma unroll
        for (int c = 0; c < CH_A; c++, ci++) if ((ci & 3) == wid) {
            size_t g = (size_t)(bm0 + c * 16 + srow) * K + (k0 + scol);
            async16(Al + g, (u16*)&AlT[0][0] + c * 512 + lane * 8);
        }
        #pragma unroll
        for (int c = 0; c < CH_B; c++, ci++) if ((ci & 3) == wid) {
            size_t g = (size_t)(bn0 + c * 16 + srow) * K + (k0 + scol);
            async16(Bh + g, (u16*)&BhT[0][0] + c * 512 + lane * 8);
        }
        #pragma unroll
        for (int c = 0; c < CH_B; c++, ci++) if ((ci & 3) == wid) {
            size_t g = (size_t)(bn0 + c * 16 + srow) * K + (k0 + scol);
            async16(Bl + g, (u16*)&BlT[0][0] + c * 512 + lane * 8);
        }
        __syncthreads();

        short8 ah[MF], al[MF], bh[NF], bl[NF];
        #pragma unroll
        for (int i = 0; i < MF; i++) {
            int r = wr * (MF * 16) + i * 16 + lr;
            ah[i] = *(const short8*)&AhT[r][lk];
            al[i] = *(const short8*)&AlT[r][lk];
        }
        #pragma unroll
        for (int j = 0; j < NF; j++) {
            int r = wc * (NF * 16) + j * 16 + lr;
            bh[j] = *(const short8*)&BhT[r][lk];
            bl[j] = *(const short8*)&BlT[r][lk];
        }
        #pragma unroll
        for (int i = 0; i < MF; i++)
            #pragma unroll
            for (int j = 0; j < NF; j++) {
                acc[i][j] = __builtin_amdgcn_mfma_f32_16x16x32_bf16(ah[i], bh[j], acc[i][j], 0, 0, 0);
                acc[i][j] = __builtin_amdgcn_mfma_f32_16x16x32_bf16(ah[i], bl[j], acc[i][j], 0, 0, 0);
                acc[i][j] = __builtin_amdgcn_mfma_f32_16x16x32_bf16(al[i], bh[j], acc[i][j], 0, 0, 0);
            }
        __syncthreads();
    }

    float* Cp = C;
    if (EPI == 5) Cp = C + (size_t)blockIdx.z * M * N;
    #pragma unroll
    for (int i = 0; i < MF; i++)
        #pragma unroll
        for (int j = 0; j < NF; j++) {
            int rowg = bm0 + wr * (MF * 16) + i * 16 + (lane >> 4) * 4;
            int colg = bn0 + wc * (NF * 16) + j * 16 + lr;
            #pragma unroll
            for (int q = 0; q < 4; q++) {
                float v = acc[i][j][q];
                if (EPI == 0 || EPI == 5) {
                    Cp[(size_t)(rowg + q) * N + colg] = v;
                } else if (EPI == 1) {
                    size_t idx = (size_t)(rowg + q) * N + colg;
                    C[idx] = v + aux[idx];
                } else if (EPI == 2) {
                    C[(size_t)(rowg + q) * N + colg] = softplusf_(v + aux[colg]);
                } else if (EPI == 4) {
                    if (colg < DI) C[(size_t)(rowg + q) * DI + colg] = v;
                    else C2[(size_t)(rowg + q) * DI + (colg - DI)] = v * sigmoidf_(v);
                }
            }
        }
}

// ---------------- bcd split-K reduce: sum partials, emit f32 + hi/lo of cols<64 ----
__global__ __launch_bounds__(256) void bcd_reduce_k(const float* __restrict__ partial,
                                                    float* __restrict__ bcd,
                                                    u16* __restrict__ bH,
                                                    u16* __restrict__ bL) {
    const int NT = Lseq * 96;
    int t = blockIdx.x * 256 + threadIdx.x;
    float s = 0.f;
    #pragma unroll
    for (int z = 0; z < SPLITK; z++) s += partial[(size_t)z * NT + t];
    bcd[t] = s;
    int col = t % 96, row = t / 96;
    if (col < DRr) {
        u16 h = f2bf(s);
        bH[(size_t)row * DRr + col] = h;
        bL[(size_t)row * DRr + col] = f2bf(s - bf2f(h));
    }
}

// ---------------- Conv1d(K=4) + SiLU; emits f32 + split bf16 ----------------
__global__ __launch_bounds__(256) void conv_silu_k(const float* __restrict__ xs,
                                                   const float* __restrict__ cw,
                                                   const float* __restrict__ cb,
                                                   float* __restrict__ xc,
                                                   u16* __restrict__ xcH,
                                                   u16* __restrict__ xcL) {
    int d = blockIdx.x * 256 + threadIdx.x;
    int l = blockIdx.y;
    float4 w = reinterpret_cast<const float4*>(cw)[d];
    float wk[4] = {w.x, w.y, w.z, w.w};
    float s = cb[d];
    #pragma unroll
    for (int k = 0; k < 4; k++) {
        int ls = l - 3 + k;
        if (ls >= 0) s = fmaf(xs[(size_t)ls * DI + d], wk[k], s);
    }
    float v = s * sigmoidf_(s);
    size_t o = (size_t)l * DI + d;
    xc[o] = v;
    u16 h = f2bf(v);
    xcH[o] = h;
    xcL[o] = f2bf(v - bf2f(h));
}

// ---------------- Scan pass 1 ----------------
__global__ __launch_bounds__(256) void scan1_k(const float* __restrict__ delta,
                                               const float* __restrict__ xc,
                                               const float* __restrict__ bcd,
                                               const float* __restrict__ lmA,
                                               float* __restrict__ Pb,
                                               float* __restrict__ Sb) {
    int n = threadIdx.x & 15;
    int dl = threadIdx.x >> 4;
    int d = blockIdx.x * 16 + dl;
    int c = blockIdx.y;
    float negA = -expf(lmA[(size_t)d * Nst + n]);
    float h = 0.f, P = 1.f;
    int l0 = c * LCHUNK;
    for (int l = l0; l < l0 + LCHUNK; ++l) {
        float dv = delta[(size_t)l * DI + d];
        float a = expf(dv * negA);
        float bx = dv * bcd[(size_t)l * 96 + DRr + n] * xc[(size_t)l * DI + d];
        h = fmaf(a, h, bx);
        P *= a;
    }
    size_t idx = ((size_t)c * DI + d) * Nst + n;
    Pb[idx] = P;
    Sb[idx] = h;
}

// ---------------- Scan pass 2: combine in place ----------------
__global__ __launch_bounds__(256) void scan2_k(float* __restrict__ PH,
                                               const float* __restrict__ Sb) {
    int t = blockIdx.x * 256 + threadIdx.x;
    int d = t >> 4, n = t & 15;
    float H = 0.f;
    for (int c = 0; c < NCHUNK; c++) {
        size_t idx = ((size_t)c * DI + d) * Nst + n;
        float P = PH[idx], S = Sb[idx];
        PH[idx] = H;
        H = S + P * H;
    }
}

// ---------------- Scan pass 3: rescan, gate, emit y split bf16 ----------------
__global__ __launch_bounds__(256) void scan3_k(const float* __restrict__ delta,
                                               const float* __restrict__ xc,
                                               const float* __restrict__ bcd,
                                               const float* __restrict__ lmA,
                                               const float* __restrict__ Dp,
                                               const float* __restrict__ gate,
                                               const float* __restrict__ Hinit,
                                               u16* __restrict__ yH,
                                               u16* __restrict__ yL) {
    int n = threadIdx.x & 15;
    int dl = threadIdx.x >> 4;
    int d = blockIdx.x * 16 + dl;
    int c = blockIdx.y;
    float negA = -expf(lmA[(size_t)d * Nst + n]);
    float Dpv = Dp[d];
    float h = Hinit[((size_t)c * DI + d) * Nst + n];
    int l0 = c * LCHUNK;
    for (int l = l0; l < l0 + LCHUNK; ++l) {
        float dv = delta[(size_t)l * DI + d];
        float xcv = xc[(size_t)l * DI + d];
        float a = expf(dv * negA);
        float bx = dv * bcd[(size_t)l * 96 + DRr + n] * xcv;
        h = fmaf(a, h, bx);
        float v = bcd[(size_t)l * 96 + DRr + Nst + n] * h;
        v += __shfl_xor(v, 1);
        v += __shfl_xor(v, 2);
        v += __shfl_xor(v, 4);
        v += __shfl_xor(v, 8);
        if (n == 0) {
            float yv = (v + xcv * Dpv) * gate[(size_t)l * DI + d];
            size_t o = (size_t)l * DI + d;
            u16 hq = f2bf(yv);
            yH[o] = hq;
            yL[o] = f2bf(yv - bf2f(hq));
        }
    }
}

extern "C" void kernel_launch(void* const* d_in, const int* in_sizes, int n_in,
                              void* d_out, int out_size, void* d_ws, size_t ws_size,
                              hipStream_t stream) {
    const float* x          = (const float*)d_in[0];
    const float* rms_w      = (const float*)d_in[1];
    const float* in_proj_w  = (const float*)d_in[2];   // (1024, 4096)
    const float* conv_w     = (const float*)d_in[3];
    const float* conv_b     = (const float*)d_in[4];
    const float* bcd_w      = (const float*)d_in[5];   // (2048, 96)
    const float* dup_w      = (const float*)d_in[6];   // (64, 2048)
    const float* dup_b      = (const float*)d_in[7];
    const float* lmA        = (const float*)d_in[8];
    const float* Dp         = (const float*)d_in[9];
    const float* out_proj_w = (const float*)d_in[10];  // (2048, 1024)
    float* out = (float*)d_out;
    char*  W   = (char*)d_ws;

    const size_t MB = 1ull << 20;
    // Region A: 0-16MB  : WiH/WiL -> xcH/xcL -> delta
    u16*   WiH  = (u16*)(W + 0);
    u16*   WiL  = (u16*)(W + 8 * MB);
    u16*   xcH  = (u16*)(W + 0);
    u16*   xcL  = (u16*)(W + 8 * MB);
    float* delta= (float*)(W + 0);
    // Region B: 16-32MB : xs -> {partials(12MB) + small weights} -> yH/yL
    float* xs   = (float*)(W + 16 * MB);
    float* part = (float*)(W + 16 * MB);                 // 12MB
    u16*   bwTH = (u16*)(W + 28 * MB);                   // 384KB (96x2048)
    u16*   bwTL = (u16*)(W + 28 * MB + 384 * 1024);
    u16*   dwTH = (u16*)(W + 28 * MB + 768 * 1024);      // 256KB (2048x64)
    u16*   dwTL = (u16*)(W + 28 * MB + 1024 * 1024);
    u16*   bcdH = (u16*)(W + 28 * MB + 1280 * 1024);     // 256KB (2048x64)
    u16*   bcdL = (u16*)(W + 28 * MB + 1536 * 1024);
    u16*   yH   = (u16*)(W + 16 * MB);
    u16*   yL   = (u16*)(W + 24 * MB);
    // Region C/D
    float* gate = (float*)(W + 32 * MB);
    float* xc   = (float*)(W + 48 * MB);
    // Region E: 64-72MB : xnH/xnL -> WoH/WoL
    u16*   xnH  = (u16*)(W + 64 * MB);
    u16*   xnL  = (u16*)(W + 68 * MB);
    u16*   WoH  = (u16*)(W + 64 * MB);
    u16*   WoL  = (u16*)(W + 68 * MB);
    // Region F
    float* bcd  = (float*)(W + 72 * MB);                 // 768KB
    float* Pb   = (float*)(W + 73 * MB);                 // 2MB (becomes Hinit)
    float* Sb   = (float*)(W + 75 * MB);                 // 2MB

    // 1. RMSNorm -> split bf16
    rmsnorm_split_k<<<Lseq, 256, 0, stream>>>(x, rms_w, xnH, xnL);
    // 2. in_proj_w -> WiT hi/lo (4096x1024)
    wsplitT_k<<<dim3(4096 / 32, 1024 / 32), 256, 0, stream>>>(in_proj_w, 1024, 4096, WiH, WiL);
    // 3. in_proj: xs / gate (dual epilogue)
    gemm_mfma3<128, 128, 4><<<dim3(4096 / 128, Lseq / 128), 256, 0, stream>>>(
        xnH, xnL, WiH, WiL, xs, gate, nullptr, Lseq, 2 * DI, Dmod);
    // 4. conv + silu -> xc f32 + split
    conv_silu_k<<<dim3(DI / 256, Lseq), 256, 0, stream>>>(xs, conv_w, conv_b, xc, xcH, xcL);
    // 5. out_proj_w -> WoT hi/lo (1024x2048)   (xn dead)
    wsplitT_k<<<dim3(1024 / 32, 2048 / 32), 256, 0, stream>>>(out_proj_w, 2048, 1024, WoH, WoL);
    // 6. bcd_w (2048x96) -> bwT hi/lo (96x2048); dup_w (64x2048) -> dwT hi/lo (2048x64)
    wsplitT_k<<<dim3(96 / 32, 2048 / 32), 256, 0, stream>>>(bcd_w, 2048, 96, bwTH, bwTL);
    wsplitT_k<<<dim3(2048 / 32, 64 / 32), 256, 0, stream>>>(dup_w, 64, 2048, dwTH, dwTL);
    // 7. bcd = xc @ bcd_w via split-K MFMA -> partials, then reduce
    gemm_mfma3<128, 96, 5><<<dim3(1, Lseq / 128, SPLITK), 256, 0, stream>>>(
        xcH, xcL, bwTH, bwTL, part, nullptr, nullptr, Lseq, 96, DI);
    bcd_reduce_k<<<Lseq * 96 / 256, 256, 0, stream>>>(part, bcd, bcdH, bcdL);
    // 8. delta = softplus(bcd[:, :64] @ dup_w + dup_b) via MFMA
    gemm_mfma3<128, 128, 2><<<dim3(DI / 128, Lseq / 128), 256, 0, stream>>>(
        bcdH, bcdL, dwTH, dwTL, delta, nullptr, dup_b, Lseq, DI, DRr);
    // 9-11. chunked selective scan
    scan1_k<<<dim3(DI / 16, NCHUNK), 256, 0, stream>>>(delta, xc, bcd, lmA, Pb, Sb);
    scan2_k<<<dim3(DI * Nst / 256), 256, 0, stream>>>(Pb, Sb);
    scan3_k<<<dim3(DI / 16, NCHUNK), 256, 0, stream>>>(delta, xc, bcd, lmA, Dp, gate, Pb, yH, yL);
    // 12. out = y @ out_proj_w + x
    gemm_mfma3<64, 128, 1><<<dim3(Dmod / 128, Lseq / 64), 256, 0, stream>>>(
        yH, yL, WoH, WoL, out, nullptr, x, Lseq, Dmod, DI);
}

// Round 4
// 292.106 us; speedup vs baseline: 2.4381x; 1.2753x over previous
//
#include <hip/hip_runtime.h>
#include <hip/hip_bf16.h>
#include <math.h>

#define Lseq 2048
#define Dmod 1024
#define DI   2048
#define Nst  16
#define DRr  64
#define NCHUNK 32
#define LCHUNK 64
#define SPLITK 16

typedef unsigned short u16;
typedef float  f32x4  __attribute__((ext_vector_type(4)));
typedef short  short8 __attribute__((ext_vector_type(8)));

__device__ __forceinline__ float sigmoidf_(float x) { return 1.f / (1.f + expf(-x)); }
__device__ __forceinline__ float softplusf_(float x) {
    return fmaxf(x, 0.f) + log1pf(expf(-fabsf(x)));
}
__device__ __forceinline__ u16 f2bf(float x) {
    union { float f; unsigned u; } v; v.f = x;
    unsigned r = (v.u + 0x7fffu + ((v.u >> 16) & 1u)) >> 16;
    return (u16)r;
}
__device__ __forceinline__ float bf2f(u16 h) {
    union { unsigned u; float f; } v; v.u = ((unsigned)h) << 16; return v.f;
}
__device__ __forceinline__ void async16(const void* g, void* l) {
    __builtin_amdgcn_global_load_lds((__attribute__((address_space(1))) void*)g,
                                     (__attribute__((address_space(3))) void*)l, 16, 0, 0);
}

struct __align__(8) u16x4 { u16 x, y, z, w; };

// ---------------- RMSNorm -> split bf16 hi/lo ----------------
__global__ __launch_bounds__(256) void rmsnorm_split_k(const float* __restrict__ x,
                                                       const float* __restrict__ w,
                                                       u16* __restrict__ xh,
                                                       u16* __restrict__ xl) {
    int row = blockIdx.x;
    int tid = threadIdx.x;
    float4 v = reinterpret_cast<const float4*>(x + (size_t)row * Dmod)[tid];
    float ss = v.x * v.x + v.y * v.y + v.z * v.z + v.w * v.w;
    #pragma unroll
    for (int m = 32; m >= 1; m >>= 1) ss += __shfl_xor(ss, m);
    __shared__ float s4[4];
    if ((tid & 63) == 0) s4[tid >> 6] = ss;
    __syncthreads();
    float tot = s4[0] + s4[1] + s4[2] + s4[3];
    float scale = rsqrtf(tot * (1.0f / Dmod) + 1e-5f);
    float4 wv = reinterpret_cast<const float4*>(w)[tid];
    float o[4] = {v.x * scale * wv.x, v.y * scale * wv.y,
                  v.z * scale * wv.z, v.w * scale * wv.w};
    u16x4 H, L;
    u16* hp = &H.x; u16* lp = &L.x;
    #pragma unroll
    for (int q = 0; q < 4; q++) {
        u16 h = f2bf(o[q]); hp[q] = h; lp[q] = f2bf(o[q] - bf2f(h));
    }
    reinterpret_cast<u16x4*>(xh + (size_t)row * Dmod)[tid] = H;
    reinterpret_cast<u16x4*>(xl + (size_t)row * Dmod)[tid] = L;
}

// ---------------- Weight transpose + split: W[R][Cn] -> Th/Tl [Cn][R] ----------------
__global__ __launch_bounds__(256) void wsplitT_k(const float* __restrict__ W, int R, int Cn,
                                                 u16* __restrict__ Th, u16* __restrict__ Tl) {
    __shared__ float t[32][33];
    int r0 = blockIdx.y * 32, c0 = blockIdx.x * 32;
    int tr = threadIdx.x >> 3;
    int tc4 = (threadIdx.x & 7) * 4;
    float4 v = *reinterpret_cast<const float4*>(&W[(size_t)(r0 + tr) * Cn + c0 + tc4]);
    t[tr][tc4 + 0] = v.x; t[tr][tc4 + 1] = v.y;
    t[tr][tc4 + 2] = v.z; t[tr][tc4 + 3] = v.w;
    __syncthreads();
    u16x4 H, L;
    u16* hp = &H.x; u16* lp = &L.x;
    #pragma unroll
    for (int q = 0; q < 4; q++) {
        float xv = t[tc4 + q][tr];
        u16 h = f2bf(xv); hp[q] = h; lp[q] = f2bf(xv - bf2f(h));
    }
    size_t o = (size_t)(c0 + tr) * R + r0 + tc4;
    *reinterpret_cast<u16x4*>(&Th[o]) = H;
    *reinterpret_cast<u16x4*>(&Tl[o]) = L;
}

// ---------------- Split-bf16 MFMA GEMM: C[M][N] = A[M][K] @ Bt[N][K]^T ----------------
// EPI: 0 plain; 1 C=acc+aux; 2 C=softplus(acc+aux[col]); 4 dual in_proj; 5 split-K partial.
template <int BM, int BN, int EPI>
__global__ __launch_bounds__(256) void gemm_mfma3(
    const u16* __restrict__ Ah, const u16* __restrict__ Al,
    const u16* __restrict__ Bh, const u16* __restrict__ Bl,
    float* __restrict__ C, float* __restrict__ C2, const float* __restrict__ aux,
    int M, int N, int K) {
    constexpr int BK = 32;
    constexpr int MF = BM / 32, NF = BN / 32;
    constexpr int CH_A = BM / 16, CH_B = BN / 16;
    __shared__ u16 AhT[BM][BK], AlT[BM][BK], BhT[BN][BK], BlT[BN][BK];
    const int tid = threadIdx.x, lane = tid & 63, wid = tid >> 6;
    const int wr = wid >> 1, wc = wid & 1;
    const int lr = lane & 15, lk = (lane >> 4) * 8;
    const int bm0 = blockIdx.y * BM, bn0 = blockIdx.x * BN;
    const int srow = lane >> 2, scol = (lane & 3) * 8;

    int kbeg = 0, kend = K;
    if (EPI == 5) {
        int ks = K / gridDim.z;
        kbeg = blockIdx.z * ks;
        kend = kbeg + ks;
    }

    f32x4 acc[MF][NF];
    #pragma unroll
    for (int i = 0; i < MF; i++)
        #pragma unroll
        for (int j = 0; j < NF; j++) acc[i][j] = (f32x4){0.f, 0.f, 0.f, 0.f};

    for (int k0 = kbeg; k0 < kend; k0 += BK) {
        int ci = 0;
        #pragma unroll
        for (int c = 0; c < CH_A; c++, ci++) if ((ci & 3) == wid) {
            size_t g = (size_t)(bm0 + c * 16 + srow) * K + (k0 + scol);
            async16(Ah + g, (u16*)&AhT[0][0] + c * 512 + lane * 8);
        }
        #pragma unroll
        for (int c = 0; c < CH_A; c++, ci++) if ((ci & 3) == wid) {
            size_t g = (size_t)(bm0 + c * 16 + srow) * K + (k0 + scol);
            async16(Al + g, (u16*)&AlT[0][0] + c * 512 + lane * 8);
        }
        #pragma unroll
        for (int c = 0; c < CH_B; c++, ci++) if ((ci & 3) == wid) {
            size_t g = (size_t)(bn0 + c * 16 + srow) * K + (k0 + scol);
            async16(Bh + g, (u16*)&BhT[0][0] + c * 512 + lane * 8);
        }
        #pragma unroll
        for (int c = 0; c < CH_B; c++, ci++) if ((ci & 3) == wid) {
            size_t g = (size_t)(bn0 + c * 16 + srow) * K + (k0 + scol);
            async16(Bl + g, (u16*)&BlT[0][0] + c * 512 + lane * 8);
        }
        __syncthreads();

        short8 ah[MF], al[MF], bh[NF], bl[NF];
        #pragma unroll
        for (int i = 0; i < MF; i++) {
            int r = wr * (MF * 16) + i * 16 + lr;
            ah[i] = *(const short8*)&AhT[r][lk];
            al[i] = *(const short8*)&AlT[r][lk];
        }
        #pragma unroll
        for (int j = 0; j < NF; j++) {
            int r = wc * (NF * 16) + j * 16 + lr;
            bh[j] = *(const short8*)&BhT[r][lk];
            bl[j] = *(const short8*)&BlT[r][lk];
        }
        #pragma unroll
        for (int i = 0; i < MF; i++)
            #pragma unroll
            for (int j = 0; j < NF; j++) {
                acc[i][j] = __builtin_amdgcn_mfma_f32_16x16x32_bf16(ah[i], bh[j], acc[i][j], 0, 0, 0);
                acc[i][j] = __builtin_amdgcn_mfma_f32_16x16x32_bf16(ah[i], bl[j], acc[i][j], 0, 0, 0);
                acc[i][j] = __builtin_amdgcn_mfma_f32_16x16x32_bf16(al[i], bh[j], acc[i][j], 0, 0, 0);
            }
        __syncthreads();
    }

    float* Cp = C;
    if (EPI == 5) Cp = C + (size_t)blockIdx.z * M * N;
    #pragma unroll
    for (int i = 0; i < MF; i++)
        #pragma unroll
        for (int j = 0; j < NF; j++) {
            int rowg = bm0 + wr * (MF * 16) + i * 16 + (lane >> 4) * 4;
            int colg = bn0 + wc * (NF * 16) + j * 16 + lr;
            #pragma unroll
            for (int q = 0; q < 4; q++) {
                float v = acc[i][j][q];
                if (EPI == 0 || EPI == 5) {
                    Cp[(size_t)(rowg + q) * N + colg] = v;
                } else if (EPI == 1) {
                    size_t idx = (size_t)(rowg + q) * N + colg;
                    C[idx] = v + aux[idx];
                } else if (EPI == 2) {
                    C[(size_t)(rowg + q) * N + colg] = softplusf_(v + aux[colg]);
                } else if (EPI == 4) {
                    if (colg < DI) C[(size_t)(rowg + q) * DI + colg] = v;
                    else C2[(size_t)(rowg + q) * DI + (colg - DI)] = v * sigmoidf_(v);
                }
            }
        }
}

// ---------------- bcd split-K reduce ----------------
__global__ __launch_bounds__(256) void bcd_reduce_k(const float* __restrict__ partial,
                                                    float* __restrict__ bcd,
                                                    u16* __restrict__ bH,
                                                    u16* __restrict__ bL) {
    const int NT = Lseq * 96;
    int t = blockIdx.x * 256 + threadIdx.x;
    float s = 0.f;
    #pragma unroll
    for (int z = 0; z < SPLITK; z++) s += partial[(size_t)z * NT + t];
    bcd[t] = s;
    int col = t % 96, row = t / 96;
    if (col < DRr) {
        u16 h = f2bf(s);
        bH[(size_t)row * DRr + col] = h;
        bL[(size_t)row * DRr + col] = f2bf(s - bf2f(h));
    }
}

// ---------------- Conv1d(K=4) + SiLU -> split bf16 only ----------------
__global__ __launch_bounds__(256) void conv_silu_k(const float* __restrict__ xs,
                                                   const float* __restrict__ cw,
                                                   const float* __restrict__ cb,
                                                   u16* __restrict__ xcH,
                                                   u16* __restrict__ xcL) {
    int d = blockIdx.x * 256 + threadIdx.x;
    int l = blockIdx.y;
    float4 w = reinterpret_cast<const float4*>(cw)[d];
    float wk[4] = {w.x, w.y, w.z, w.w};
    float s = cb[d];
    #pragma unroll
    for (int k = 0; k < 4; k++) {
        int ls = l - 3 + k;
        if (ls >= 0) s = fmaf(xs[(size_t)ls * DI + d], wk[k], s);
    }
    float v = s * sigmoidf_(s);
    size_t o = (size_t)l * DI + d;
    u16 h = f2bf(v);
    xcH[o] = h;
    xcL[o] = f2bf(v - bf2f(h));
}

// ---------------- Scan pass 1: thread=(d,half), 8 states in registers ----------------
// grid (16, NCHUNK), block 256. d = (bx*256+tid)>>1, half = tid&1.
__global__ __launch_bounds__(256) void scan1_k(const float* __restrict__ delta,
                                               const u16* __restrict__ xcH,
                                               const u16* __restrict__ xcL,
                                               const float* __restrict__ bcd,
                                               const float* __restrict__ lmA,
                                               float* __restrict__ Pb,
                                               float* __restrict__ Sb) {
    __shared__ float Bs[LCHUNK][16];
    const int tid = threadIdx.x;
    const int d = (blockIdx.x * 256 + tid) >> 1;
    const int half = tid & 1;
    const int c = blockIdx.y;
    const int l0 = c * LCHUNK;
    // stage Bm: 64 rows x 16 floats = 256 float4, 1/thread
    {
        int row = tid >> 2, q = (tid & 3) * 4;
        float4 v = *reinterpret_cast<const float4*>(&bcd[(size_t)(l0 + row) * 96 + DRr + q]);
        *reinterpret_cast<float4*>(&Bs[row][q]) = v;
    }
    __syncthreads();
    float negA[8], h[8];
    #pragma unroll
    for (int j = 0; j < 8; j++) {
        negA[j] = -__expf(lmA[(size_t)d * Nst + half * 8 + j]);
        h[j] = 0.f;
    }
    float sdv = 0.f;
    for (int l = 0; l < LCHUNK; ++l) {
        size_t o = (size_t)(l0 + l) * DI + d;
        float dv = delta[o];
        float xcv = bf2f(xcH[o]) + bf2f(xcL[o]);
        sdv += dv;
        float dvx = dv * xcv;
        #pragma unroll
        for (int j = 0; j < 8; j++) {
            float a = __expf(dv * negA[j]);
            h[j] = fmaf(a, h[j], dvx * Bs[l][half * 8 + j]);
        }
    }
    size_t base = ((size_t)c * DI + d) * Nst + half * 8;
    #pragma unroll
    for (int j = 0; j < 8; j++) {
        Pb[base + j] = __expf(sdv * negA[j]);
        Sb[base + j] = h[j];
    }
}

// ---------------- Scan pass 2: combine in place (Pb -> Hinit) ----------------
__global__ __launch_bounds__(256) void scan2_k(float* __restrict__ PH,
                                               const float* __restrict__ Sb) {
    int t = blockIdx.x * 256 + threadIdx.x;   // 0..32767 = d*16+n
    float H = 0.f;
    for (int c = 0; c < NCHUNK; c++) {
        size_t idx = (size_t)c * (DI * Nst) + t;
        float P = PH[idx], S = Sb[idx];
        PH[idx] = H;
        H = S + P * H;
    }
}

// ---------------- Scan pass 3: rescan with init, emit gated y split bf16 ----------------
__global__ __launch_bounds__(256) void scan3_k(const float* __restrict__ delta,
                                               const u16* __restrict__ xcH,
                                               const u16* __restrict__ xcL,
                                               const float* __restrict__ bcd,
                                               const float* __restrict__ lmA,
                                               const float* __restrict__ Dp,
                                               const float* __restrict__ gate,
                                               const float* __restrict__ Hinit,
                                               u16* __restrict__ yH,
                                               u16* __restrict__ yL) {
    __shared__ float BCs[LCHUNK][32];   // [l][0..15]=Bm, [16..31]=Cm
    const int tid = threadIdx.x;
    const int d = (blockIdx.x * 256 + tid) >> 1;
    const int half = tid & 1;
    const int c = blockIdx.y;
    const int l0 = c * LCHUNK;
    // stage Bm+Cm: 64 rows x 32 floats = 512 float4, 2/thread
    #pragma unroll
    for (int i = 0; i < 2; i++) {
        int idx = tid + 256 * i;
        int row = idx >> 3, q = (idx & 7) * 4;
        float4 v = *reinterpret_cast<const float4*>(&bcd[(size_t)(l0 + row) * 96 + DRr + q]);
        *reinterpret_cast<float4*>(&BCs[row][q]) = v;
    }
    __syncthreads();
    float negA[8], h[8];
    size_t hbase = ((size_t)c * DI + d) * Nst + half * 8;
    #pragma unroll
    for (int j = 0; j < 8; j++) {
        negA[j] = -__expf(lmA[(size_t)d * Nst + half * 8 + j]);
        h[j] = Hinit[hbase + j];
    }
    float Dpv = Dp[d];
    for (int l = 0; l < LCHUNK; ++l) {
        size_t o = (size_t)(l0 + l) * DI + d;
        float dv = delta[o];
        float xcv = bf2f(xcH[o]) + bf2f(xcL[o]);
        float dvx = dv * xcv;
        float yp = 0.f;
        #pragma unroll
        for (int j = 0; j < 8; j++) {
            float a = __expf(dv * negA[j]);
            h[j] = fmaf(a, h[j], dvx * BCs[l][half * 8 + j]);
            yp = fmaf(BCs[l][16 + half * 8 + j], h[j], yp);
        }
        yp += __shfl_xor(yp, 1);
        if (half == 0) {
            float yv = (yp + xcv * Dpv) * gate[o];
            u16 hq = f2bf(yv);
            yH[o] = hq;
            yL[o] = f2bf(yv - bf2f(hq));
        }
    }
}

extern "C" void kernel_launch(void* const* d_in, const int* in_sizes, int n_in,
                              void* d_out, int out_size, void* d_ws, size_t ws_size,
                              hipStream_t stream) {
    const float* x          = (const float*)d_in[0];
    const float* rms_w      = (const float*)d_in[1];
    const float* in_proj_w  = (const float*)d_in[2];
    const float* conv_w     = (const float*)d_in[3];
    const float* conv_b     = (const float*)d_in[4];
    const float* bcd_w      = (const float*)d_in[5];
    const float* dup_w      = (const float*)d_in[6];
    const float* dup_b      = (const float*)d_in[7];
    const float* lmA        = (const float*)d_in[8];
    const float* Dp         = (const float*)d_in[9];
    const float* out_proj_w = (const float*)d_in[10];
    float* out = (float*)d_out;
    char*  W   = (char*)d_ws;

    const size_t MB = 1ull << 20;
    // Region A: 0-16MB  : WiH/WiL -> delta
    u16*   WiH  = (u16*)(W + 0);
    u16*   WiL  = (u16*)(W + 8 * MB);
    float* delta= (float*)(W + 0);
    // Region B: 16-32MB : xs -> {part(12)+small wts} -> Sb(4) -> yH/yL(16)
    float* xs   = (float*)(W + 16 * MB);
    float* part = (float*)(W + 16 * MB);
    u16*   bwTH = (u16*)(W + 28 * MB);
    u16*   bwTL = (u16*)(W + 28 * MB + 384 * 1024);
    u16*   dwTH = (u16*)(W + 28 * MB + 768 * 1024);
    u16*   dwTL = (u16*)(W + 28 * MB + 1024 * 1024);
    u16*   bcdH = (u16*)(W + 28 * MB + 1280 * 1024);
    u16*   bcdL = (u16*)(W + 28 * MB + 1536 * 1024);
    float* Sb   = (float*)(W + 16 * MB);                 // 4MB, scan1->scan2
    u16*   yH   = (u16*)(W + 16 * MB);
    u16*   yL   = (u16*)(W + 24 * MB);
    // Region C: 32-48MB : gate
    float* gate = (float*)(W + 32 * MB);
    // Region D: 48-64MB : xcH/xcL
    u16*   xcH  = (u16*)(W + 48 * MB);
    u16*   xcL  = (u16*)(W + 56 * MB);
    // Region E: 64-72MB : xnH/xnL -> WoH/WoL
    u16*   xnH  = (u16*)(W + 64 * MB);
    u16*   xnL  = (u16*)(W + 68 * MB);
    u16*   WoH  = (u16*)(W + 64 * MB);
    u16*   WoL  = (u16*)(W + 68 * MB);
    // Region F: 72-77MB : bcd f32 (768KB) + Pb (4MB, becomes Hinit)
    float* bcd  = (float*)(W + 72 * MB);
    float* Pb   = (float*)(W + 73 * MB);

    // 1. RMSNorm -> split bf16
    rmsnorm_split_k<<<Lseq, 256, 0, stream>>>(x, rms_w, xnH, xnL);
    // 2. in_proj_w -> WiT hi/lo
    wsplitT_k<<<dim3(4096 / 32, 1024 / 32), 256, 0, stream>>>(in_proj_w, 1024, 4096, WiH, WiL);
    // 3. in_proj: xs / gate
    gemm_mfma3<128, 128, 4><<<dim3(4096 / 128, Lseq / 128), 256, 0, stream>>>(
        xnH, xnL, WiH, WiL, xs, gate, nullptr, Lseq, 2 * DI, Dmod);
    // 4. conv + silu -> xc split bf16
    conv_silu_k<<<dim3(DI / 256, Lseq), 256, 0, stream>>>(xs, conv_w, conv_b, xcH, xcL);
    // 5. out_proj_w -> WoT hi/lo (xn dead)
    wsplitT_k<<<dim3(1024 / 32, 2048 / 32), 256, 0, stream>>>(out_proj_w, 2048, 1024, WoH, WoL);
    // 6. small weights
    wsplitT_k<<<dim3(96 / 32, 2048 / 32), 256, 0, stream>>>(bcd_w, 2048, 96, bwTH, bwTL);
    wsplitT_k<<<dim3(2048 / 32, 64 / 32), 256, 0, stream>>>(dup_w, 64, 2048, dwTH, dwTL);
    // 7. bcd = xc @ bcd_w (split-K MFMA + reduce)
    gemm_mfma3<128, 96, 5><<<dim3(1, Lseq / 128, SPLITK), 256, 0, stream>>>(
        xcH, xcL, bwTH, bwTL, part, nullptr, nullptr, Lseq, 96, DI);
    bcd_reduce_k<<<Lseq * 96 / 256, 256, 0, stream>>>(part, bcd, bcdH, bcdL);
    // 8. delta = softplus(bcd[:, :64] @ dup_w + dup_b)
    gemm_mfma3<128, 128, 2><<<dim3(DI / 128, Lseq / 128), 256, 0, stream>>>(
        bcdH, bcdL, dwTH, dwTL, delta, nullptr, dup_b, Lseq, DI, DRr);
    // 9-11. chunked selective scan (register-state form)
    scan1_k<<<dim3(16, NCHUNK), 256, 0, stream>>>(delta, xcH, xcL, bcd, lmA, Pb, Sb);
    scan2_k<<<dim3(DI * Nst / 256), 256, 0, stream>>>(Pb, Sb);
    scan3_k<<<dim3(16, NCHUNK), 256, 0, stream>>>(delta, xcH, xcL, bcd, lmA, Dp, gate, Pb, yH, yL);
    // 12. out = y @ out_proj_w + x
    gemm_mfma3<64, 128, 1><<<dim3(Dmod / 128, Lseq / 64), 256, 0, stream>>>(
        yH, yL, WoH, WoL, out, nullptr, x, Lseq, Dmod, DI);
}

// Round 5
// 281.420 us; speedup vs baseline: 2.5306x; 1.0380x over previous
//
#include <hip/hip_runtime.h>
#include <hip/hip_bf16.h>
#include <math.h>

#define Lseq 2048
#define Dmod 1024
#define DI   2048
#define Nst  16
#define DRr  64
#define NCHUNK 32
#define LCHUNK 64
#define SPLITK 16

typedef unsigned short u16;
typedef float  f32x4  __attribute__((ext_vector_type(4)));
typedef short  short8 __attribute__((ext_vector_type(8)));

__device__ __forceinline__ float sigmoidf_(float x) { return 1.f / (1.f + expf(-x)); }
__device__ __forceinline__ float softplusf_(float x) {
    return fmaxf(x, 0.f) + log1pf(expf(-fabsf(x)));
}
__device__ __forceinline__ u16 f2bf(float x) {
    union { float f; unsigned u; } v; v.f = x;
    unsigned r = (v.u + 0x7fffu + ((v.u >> 16) & 1u)) >> 16;
    return (u16)r;
}
__device__ __forceinline__ float bf2f(u16 h) {
    union { unsigned u; float f; } v; v.u = ((unsigned)h) << 16; return v.f;
}
__device__ __forceinline__ void async16(const void* g, void* l) {
    __builtin_amdgcn_global_load_lds((__attribute__((address_space(1))) void*)g,
                                     (__attribute__((address_space(3))) void*)l, 16, 0, 0);
}

struct __align__(8) u16x4 { u16 x, y, z, w; };

// ---------------- RMSNorm -> split bf16 hi/lo ----------------
__global__ __launch_bounds__(256) void rmsnorm_split_k(const float* __restrict__ x,
                                                       const float* __restrict__ w,
                                                       u16* __restrict__ xh,
                                                       u16* __restrict__ xl) {
    int row = blockIdx.x;
    int tid = threadIdx.x;
    float4 v = reinterpret_cast<const float4*>(x + (size_t)row * Dmod)[tid];
    float ss = v.x * v.x + v.y * v.y + v.z * v.z + v.w * v.w;
    #pragma unroll
    for (int m = 32; m >= 1; m >>= 1) ss += __shfl_xor(ss, m);
    __shared__ float s4[4];
    if ((tid & 63) == 0) s4[tid >> 6] = ss;
    __syncthreads();
    float tot = s4[0] + s4[1] + s4[2] + s4[3];
    float scale = rsqrtf(tot * (1.0f / Dmod) + 1e-5f);
    float4 wv = reinterpret_cast<const float4*>(w)[tid];
    float o[4] = {v.x * scale * wv.x, v.y * scale * wv.y,
                  v.z * scale * wv.z, v.w * scale * wv.w};
    u16x4 H, L;
    u16* hp = &H.x; u16* lp = &L.x;
    #pragma unroll
    for (int q = 0; q < 4; q++) {
        u16 h = f2bf(o[q]); hp[q] = h; lp[q] = f2bf(o[q] - bf2f(h));
    }
    reinterpret_cast<u16x4*>(xh + (size_t)row * Dmod)[tid] = H;
    reinterpret_cast<u16x4*>(xl + (size_t)row * Dmod)[tid] = L;
}

// ---------------- Weight transpose + split body ----------------
__device__ __forceinline__ void wsplit_body(const float* __restrict__ W, int R, int Cn,
                                            int bx, int by, float (*t)[33],
                                            u16* __restrict__ Th, u16* __restrict__ Tl) {
    int r0 = by * 32, c0 = bx * 32;
    int tr = threadIdx.x >> 3;
    int tc4 = (threadIdx.x & 7) * 4;
    float4 v = *reinterpret_cast<const float4*>(&W[(size_t)(r0 + tr) * Cn + c0 + tc4]);
    t[tr][tc4 + 0] = v.x; t[tr][tc4 + 1] = v.y;
    t[tr][tc4 + 2] = v.z; t[tr][tc4 + 3] = v.w;
    __syncthreads();
    u16x4 H, L;
    u16* hp = &H.x; u16* lp = &L.x;
    #pragma unroll
    for (int q = 0; q < 4; q++) {
        float xv = t[tc4 + q][tr];
        u16 h = f2bf(xv); hp[q] = h; lp[q] = f2bf(xv - bf2f(h));
    }
    size_t o = (size_t)(c0 + tr) * R + r0 + tc4;
    *reinterpret_cast<u16x4*>(&Th[o]) = H;
    *reinterpret_cast<u16x4*>(&Tl[o]) = L;
}

__global__ __launch_bounds__(256) void wsplitT_k(const float* __restrict__ W, int R, int Cn,
                                                 u16* __restrict__ Th, u16* __restrict__ Tl) {
    __shared__ float t[32][33];
    wsplit_body(W, R, Cn, blockIdx.x, blockIdx.y, t, Th, Tl);
}

// Combined prep for out_proj_w (2048 blk), bcd_w (192 blk), dup_w (128 blk)
__global__ __launch_bounds__(256) void wsplit3_k(const float* __restrict__ Wo,
                                                 const float* __restrict__ Wb,
                                                 const float* __restrict__ Wd,
                                                 u16* WoH, u16* WoL,
                                                 u16* bwTH, u16* bwTL,
                                                 u16* dwTH, u16* dwTL) {
    __shared__ float t[32][33];
    int b = blockIdx.x;
    if (b < 2048) {
        wsplit_body(Wo, 2048, 1024, b & 31, b >> 5, t, WoH, WoL);
    } else if (b < 2240) {
        int bb = b - 2048;
        wsplit_body(Wb, 2048, 96, bb % 3, bb / 3, t, bwTH, bwTL);
    } else {
        int bb = b - 2240;
        wsplit_body(Wd, 64, 2048, bb & 63, bb >> 6, t, dwTH, dwTL);
    }
}

// ---------------- Split-bf16 MFMA GEMM: C[M][N] = A[M][K] @ Bt[N][K]^T ----------------
// EPI: 2 C=softplus(acc+aux[col]); 4 dual in_proj; 5 split-K partial write.
template <int BM, int BN, int EPI>
__global__ __launch_bounds__(256) void gemm_mfma3(
    const u16* __restrict__ Ah, const u16* __restrict__ Al,
    const u16* __restrict__ Bh, const u16* __restrict__ Bl,
    float* __restrict__ C, float* __restrict__ C2, const float* __restrict__ aux,
    int M, int N, int K) {
    constexpr int BK = 32;
    constexpr int MF = BM / 32, NF = BN / 32;
    constexpr int CH_A = BM / 16, CH_B = BN / 16;
    __shared__ u16 AhT[BM][BK], AlT[BM][BK], BhT[BN][BK], BlT[BN][BK];
    const int tid = threadIdx.x, lane = tid & 63, wid = tid >> 6;
    const int wr = wid >> 1, wc = wid & 1;
    const int lr = lane & 15, lk = (lane >> 4) * 8;
    const int bm0 = blockIdx.y * BM, bn0 = blockIdx.x * BN;
    const int srow = lane >> 2, scol = (lane & 3) * 8;

    int kbeg = 0, kend = K;
    if (EPI == 5) {
        int ks = K / gridDim.z;
        kbeg = blockIdx.z * ks;
        kend = kbeg + ks;
    }

    f32x4 acc[MF][NF];
    #pragma unroll
    for (int i = 0; i < MF; i++)
        #pragma unroll
        for (int j = 0; j < NF; j++) acc[i][j] = (f32x4){0.f, 0.f, 0.f, 0.f};

    for (int k0 = kbeg; k0 < kend; k0 += BK) {
        int ci = 0;
        #pragma unroll
        for (int c = 0; c < CH_A; c++, ci++) if ((ci & 3) == wid) {
            size_t g = (size_t)(bm0 + c * 16 + srow) * K + (k0 + scol);
            async16(Ah + g, (u16*)&AhT[0][0] + c * 512 + lane * 8);
        }
        #pragma unroll
        for (int c = 0; c < CH_A; c++, ci++) if ((ci & 3) == wid) {
            size_t g = (size_t)(bm0 + c * 16 + srow) * K + (k0 + scol);
            async16(Al + g, (u16*)&AlT[0][0] + c * 512 + lane * 8);
        }
        #pragma unroll
        for (int c = 0; c < CH_B; c++, ci++) if ((ci & 3) == wid) {
            size_t g = (size_t)(bn0 + c * 16 + srow) * K + (k0 + scol);
            async16(Bh + g, (u16*)&BhT[0][0] + c * 512 + lane * 8);
        }
        #pragma unroll
        for (int c = 0; c < CH_B; c++, ci++) if ((ci & 3) == wid) {
            size_t g = (size_t)(bn0 + c * 16 + srow) * K + (k0 + scol);
            async16(Bl + g, (u16*)&BlT[0][0] + c * 512 + lane * 8);
        }
        __syncthreads();

        short8 ah[MF], al[MF], bh[NF], bl[NF];
        #pragma unroll
        for (int i = 0; i < MF; i++) {
            int r = wr * (MF * 16) + i * 16 + lr;
            ah[i] = *(const short8*)&AhT[r][lk];
            al[i] = *(const short8*)&AlT[r][lk];
        }
        #pragma unroll
        for (int j = 0; j < NF; j++) {
            int r = wc * (NF * 16) + j * 16 + lr;
            bh[j] = *(const short8*)&BhT[r][lk];
            bl[j] = *(const short8*)&BlT[r][lk];
        }
        #pragma unroll
        for (int i = 0; i < MF; i++)
            #pragma unroll
            for (int j = 0; j < NF; j++) {
                acc[i][j] = __builtin_amdgcn_mfma_f32_16x16x32_bf16(ah[i], bh[j], acc[i][j], 0, 0, 0);
                acc[i][j] = __builtin_amdgcn_mfma_f32_16x16x32_bf16(ah[i], bl[j], acc[i][j], 0, 0, 0);
                acc[i][j] = __builtin_amdgcn_mfma_f32_16x16x32_bf16(al[i], bh[j], acc[i][j], 0, 0, 0);
            }
        __syncthreads();
    }

    float* Cp = C;
    if (EPI == 5) Cp = C + (size_t)blockIdx.z * M * N;
    #pragma unroll
    for (int i = 0; i < MF; i++)
        #pragma unroll
        for (int j = 0; j < NF; j++) {
            int rowg = bm0 + wr * (MF * 16) + i * 16 + (lane >> 4) * 4;
            int colg = bn0 + wc * (NF * 16) + j * 16 + lr;
            #pragma unroll
            for (int q = 0; q < 4; q++) {
                float v = acc[i][j][q];
                if (EPI == 5) {
                    Cp[(size_t)(rowg + q) * N + colg] = v;
                } else if (EPI == 2) {
                    C[(size_t)(rowg + q) * N + colg] = softplusf_(v + aux[colg]);
                } else if (EPI == 4) {
                    if (colg < DI) C[(size_t)(rowg + q) * DI + colg] = v;
                    else C2[(size_t)(rowg + q) * DI + (colg - DI)] = v * sigmoidf_(v);
                }
            }
        }
}

// ---------------- bcd split-K reduce ----------------
__global__ __launch_bounds__(256) void bcd_reduce_k(const float* __restrict__ partial,
                                                    float* __restrict__ bcd,
                                                    u16* __restrict__ bH,
                                                    u16* __restrict__ bL) {
    const int NT = Lseq * 96;
    int t = blockIdx.x * 256 + threadIdx.x;
    float s = 0.f;
    #pragma unroll
    for (int z = 0; z < SPLITK; z++) s += partial[(size_t)z * NT + t];
    bcd[t] = s;
    int col = t % 96, row = t / 96;
    if (col < DRr) {
        u16 h = f2bf(s);
        bH[(size_t)row * DRr + col] = h;
        bL[(size_t)row * DRr + col] = f2bf(s - bf2f(h));
    }
}

// ---------------- out split-K=2 reduce + residual: out = p0 + p1 + x ----------------
__global__ __launch_bounds__(256) void out_reduce_k(const float* __restrict__ part,
                                                    const float* __restrict__ x,
                                                    float* __restrict__ out) {
    int t = blockIdx.x * 256 + threadIdx.x;   // float4 index
    const size_t NT = (size_t)Lseq * Dmod;
    float4 a = reinterpret_cast<const float4*>(part)[t];
    float4 b = reinterpret_cast<const float4*>(part + NT)[t];
    float4 xv = reinterpret_cast<const float4*>(x)[t];
    float4 o;
    o.x = a.x + b.x + xv.x; o.y = a.y + b.y + xv.y;
    o.z = a.z + b.z + xv.z; o.w = a.w + b.w + xv.w;
    reinterpret_cast<float4*>(out)[t] = o;
}

// ---------------- Conv1d(K=4) + SiLU -> split bf16 ----------------
__global__ __launch_bounds__(256) void conv_silu_k(const float* __restrict__ xs,
                                                   const float* __restrict__ cw,
                                                   const float* __restrict__ cb,
                                                   u16* __restrict__ xcH,
                                                   u16* __restrict__ xcL) {
    int d = blockIdx.x * 256 + threadIdx.x;
    int l = blockIdx.y;
    float4 w = reinterpret_cast<const float4*>(cw)[d];
    float wk[4] = {w.x, w.y, w.z, w.w};
    float s = cb[d];
    #pragma unroll
    for (int k = 0; k < 4; k++) {
        int ls = l - 3 + k;
        if (ls >= 0) s = fmaf(xs[(size_t)ls * DI + d], wk[k], s);
    }
    float v = s * sigmoidf_(s);
    size_t o = (size_t)l * DI + d;
    u16 h = f2bf(v);
    xcH[o] = h;
    xcL[o] = f2bf(v - bf2f(h));
}

// ---------------- Scan pass 1: thread=(d,half), 8 states in registers ----------------
__global__ __launch_bounds__(256) void scan1_k(const float* __restrict__ delta,
                                               const u16* __restrict__ xcH,
                                               const u16* __restrict__ xcL,
                                               const float* __restrict__ bcd,
                                               const float* __restrict__ lmA,
                                               float* __restrict__ Pb,
                                               float* __restrict__ Sb) {
    __shared__ float Bs[LCHUNK][16];
    const int tid = threadIdx.x;
    const int d = (blockIdx.x * 256 + tid) >> 1;
    const int half = tid & 1;
    const int c = blockIdx.y;
    const int l0 = c * LCHUNK;
    {
        int row = tid >> 2, q = (tid & 3) * 4;
        float4 v = *reinterpret_cast<const float4*>(&bcd[(size_t)(l0 + row) * 96 + DRr + q]);
        *reinterpret_cast<float4*>(&Bs[row][q]) = v;
    }
    __syncthreads();
    float negA[8], h[8];
    #pragma unroll
    for (int j = 0; j < 8; j++) {
        negA[j] = -__expf(lmA[(size_t)d * Nst + half * 8 + j]);
        h[j] = 0.f;
    }
    float sdv = 0.f;
    for (int l = 0; l < LCHUNK; ++l) {
        size_t o = (size_t)(l0 + l) * DI + d;
        float dv = delta[o];
        float xcv = bf2f(xcH[o]) + bf2f(xcL[o]);
        sdv += dv;
        float dvx = dv * xcv;
        #pragma unroll
        for (int j = 0; j < 8; j++) {
            float a = __expf(dv * negA[j]);
            h[j] = fmaf(a, h[j], dvx * Bs[l][half * 8 + j]);
        }
    }
    size_t base = ((size_t)c * DI + d) * Nst + half * 8;
    #pragma unroll
    for (int j = 0; j < 8; j++) {
        Pb[base + j] = __expf(sdv * negA[j]);
        Sb[base + j] = h[j];
    }
}

// ---------------- Scan pass 2: combine in place (Pb -> Hinit) ----------------
__global__ __launch_bounds__(256) void scan2_k(float* __restrict__ PH,
                                               const float* __restrict__ Sb) {
    int t = blockIdx.x * 256 + threadIdx.x;
    float H = 0.f;
    for (int c = 0; c < NCHUNK; c++) {
        size_t idx = (size_t)c * (DI * Nst) + t;
        float P = PH[idx], S = Sb[idx];
        PH[idx] = H;
        H = S + P * H;
    }
}

// ---------------- Scan pass 3: rescan with init, emit gated y split bf16 ----------------
__global__ __launch_bounds__(256) void scan3_k(const float* __restrict__ delta,
                                               const u16* __restrict__ xcH,
                                               const u16* __restrict__ xcL,
                                               const float* __restrict__ bcd,
                                               const float* __restrict__ lmA,
                                               const float* __restrict__ Dp,
                                               const float* __restrict__ gate,
                                               const float* __restrict__ Hinit,
                                               u16* __restrict__ yH,
                                               u16* __restrict__ yL) {
    __shared__ float BCs[LCHUNK][32];
    const int tid = threadIdx.x;
    const int d = (blockIdx.x * 256 + tid) >> 1;
    const int half = tid & 1;
    const int c = blockIdx.y;
    const int l0 = c * LCHUNK;
    #pragma unroll
    for (int i = 0; i < 2; i++) {
        int idx = tid + 256 * i;
        int row = idx >> 3, q = (idx & 7) * 4;
        float4 v = *reinterpret_cast<const float4*>(&bcd[(size_t)(l0 + row) * 96 + DRr + q]);
        *reinterpret_cast<float4*>(&BCs[row][q]) = v;
    }
    __syncthreads();
    float negA[8], h[8];
    size_t hbase = ((size_t)c * DI + d) * Nst + half * 8;
    #pragma unroll
    for (int j = 0; j < 8; j++) {
        negA[j] = -__expf(lmA[(size_t)d * Nst + half * 8 + j]);
        h[j] = Hinit[hbase + j];
    }
    float Dpv = Dp[d];
    for (int l = 0; l < LCHUNK; ++l) {
        size_t o = (size_t)(l0 + l) * DI + d;
        float dv = delta[o];
        float xcv = bf2f(xcH[o]) + bf2f(xcL[o]);
        float dvx = dv * xcv;
        float yp = 0.f;
        #pragma unroll
        for (int j = 0; j < 8; j++) {
            float a = __expf(dv * negA[j]);
            h[j] = fmaf(a, h[j], dvx * BCs[l][half * 8 + j]);
            yp = fmaf(BCs[l][16 + half * 8 + j], h[j], yp);
        }
        yp += __shfl_xor(yp, 1);
        if (half == 0) {
            float yv = (yp + xcv * Dpv) * gate[o];
            u16 hq = f2bf(yv);
            yH[o] = hq;
            yL[o] = f2bf(yv - bf2f(hq));
        }
    }
}

extern "C" void kernel_launch(void* const* d_in, const int* in_sizes, int n_in,
                              void* d_out, int out_size, void* d_ws, size_t ws_size,
                              hipStream_t stream) {
    const float* x          = (const float*)d_in[0];
    const float* rms_w      = (const float*)d_in[1];
    const float* in_proj_w  = (const float*)d_in[2];
    const float* conv_w     = (const float*)d_in[3];
    const float* conv_b     = (const float*)d_in[4];
    const float* bcd_w      = (const float*)d_in[5];
    const float* dup_w      = (const float*)d_in[6];
    const float* dup_b      = (const float*)d_in[7];
    const float* lmA        = (const float*)d_in[8];
    const float* Dp         = (const float*)d_in[9];
    const float* out_proj_w = (const float*)d_in[10];
    float* out = (float*)d_out;
    char*  W   = (char*)d_ws;

    const size_t MB = 1ull << 20;
    // Region A: 0-16MB  : WiH/WiL -> delta -> out_part (16MB, split-K=2)
    u16*   WiH  = (u16*)(W + 0);
    u16*   WiL  = (u16*)(W + 8 * MB);
    float* delta= (float*)(W + 0);
    float* opart= (float*)(W + 0);
    // Region B: 16-32MB : xs -> {part(12)+small wts} -> Sb(4) -> yH/yL(16)
    float* xs   = (float*)(W + 16 * MB);
    float* part = (float*)(W + 16 * MB);
    u16*   bwTH = (u16*)(W + 28 * MB);
    u16*   bwTL = (u16*)(W + 28 * MB + 384 * 1024);
    u16*   dwTH = (u16*)(W + 28 * MB + 768 * 1024);
    u16*   dwTL = (u16*)(W + 28 * MB + 1024 * 1024);
    u16*   bcdH = (u16*)(W + 28 * MB + 1280 * 1024);
    u16*   bcdL = (u16*)(W + 28 * MB + 1536 * 1024);
    float* Sb   = (float*)(W + 16 * MB);
    u16*   yH   = (u16*)(W + 16 * MB);
    u16*   yL   = (u16*)(W + 24 * MB);
    // Region C: 32-48MB : gate
    float* gate = (float*)(W + 32 * MB);
    // Region D: 48-64MB : xcH/xcL
    u16*   xcH  = (u16*)(W + 48 * MB);
    u16*   xcL  = (u16*)(W + 56 * MB);
    // Region E: 64-72MB : xnH/xnL -> WoH/WoL
    u16*   xnH  = (u16*)(W + 64 * MB);
    u16*   xnL  = (u16*)(W + 68 * MB);
    u16*   WoH  = (u16*)(W + 64 * MB);
    u16*   WoL  = (u16*)(W + 68 * MB);
    // Region F: 72-77MB : bcd f32 + Pb (becomes Hinit)
    float* bcd  = (float*)(W + 72 * MB);
    float* Pb   = (float*)(W + 73 * MB);

    // 1. RMSNorm -> split bf16
    rmsnorm_split_k<<<Lseq, 256, 0, stream>>>(x, rms_w, xnH, xnL);
    // 2. in_proj_w -> WiT hi/lo
    wsplitT_k<<<dim3(4096 / 32, 1024 / 32), 256, 0, stream>>>(in_proj_w, 1024, 4096, WiH, WiL);
    // 3. in_proj: xs / gate  (128x64 tile, 1024 blocks = 4/CU)
    gemm_mfma3<128, 64, 4><<<dim3(4096 / 64, Lseq / 128), 256, 0, stream>>>(
        xnH, xnL, WiH, WiL, xs, gate, nullptr, Lseq, 2 * DI, Dmod);
    // 4. conv + silu -> xc split bf16
    conv_silu_k<<<dim3(DI / 256, Lseq), 256, 0, stream>>>(xs, conv_w, conv_b, xcH, xcL);
    // 5. combined prep: out_proj_w / bcd_w / dup_w (xn dead)
    wsplit3_k<<<2368, 256, 0, stream>>>(out_proj_w, bcd_w, dup_w,
                                        WoH, WoL, bwTH, bwTL, dwTH, dwTL);
    // 6. bcd = xc @ bcd_w (split-K MFMA + reduce)
    gemm_mfma3<128, 96, 5><<<dim3(1, Lseq / 128, SPLITK), 256, 0, stream>>>(
        xcH, xcL, bwTH, bwTL, part, nullptr, nullptr, Lseq, 96, DI);
    bcd_reduce_k<<<Lseq * 96 / 256, 256, 0, stream>>>(part, bcd, bcdH, bcdL);
    // 7. delta = softplus(bcd[:, :64] @ dup_w + dup_b)
    gemm_mfma3<128, 128, 2><<<dim3(DI / 128, Lseq / 128), 256, 0, stream>>>(
        bcdH, bcdL, dwTH, dwTL, delta, nullptr, dup_b, Lseq, DI, DRr);
    // 8-10. chunked selective scan
    scan1_k<<<dim3(16, NCHUNK), 256, 0, stream>>>(delta, xcH, xcL, bcd, lmA, Pb, Sb);
    scan2_k<<<dim3(DI * Nst / 256), 256, 0, stream>>>(Pb, Sb);
    scan3_k<<<dim3(16, NCHUNK), 256, 0, stream>>>(delta, xcH, xcL, bcd, lmA, Dp, gate, Pb, yH, yL);
    // 11. out_proj: split-K=2 partials (128x64 tile, 512 blocks), then reduce + residual
    gemm_mfma3<128, 64, 5><<<dim3(Dmod / 64, Lseq / 128, 2), 256, 0, stream>>>(
        yH, yL, WoH, WoL, opart, nullptr, nullptr, Lseq, Dmod, DI);
    out_reduce_k<<<Lseq * Dmod / 1024, 256, 0, stream>>>(opart, x, out);
}

// Round 6
// 258.297 us; speedup vs baseline: 2.7572x; 1.0895x over previous
//
#include <hip/hip_runtime.h>
#include <hip/hip_bf16.h>
#include <math.h>

#define Lseq 2048
#define Dmod 1024
#define DI   2048
#define Nst  16
#define DRr  64
#define NCHUNK 32
#define LCHUNK 64
#define SPLITK 16
#define OSPLIT 4

typedef unsigned short u16;
typedef float  f32x4  __attribute__((ext_vector_type(4)));
typedef short  short8 __attribute__((ext_vector_type(8)));

__device__ __forceinline__ float sigmoidf_(float x) { return 1.f / (1.f + expf(-x)); }
__device__ __forceinline__ float softplusf_(float x) {
    return fmaxf(x, 0.f) + log1pf(expf(-fabsf(x)));
}
__device__ __forceinline__ u16 f2bf(float x) {
    union { float f; unsigned u; } v; v.f = x;
    unsigned r = (v.u + 0x7fffu + ((v.u >> 16) & 1u)) >> 16;
    return (u16)r;
}
__device__ __forceinline__ float bf2f(u16 h) {
    union { unsigned u; float f; } v; v.u = ((unsigned)h) << 16; return v.f;
}
__device__ __forceinline__ void async16(const void* g, void* l) {
    __builtin_amdgcn_global_load_lds((__attribute__((address_space(1))) void*)g,
                                     (__attribute__((address_space(3))) void*)l, 16, 0, 0);
}

struct __align__(8) u16x4 { u16 x, y, z, w; };

// ---------------- RMSNorm -> split bf16 hi/lo ----------------
__global__ __launch_bounds__(256) void rmsnorm_split_k(const float* __restrict__ x,
                                                       const float* __restrict__ w,
                                                       u16* __restrict__ xh,
                                                       u16* __restrict__ xl) {
    int row = blockIdx.x;
    int tid = threadIdx.x;
    float4 v = reinterpret_cast<const float4*>(x + (size_t)row * Dmod)[tid];
    float ss = v.x * v.x + v.y * v.y + v.z * v.z + v.w * v.w;
    #pragma unroll
    for (int m = 32; m >= 1; m >>= 1) ss += __shfl_xor(ss, m);
    __shared__ float s4[4];
    if ((tid & 63) == 0) s4[tid >> 6] = ss;
    __syncthreads();
    float tot = s4[0] + s4[1] + s4[2] + s4[3];
    float scale = rsqrtf(tot * (1.0f / Dmod) + 1e-5f);
    float4 wv = reinterpret_cast<const float4*>(w)[tid];
    float o[4] = {v.x * scale * wv.x, v.y * scale * wv.y,
                  v.z * scale * wv.z, v.w * scale * wv.w};
    u16x4 H, L;
    u16* hp = &H.x; u16* lp = &L.x;
    #pragma unroll
    for (int q = 0; q < 4; q++) {
        u16 h = f2bf(o[q]); hp[q] = h; lp[q] = f2bf(o[q] - bf2f(h));
    }
    reinterpret_cast<u16x4*>(xh + (size_t)row * Dmod)[tid] = H;
    reinterpret_cast<u16x4*>(xl + (size_t)row * Dmod)[tid] = L;
}

// ---------------- Weight transpose + split body ----------------
__device__ __forceinline__ void wsplit_body(const float* __restrict__ W, int R, int Cn,
                                            int bx, int by, float (*t)[33],
                                            u16* __restrict__ Th, u16* __restrict__ Tl) {
    int r0 = by * 32, c0 = bx * 32;
    int tr = threadIdx.x >> 3;
    int tc4 = (threadIdx.x & 7) * 4;
    float4 v = *reinterpret_cast<const float4*>(&W[(size_t)(r0 + tr) * Cn + c0 + tc4]);
    t[tr][tc4 + 0] = v.x; t[tr][tc4 + 1] = v.y;
    t[tr][tc4 + 2] = v.z; t[tr][tc4 + 3] = v.w;
    __syncthreads();
    u16x4 H, L;
    u16* hp = &H.x; u16* lp = &L.x;
    #pragma unroll
    for (int q = 0; q < 4; q++) {
        float xv = t[tc4 + q][tr];
        u16 h = f2bf(xv); hp[q] = h; lp[q] = f2bf(xv - bf2f(h));
    }
    size_t o = (size_t)(c0 + tr) * R + r0 + tc4;
    *reinterpret_cast<u16x4*>(&Th[o]) = H;
    *reinterpret_cast<u16x4*>(&Tl[o]) = L;
}

__global__ __launch_bounds__(256) void wsplitT_k(const float* __restrict__ W, int R, int Cn,
                                                 u16* __restrict__ Th, u16* __restrict__ Tl) {
    __shared__ float t[32][33];
    wsplit_body(W, R, Cn, blockIdx.x, blockIdx.y, t, Th, Tl);
}

// Combined prep for out_proj_w (2048 blk), bcd_w (192 blk), dup_w (128 blk)
__global__ __launch_bounds__(256) void wsplit3_k(const float* __restrict__ Wo,
                                                 const float* __restrict__ Wb,
                                                 const float* __restrict__ Wd,
                                                 u16* WoH, u16* WoL,
                                                 u16* bwTH, u16* bwTL,
                                                 u16* dwTH, u16* dwTL) {
    __shared__ float t[32][33];
    int b = blockIdx.x;
    if (b < 2048) {
        wsplit_body(Wo, 2048, 1024, b & 31, b >> 5, t, WoH, WoL);
    } else if (b < 2240) {
        int bb = b - 2048;
        wsplit_body(Wb, 2048, 96, bb % 3, bb / 3, t, bwTH, bwTL);
    } else {
        int bb = b - 2240;
        wsplit_body(Wd, 64, 2048, bb & 63, bb >> 6, t, dwTH, dwTL);
    }
}

// ---------------- Split-bf16 MFMA GEMM: C[M][N] = A[M][K] @ Bt[N][K]^T ----------------
// EPI: 2 C=softplus(acc+aux[col]); 4 dual in_proj; 5 split-K partial write.
template <int BM, int BN, int EPI>
__global__ __launch_bounds__(256) void gemm_mfma3(
    const u16* __restrict__ Ah, const u16* __restrict__ Al,
    const u16* __restrict__ Bh, const u16* __restrict__ Bl,
    float* __restrict__ C, float* __restrict__ C2, const float* __restrict__ aux,
    int M, int N, int K) {
    constexpr int BK = 32;
    constexpr int MF = BM / 32, NF = BN / 32;
    constexpr int CH_A = BM / 16, CH_B = BN / 16;
    __shared__ u16 AhT[BM][BK], AlT[BM][BK], BhT[BN][BK], BlT[BN][BK];
    const int tid = threadIdx.x, lane = tid & 63, wid = tid >> 6;
    const int wr = wid >> 1, wc = wid & 1;
    const int lr = lane & 15, lk = (lane >> 4) * 8;
    const int bm0 = blockIdx.y * BM, bn0 = blockIdx.x * BN;
    const int srow = lane >> 2, scol = (lane & 3) * 8;

    int kbeg = 0, kend = K;
    if (EPI == 5) {
        int ks = K / gridDim.z;
        kbeg = blockIdx.z * ks;
        kend = kbeg + ks;
    }

    f32x4 acc[MF][NF];
    #pragma unroll
    for (int i = 0; i < MF; i++)
        #pragma unroll
        for (int j = 0; j < NF; j++) acc[i][j] = (f32x4){0.f, 0.f, 0.f, 0.f};

    for (int k0 = kbeg; k0 < kend; k0 += BK) {
        int ci = 0;
        #pragma unroll
        for (int c = 0; c < CH_A; c++, ci++) if ((ci & 3) == wid) {
            size_t g = (size_t)(bm0 + c * 16 + srow) * K + (k0 + scol);
            async16(Ah + g, (u16*)&AhT[0][0] + c * 512 + lane * 8);
        }
        #pragma unroll
        for (int c = 0; c < CH_A; c++, ci++) if ((ci & 3) == wid) {
            size_t g = (size_t)(bm0 + c * 16 + srow) * K + (k0 + scol);
            async16(Al + g, (u16*)&AlT[0][0] + c * 512 + lane * 8);
        }
        #pragma unroll
        for (int c = 0; c < CH_B; c++, ci++) if ((ci & 3) == wid) {
            size_t g = (size_t)(bn0 + c * 16 + srow) * K + (k0 + scol);
            async16(Bh + g, (u16*)&BhT[0][0] + c * 512 + lane * 8);
        }
        #pragma unroll
        for (int c = 0; c < CH_B; c++, ci++) if ((ci & 3) == wid) {
            size_t g = (size_t)(bn0 + c * 16 + srow) * K + (k0 + scol);
            async16(Bl + g, (u16*)&BlT[0][0] + c * 512 + lane * 8);
        }
        __syncthreads();

        short8 ah[MF], al[MF], bh[NF], bl[NF];
        #pragma unroll
        for (int i = 0; i < MF; i++) {
            int r = wr * (MF * 16) + i * 16 + lr;
            ah[i] = *(const short8*)&AhT[r][lk];
            al[i] = *(const short8*)&AlT[r][lk];
        }
        #pragma unroll
        for (int j = 0; j < NF; j++) {
            int r = wc * (NF * 16) + j * 16 + lr;
            bh[j] = *(const short8*)&BhT[r][lk];
            bl[j] = *(const short8*)&BlT[r][lk];
        }
        #pragma unroll
        for (int i = 0; i < MF; i++)
            #pragma unroll
            for (int j = 0; j < NF; j++) {
                acc[i][j] = __builtin_amdgcn_mfma_f32_16x16x32_bf16(ah[i], bh[j], acc[i][j], 0, 0, 0);
                acc[i][j] = __builtin_amdgcn_mfma_f32_16x16x32_bf16(ah[i], bl[j], acc[i][j], 0, 0, 0);
                acc[i][j] = __builtin_amdgcn_mfma_f32_16x16x32_bf16(al[i], bh[j], acc[i][j], 0, 0, 0);
            }
        __syncthreads();
    }

    float* Cp = C;
    if (EPI == 5) Cp = C + (size_t)blockIdx.z * M * N;
    #pragma unroll
    for (int i = 0; i < MF; i++)
        #pragma unroll
        for (int j = 0; j < NF; j++) {
            int rowg = bm0 + wr * (MF * 16) + i * 16 + (lane >> 4) * 4;
            int colg = bn0 + wc * (NF * 16) + j * 16 + lr;
            #pragma unroll
            for (int q = 0; q < 4; q++) {
                float v = acc[i][j][q];
                if (EPI == 5) {
                    Cp[(size_t)(rowg + q) * N + colg] = v;
                } else if (EPI == 2) {
                    C[(size_t)(rowg + q) * N + colg] = softplusf_(v + aux[colg]);
                } else if (EPI == 4) {
                    if (colg < DI) C[(size_t)(rowg + q) * DI + colg] = v;
                    else C2[(size_t)(rowg + q) * DI + (colg - DI)] = v * sigmoidf_(v);
                }
            }
        }
}

// ---------------- bcd split-K reduce ----------------
__global__ __launch_bounds__(256) void bcd_reduce_k(const float* __restrict__ partial,
                                                    float* __restrict__ bcd,
                                                    u16* __restrict__ bH,
                                                    u16* __restrict__ bL) {
    const int NT = Lseq * 96;
    int t = blockIdx.x * 256 + threadIdx.x;
    float s = 0.f;
    #pragma unroll
    for (int z = 0; z < SPLITK; z++) s += partial[(size_t)z * NT + t];
    bcd[t] = s;
    int col = t % 96, row = t / 96;
    if (col < DRr) {
        u16 h = f2bf(s);
        bH[(size_t)row * DRr + col] = h;
        bL[(size_t)row * DRr + col] = f2bf(s - bf2f(h));
    }
}

// ---------------- out split-K=4 reduce + residual: out = sum(p) + x ----------------
__global__ __launch_bounds__(256) void out_reduce_k(const float* __restrict__ part,
                                                    const float* __restrict__ x,
                                                    float* __restrict__ out) {
    int t = blockIdx.x * 256 + threadIdx.x;   // float4 index
    const size_t NT = (size_t)Lseq * Dmod;
    float4 xv = reinterpret_cast<const float4*>(x)[t];
    float4 o = xv;
    #pragma unroll
    for (int z = 0; z < OSPLIT; z++) {
        float4 p = reinterpret_cast<const float4*>(part + (size_t)z * NT)[t];
        o.x += p.x; o.y += p.y; o.z += p.z; o.w += p.w;
    }
    reinterpret_cast<float4*>(out)[t] = o;
}

// ---------------- Conv1d(K=4) + SiLU -> split bf16 ----------------
__global__ __launch_bounds__(256) void conv_silu_k(const float* __restrict__ xs,
                                                   const float* __restrict__ cw,
                                                   const float* __restrict__ cb,
                                                   u16* __restrict__ xcH,
                                                   u16* __restrict__ xcL) {
    int d = blockIdx.x * 256 + threadIdx.x;
    int l = blockIdx.y;
    float4 w = reinterpret_cast<const float4*>(cw)[d];
    float wk[4] = {w.x, w.y, w.z, w.w};
    float s = cb[d];
    #pragma unroll
    for (int k = 0; k < 4; k++) {
        int ls = l - 3 + k;
        if (ls >= 0) s = fmaf(xs[(size_t)ls * DI + d], wk[k], s);
    }
    float v = s * sigmoidf_(s);
    size_t o = (size_t)l * DI + d;
    u16 h = f2bf(v);
    xcH[o] = h;
    xcL[o] = f2bf(v - bf2f(h));
}

// ---------------- Scan pass 1: thread=(d,half), 8 states in registers ----------------
__global__ __launch_bounds__(256) void scan1_k(const float* __restrict__ delta,
                                               const u16* __restrict__ xcH,
                                               const u16* __restrict__ xcL,
                                               const float* __restrict__ bcd,
                                               const float* __restrict__ lmA,
                                               float* __restrict__ Pb,
                                               float* __restrict__ Sb) {
    __shared__ float Bs[LCHUNK][16];
    const int tid = threadIdx.x;
    const int d = (blockIdx.x * 256 + tid) >> 1;
    const int half = tid & 1;
    const int c = blockIdx.y;
    const int l0 = c * LCHUNK;
    {
        int row = tid >> 2, q = (tid & 3) * 4;
        float4 v = *reinterpret_cast<const float4*>(&bcd[(size_t)(l0 + row) * 96 + DRr + q]);
        *reinterpret_cast<float4*>(&Bs[row][q]) = v;
    }
    __syncthreads();
    float negA[8], h[8];
    #pragma unroll
    for (int j = 0; j < 8; j++) {
        negA[j] = -__expf(lmA[(size_t)d * Nst + half * 8 + j]);
        h[j] = 0.f;
    }
    float sdv = 0.f;
    for (int l = 0; l < LCHUNK; ++l) {
        size_t o = (size_t)(l0 + l) * DI + d;
        float dv = delta[o];
        float xcv = bf2f(xcH[o]) + bf2f(xcL[o]);
        sdv += dv;
        float dvx = dv * xcv;
        #pragma unroll
        for (int j = 0; j < 8; j++) {
            float a = __expf(dv * negA[j]);
            h[j] = fmaf(a, h[j], dvx * Bs[l][half * 8 + j]);
        }
    }
    size_t base = ((size_t)c * DI + d) * Nst + half * 8;
    #pragma unroll
    for (int j = 0; j < 8; j++) {
        Pb[base + j] = __expf(sdv * negA[j]);
        Sb[base + j] = h[j];
    }
}

// ---------------- Scan pass 2: combine in place (Pb -> Hinit) ----------------
__global__ __launch_bounds__(256) void scan2_k(float* __restrict__ PH,
                                               const float* __restrict__ Sb) {
    int t = blockIdx.x * 256 + threadIdx.x;
    float H = 0.f;
    for (int c = 0; c < NCHUNK; c++) {
        size_t idx = (size_t)c * (DI * Nst) + t;
        float P = PH[idx], S = Sb[idx];
        PH[idx] = H;
        H = S + P * H;
    }
}

// ---------------- Scan pass 3: rescan with init, emit gated y split bf16 ----------------
__global__ __launch_bounds__(256) void scan3_k(const float* __restrict__ delta,
                                               const u16* __restrict__ xcH,
                                               const u16* __restrict__ xcL,
                                               const float* __restrict__ bcd,
                                               const float* __restrict__ lmA,
                                               const float* __restrict__ Dp,
                                               const float* __restrict__ gate,
                                               const float* __restrict__ Hinit,
                                               u16* __restrict__ yH,
                                               u16* __restrict__ yL) {
    __shared__ float BCs[LCHUNK][32];
    const int tid = threadIdx.x;
    const int d = (blockIdx.x * 256 + tid) >> 1;
    const int half = tid & 1;
    const int c = blockIdx.y;
    const int l0 = c * LCHUNK;
    #pragma unroll
    for (int i = 0; i < 2; i++) {
        int idx = tid + 256 * i;
        int row = idx >> 3, q = (idx & 7) * 4;
        float4 v = *reinterpret_cast<const float4*>(&bcd[(size_t)(l0 + row) * 96 + DRr + q]);
        *reinterpret_cast<float4*>(&BCs[row][q]) = v;
    }
    __syncthreads();
    float negA[8], h[8];
    size_t hbase = ((size_t)c * DI + d) * Nst + half * 8;
    #pragma unroll
    for (int j = 0; j < 8; j++) {
        negA[j] = -__expf(lmA[(size_t)d * Nst + half * 8 + j]);
        h[j] = Hinit[hbase + j];
    }
    float Dpv = Dp[d];
    for (int l = 0; l < LCHUNK; ++l) {
        size_t o = (size_t)(l0 + l) * DI + d;
        float dv = delta[o];
        float xcv = bf2f(xcH[o]) + bf2f(xcL[o]);
        float dvx = dv * xcv;
        float yp = 0.f;
        #pragma unroll
        for (int j = 0; j < 8; j++) {
            float a = __expf(dv * negA[j]);
            h[j] = fmaf(a, h[j], dvx * BCs[l][half * 8 + j]);
            yp = fmaf(BCs[l][16 + half * 8 + j], h[j], yp);
        }
        yp += __shfl_xor(yp, 1);
        if (half == 0) {
            float yv = (yp + xcv * Dpv) * gate[o];
            u16 hq = f2bf(yv);
            yH[o] = hq;
            yL[o] = f2bf(yv - bf2f(hq));
        }
    }
}

extern "C" void kernel_launch(void* const* d_in, const int* in_sizes, int n_in,
                              void* d_out, int out_size, void* d_ws, size_t ws_size,
                              hipStream_t stream) {
    const float* x          = (const float*)d_in[0];
    const float* rms_w      = (const float*)d_in[1];
    const float* in_proj_w  = (const float*)d_in[2];
    const float* conv_w     = (const float*)d_in[3];
    const float* conv_b     = (const float*)d_in[4];
    const float* bcd_w      = (const float*)d_in[5];
    const float* dup_w      = (const float*)d_in[6];
    const float* dup_b      = (const float*)d_in[7];
    const float* lmA        = (const float*)d_in[8];
    const float* Dp         = (const float*)d_in[9];
    const float* out_proj_w = (const float*)d_in[10];
    float* out = (float*)d_out;
    char*  W   = (char*)d_ws;

    const size_t MB = 1ull << 20;
    // Region A: 0-16MB  : WiH/WiL -> delta
    u16*   WiH  = (u16*)(W + 0);
    u16*   WiL  = (u16*)(W + 8 * MB);
    float* delta= (float*)(W + 0);
    // Region B: 16-32MB : xs -> {part(12)+small wts} -> Sb(4) -> yH/yL(16)
    float* xs   = (float*)(W + 16 * MB);
    float* part = (float*)(W + 16 * MB);
    u16*   bwTH = (u16*)(W + 28 * MB);
    u16*   bwTL = (u16*)(W + 28 * MB + 384 * 1024);
    u16*   dwTH = (u16*)(W + 28 * MB + 768 * 1024);
    u16*   dwTL = (u16*)(W + 28 * MB + 1024 * 1024);
    u16*   bcdH = (u16*)(W + 28 * MB + 1280 * 1024);
    u16*   bcdL = (u16*)(W + 28 * MB + 1536 * 1024);
    float* Sb   = (float*)(W + 16 * MB);
    u16*   yH   = (u16*)(W + 16 * MB);
    u16*   yL   = (u16*)(W + 24 * MB);
    // Region C+D: 32-64MB : gate(16) + xcH/xcL(16) -> opart (32MB, split-K=4, post-scan3)
    float* gate = (float*)(W + 32 * MB);
    u16*   xcH  = (u16*)(W + 48 * MB);
    u16*   xcL  = (u16*)(W + 56 * MB);
    float* opart= (float*)(W + 32 * MB);
    // Region E: 64-72MB : xnH/xnL -> WoH/WoL
    u16*   xnH  = (u16*)(W + 64 * MB);
    u16*   xnL  = (u16*)(W + 68 * MB);
    u16*   WoH  = (u16*)(W + 64 * MB);
    u16*   WoL  = (u16*)(W + 68 * MB);
    // Region F: 72-77MB : bcd f32 + Pb (becomes Hinit)
    float* bcd  = (float*)(W + 72 * MB);
    float* Pb   = (float*)(W + 73 * MB);

    // 1. RMSNorm -> split bf16
    rmsnorm_split_k<<<Lseq, 256, 0, stream>>>(x, rms_w, xnH, xnL);
    // 2. in_proj_w -> WiT hi/lo
    wsplitT_k<<<dim3(4096 / 32, 1024 / 32), 256, 0, stream>>>(in_proj_w, 1024, 4096, WiH, WiL);
    // 3. in_proj: xs / gate  (128x128 tile, 512 blocks = 2/CU — R4-proven config)
    gemm_mfma3<128, 128, 4><<<dim3(4096 / 128, Lseq / 128), 256, 0, stream>>>(
        xnH, xnL, WiH, WiL, xs, gate, nullptr, Lseq, 2 * DI, Dmod);
    // 4. conv + silu -> xc split bf16
    conv_silu_k<<<dim3(DI / 256, Lseq), 256, 0, stream>>>(xs, conv_w, conv_b, xcH, xcL);
    // 5. combined prep: out_proj_w / bcd_w / dup_w (xn dead)
    wsplit3_k<<<2368, 256, 0, stream>>>(out_proj_w, bcd_w, dup_w,
                                        WoH, WoL, bwTH, bwTL, dwTH, dwTL);
    // 6. bcd = xc @ bcd_w (split-K MFMA + reduce)
    gemm_mfma3<128, 96, 5><<<dim3(1, Lseq / 128, SPLITK), 256, 0, stream>>>(
        xcH, xcL, bwTH, bwTL, part, nullptr, nullptr, Lseq, 96, DI);
    bcd_reduce_k<<<Lseq * 96 / 256, 256, 0, stream>>>(part, bcd, bcdH, bcdL);
    // 7. delta = softplus(bcd[:, :64] @ dup_w + dup_b)
    gemm_mfma3<128, 128, 2><<<dim3(DI / 128, Lseq / 128), 256, 0, stream>>>(
        bcdH, bcdL, dwTH, dwTL, delta, nullptr, dup_b, Lseq, DI, DRr);
    // 8-10. chunked selective scan
    scan1_k<<<dim3(16, NCHUNK), 256, 0, stream>>>(delta, xcH, xcL, bcd, lmA, Pb, Sb);
    scan2_k<<<dim3(DI * Nst / 256), 256, 0, stream>>>(Pb, Sb);
    scan3_k<<<dim3(16, NCHUNK), 256, 0, stream>>>(delta, xcH, xcL, bcd, lmA, Dp, gate, Pb, yH, yL);
    // 11. out_proj: 128x128 tile + split-K=4 (512 blocks = 2/CU), reduce + residual
    gemm_mfma3<128, 128, 5><<<dim3(Dmod / 128, Lseq / 128, OSPLIT), 256, 0, stream>>>(
        yH, yL, WoH, WoL, opart, nullptr, nullptr, Lseq, Dmod, DI);
    out_reduce_k<<<Lseq * Dmod / 1024, 256, 0, stream>>>(opart, x, out);
}

// Round 7
// 248.209 us; speedup vs baseline: 2.8692x; 1.0406x over previous
//
#include <hip/hip_runtime.h>
#include <hip/hip_bf16.h>
#include <math.h>

#define Lseq 2048
#define Dmod 1024
#define DI   2048
#define Nst  16
#define DRr  64
#define NCHUNK 32
#define LCHUNK 64
#define SPLITK 16
#define OSPLIT 4

typedef unsigned short u16;
typedef float  f32x4  __attribute__((ext_vector_type(4)));
typedef short  short8 __attribute__((ext_vector_type(8)));

__device__ __forceinline__ float sigmoidf_(float x) { return 1.f / (1.f + expf(-x)); }
__device__ __forceinline__ float softplusf_(float x) {
    return fmaxf(x, 0.f) + log1pf(expf(-fabsf(x)));
}
__device__ __forceinline__ u16 f2bf(float x) {
    union { float f; unsigned u; } v; v.f = x;
    unsigned r = (v.u + 0x7fffu + ((v.u >> 16) & 1u)) >> 16;
    return (u16)r;
}
__device__ __forceinline__ float bf2f(u16 h) {
    union { unsigned u; float f; } v; v.u = ((unsigned)h) << 16; return v.f;
}
__device__ __forceinline__ void async16(const void* g, void* l) {
    __builtin_amdgcn_global_load_lds((__attribute__((address_space(1))) void*)g,
                                     (__attribute__((address_space(3))) void*)l, 16, 0, 0);
}

struct __align__(8) u16x4 { u16 x, y, z, w; };

// ---------------- RMSNorm -> split bf16 hi/lo ----------------
__global__ __launch_bounds__(256) void rmsnorm_split_k(const float* __restrict__ x,
                                                       const float* __restrict__ w,
                                                       u16* __restrict__ xh,
                                                       u16* __restrict__ xl) {
    int row = blockIdx.x;
    int tid = threadIdx.x;
    float4 v = reinterpret_cast<const float4*>(x + (size_t)row * Dmod)[tid];
    float ss = v.x * v.x + v.y * v.y + v.z * v.z + v.w * v.w;
    #pragma unroll
    for (int m = 32; m >= 1; m >>= 1) ss += __shfl_xor(ss, m);
    __shared__ float s4[4];
    if ((tid & 63) == 0) s4[tid >> 6] = ss;
    __syncthreads();
    float tot = s4[0] + s4[1] + s4[2] + s4[3];
    float scale = rsqrtf(tot * (1.0f / Dmod) + 1e-5f);
    float4 wv = reinterpret_cast<const float4*>(w)[tid];
    float o[4] = {v.x * scale * wv.x, v.y * scale * wv.y,
                  v.z * scale * wv.z, v.w * scale * wv.w};
    u16x4 H, L;
    u16* hp = &H.x; u16* lp = &L.x;
    #pragma unroll
    for (int q = 0; q < 4; q++) {
        u16 h = f2bf(o[q]); hp[q] = h; lp[q] = f2bf(o[q] - bf2f(h));
    }
    reinterpret_cast<u16x4*>(xh + (size_t)row * Dmod)[tid] = H;
    reinterpret_cast<u16x4*>(xl + (size_t)row * Dmod)[tid] = L;
}

// ---------------- Weight transpose + split body ----------------
__device__ __forceinline__ void wsplit_body(const float* __restrict__ W, int R, int Cn,
                                            int bx, int by, float (*t)[33],
                                            u16* __restrict__ Th, u16* __restrict__ Tl) {
    int r0 = by * 32, c0 = bx * 32;
    int tr = threadIdx.x >> 3;
    int tc4 = (threadIdx.x & 7) * 4;
    float4 v = *reinterpret_cast<const float4*>(&W[(size_t)(r0 + tr) * Cn + c0 + tc4]);
    t[tr][tc4 + 0] = v.x; t[tr][tc4 + 1] = v.y;
    t[tr][tc4 + 2] = v.z; t[tr][tc4 + 3] = v.w;
    __syncthreads();
    u16x4 H, L;
    u16* hp = &H.x; u16* lp = &L.x;
    #pragma unroll
    for (int q = 0; q < 4; q++) {
        float xv = t[tc4 + q][tr];
        u16 h = f2bf(xv); hp[q] = h; lp[q] = f2bf(xv - bf2f(h));
    }
    size_t o = (size_t)(c0 + tr) * R + r0 + tc4;
    *reinterpret_cast<u16x4*>(&Th[o]) = H;
    *reinterpret_cast<u16x4*>(&Tl[o]) = L;
}

__global__ __launch_bounds__(256) void wsplitT_k(const float* __restrict__ W, int R, int Cn,
                                                 u16* __restrict__ Th, u16* __restrict__ Tl) {
    __shared__ float t[32][33];
    wsplit_body(W, R, Cn, blockIdx.x, blockIdx.y, t, Th, Tl);
}

// Combined prep for out_proj_w (2048 blk), bcd_w (192 blk), dup_w (128 blk)
__global__ __launch_bounds__(256) void wsplit3_k(const float* __restrict__ Wo,
                                                 const float* __restrict__ Wb,
                                                 const float* __restrict__ Wd,
                                                 u16* WoH, u16* WoL,
                                                 u16* bwTH, u16* bwTL,
                                                 u16* dwTH, u16* dwTL) {
    __shared__ float t[32][33];
    int b = blockIdx.x;
    if (b < 2048) {
        wsplit_body(Wo, 2048, 1024, b & 31, b >> 5, t, WoH, WoL);
    } else if (b < 2240) {
        int bb = b - 2048;
        wsplit_body(Wb, 2048, 96, bb % 3, bb / 3, t, bwTH, bwTL);
    } else {
        int bb = b - 2240;
        wsplit_body(Wd, 64, 2048, bb & 63, bb >> 6, t, dwTH, dwTL);
    }
}

// ---------------- Split-bf16 MFMA GEMM, 2-stage LDS double-buffer pipeline ----------
// C[M][N] = A[M][K] @ Bt[N][K]^T
// EPI: 2 C=softplus(acc+aux[col]); 4 dual in_proj; 5 split-K partial write.
template <int BM, int BN, int EPI>
__global__ __launch_bounds__(256) void gemm_mfma3(
    const u16* __restrict__ Ah, const u16* __restrict__ Al,
    const u16* __restrict__ Bh, const u16* __restrict__ Bl,
    float* __restrict__ C, float* __restrict__ C2, const float* __restrict__ aux,
    int M, int N, int K) {
    constexpr int BK = 32;
    constexpr int MF = BM / 32, NF = BN / 32;
    constexpr int CH_A = BM / 16, CH_B = BN / 16;
    __shared__ u16 AhT[2][BM][BK], AlT[2][BM][BK], BhT[2][BN][BK], BlT[2][BN][BK];
    const int tid = threadIdx.x, lane = tid & 63, wid = tid >> 6;
    const int wr = wid >> 1, wc = wid & 1;
    const int lr = lane & 15, lk = (lane >> 4) * 8;
    const int bm0 = blockIdx.y * BM, bn0 = blockIdx.x * BN;
    const int srow = lane >> 2, scol = (lane & 3) * 8;

    int kbeg = 0, kend = K;
    if (EPI == 5) {
        int ks = K / gridDim.z;
        kbeg = blockIdx.z * ks;
        kend = kbeg + ks;
    }
    const int nt = (kend - kbeg) / BK;

    // issue one buffer's worth of async global->LDS loads (8B-lane granular, 16B each)
    auto STAGE = [&](int buf, int k0) {
        int ci = 0;
        #pragma unroll
        for (int c = 0; c < CH_A; c++, ci++) if ((ci & 3) == wid) {
            size_t g = (size_t)(bm0 + c * 16 + srow) * K + (k0 + scol);
            async16(Ah + g, (u16*)&AhT[buf][0][0] + c * 512 + lane * 8);
        }
        #pragma unroll
        for (int c = 0; c < CH_A; c++, ci++) if ((ci & 3) == wid) {
            size_t g = (size_t)(bm0 + c * 16 + srow) * K + (k0 + scol);
            async16(Al + g, (u16*)&AlT[buf][0][0] + c * 512 + lane * 8);
        }
        #pragma unroll
        for (int c = 0; c < CH_B; c++, ci++) if ((ci & 3) == wid) {
            size_t g = (size_t)(bn0 + c * 16 + srow) * K + (k0 + scol);
            async16(Bh + g, (u16*)&BhT[buf][0][0] + c * 512 + lane * 8);
        }
        #pragma unroll
        for (int c = 0; c < CH_B; c++, ci++) if ((ci & 3) == wid) {
            size_t g = (size_t)(bn0 + c * 16 + srow) * K + (k0 + scol);
            async16(Bl + g, (u16*)&BlT[buf][0][0] + c * 512 + lane * 8);
        }
    };

    f32x4 acc[MF][NF];
    #pragma unroll
    for (int i = 0; i < MF; i++)
        #pragma unroll
        for (int j = 0; j < NF; j++) acc[i][j] = (f32x4){0.f, 0.f, 0.f, 0.f};

    // prologue: fill buffer 0
    STAGE(0, kbeg);
    asm volatile("s_waitcnt vmcnt(0)" ::: "memory");
    __builtin_amdgcn_s_barrier();

    for (int t = 0; t < nt; ++t) {
        const int cur = t & 1;
        // issue next tile's loads first — they fly under this tile's ds_read+MFMA
        if (t + 1 < nt) STAGE(cur ^ 1, kbeg + (t + 1) * BK);

        short8 ah[MF], al[MF], bh[NF], bl[NF];
        #pragma unroll
        for (int i = 0; i < MF; i++) {
            int r = wr * (MF * 16) + i * 16 + lr;
            ah[i] = *(const short8*)&AhT[cur][r][lk];
            al[i] = *(const short8*)&AlT[cur][r][lk];
        }
        #pragma unroll
        for (int j = 0; j < NF; j++) {
            int r = wc * (NF * 16) + j * 16 + lr;
            bh[j] = *(const short8*)&BhT[cur][r][lk];
            bl[j] = *(const short8*)&BlT[cur][r][lk];
        }
        asm volatile("s_waitcnt lgkmcnt(0)" ::: "memory");
        __builtin_amdgcn_sched_barrier(0);
        #pragma unroll
        for (int i = 0; i < MF; i++)
            #pragma unroll
            for (int j = 0; j < NF; j++) {
                acc[i][j] = __builtin_amdgcn_mfma_f32_16x16x32_bf16(ah[i], bh[j], acc[i][j], 0, 0, 0);
                acc[i][j] = __builtin_amdgcn_mfma_f32_16x16x32_bf16(ah[i], bl[j], acc[i][j], 0, 0, 0);
                acc[i][j] = __builtin_amdgcn_mfma_f32_16x16x32_bf16(al[i], bh[j], acc[i][j], 0, 0, 0);
            }
        if (t + 1 < nt) {
            // next buffer staged (own loads landed) + all waves done reading cur
            asm volatile("s_waitcnt vmcnt(0)" ::: "memory");
            __builtin_amdgcn_s_barrier();
        }
    }

    float* Cp = C;
    if (EPI == 5) Cp = C + (size_t)blockIdx.z * M * N;
    #pragma unroll
    for (int i = 0; i < MF; i++)
        #pragma unroll
        for (int j = 0; j < NF; j++) {
            int rowg = bm0 + wr * (MF * 16) + i * 16 + (lane >> 4) * 4;
            int colg = bn0 + wc * (NF * 16) + j * 16 + lr;
            #pragma unroll
            for (int q = 0; q < 4; q++) {
                float v = acc[i][j][q];
                if (EPI == 5) {
                    Cp[(size_t)(rowg + q) * N + colg] = v;
                } else if (EPI == 2) {
                    C[(size_t)(rowg + q) * N + colg] = softplusf_(v + aux[colg]);
                } else if (EPI == 4) {
                    if (colg < DI) C[(size_t)(rowg + q) * DI + colg] = v;
                    else C2[(size_t)(rowg + q) * DI + (colg - DI)] = v * sigmoidf_(v);
                }
            }
        }
}

// ---------------- bcd split-K reduce ----------------
__global__ __launch_bounds__(256) void bcd_reduce_k(const float* __restrict__ partial,
                                                    float* __restrict__ bcd,
                                                    u16* __restrict__ bH,
                                                    u16* __restrict__ bL) {
    const int NT = Lseq * 96;
    int t = blockIdx.x * 256 + threadIdx.x;
    float s = 0.f;
    #pragma unroll
    for (int z = 0; z < SPLITK; z++) s += partial[(size_t)z * NT + t];
    bcd[t] = s;
    int col = t % 96, row = t / 96;
    if (col < DRr) {
        u16 h = f2bf(s);
        bH[(size_t)row * DRr + col] = h;
        bL[(size_t)row * DRr + col] = f2bf(s - bf2f(h));
    }
}

// ---------------- out split-K=4 reduce + residual: out = sum(p) + x ----------------
__global__ __launch_bounds__(256) void out_reduce_k(const float* __restrict__ part,
                                                    const float* __restrict__ x,
                                                    float* __restrict__ out) {
    int t = blockIdx.x * 256 + threadIdx.x;   // float4 index
    const size_t NT = (size_t)Lseq * Dmod;
    float4 xv = reinterpret_cast<const float4*>(x)[t];
    float4 o = xv;
    #pragma unroll
    for (int z = 0; z < OSPLIT; z++) {
        float4 p = reinterpret_cast<const float4*>(part + (size_t)z * NT)[t];
        o.x += p.x; o.y += p.y; o.z += p.z; o.w += p.w;
    }
    reinterpret_cast<float4*>(out)[t] = o;
}

// ---------------- Conv1d(K=4) + SiLU -> split bf16 ----------------
__global__ __launch_bounds__(256) void conv_silu_k(const float* __restrict__ xs,
                                                   const float* __restrict__ cw,
                                                   const float* __restrict__ cb,
                                                   u16* __restrict__ xcH,
                                                   u16* __restrict__ xcL) {
    int d = blockIdx.x * 256 + threadIdx.x;
    int l = blockIdx.y;
    float4 w = reinterpret_cast<const float4*>(cw)[d];
    float wk[4] = {w.x, w.y, w.z, w.w};
    float s = cb[d];
    #pragma unroll
    for (int k = 0; k < 4; k++) {
        int ls = l - 3 + k;
        if (ls >= 0) s = fmaf(xs[(size_t)ls * DI + d], wk[k], s);
    }
    float v = s * sigmoidf_(s);
    size_t o = (size_t)l * DI + d;
    u16 h = f2bf(v);
    xcH[o] = h;
    xcL[o] = f2bf(v - bf2f(h));
}

// ---------------- Scan pass 1: thread=(d,half), 8 states in registers ----------------
__global__ __launch_bounds__(256) void scan1_k(const float* __restrict__ delta,
                                               const u16* __restrict__ xcH,
                                               const u16* __restrict__ xcL,
                                               const float* __restrict__ bcd,
                                               const float* __restrict__ lmA,
                                               float* __restrict__ Pb,
                                               float* __restrict__ Sb) {
    __shared__ float Bs[LCHUNK][16];
    const int tid = threadIdx.x;
    const int d = (blockIdx.x * 256 + tid) >> 1;
    const int half = tid & 1;
    const int c = blockIdx.y;
    const int l0 = c * LCHUNK;
    {
        int row = tid >> 2, q = (tid & 3) * 4;
        float4 v = *reinterpret_cast<const float4*>(&bcd[(size_t)(l0 + row) * 96 + DRr + q]);
        *reinterpret_cast<float4*>(&Bs[row][q]) = v;
    }
    __syncthreads();
    float negA[8], h[8];
    #pragma unroll
    for (int j = 0; j < 8; j++) {
        negA[j] = -__expf(lmA[(size_t)d * Nst + half * 8 + j]);
        h[j] = 0.f;
    }
    float sdv = 0.f;
    for (int l = 0; l < LCHUNK; ++l) {
        size_t o = (size_t)(l0 + l) * DI + d;
        float dv = delta[o];
        float xcv = bf2f(xcH[o]) + bf2f(xcL[o]);
        sdv += dv;
        float dvx = dv * xcv;
        #pragma unroll
        for (int j = 0; j < 8; j++) {
            float a = __expf(dv * negA[j]);
            h[j] = fmaf(a, h[j], dvx * Bs[l][half * 8 + j]);
        }
    }
    size_t base = ((size_t)c * DI + d) * Nst + half * 8;
    #pragma unroll
    for (int j = 0; j < 8; j++) {
        Pb[base + j] = __expf(sdv * negA[j]);
        Sb[base + j] = h[j];
    }
}

// ---------------- Scan pass 2: combine in place (Pb -> Hinit) ----------------
__global__ __launch_bounds__(256) void scan2_k(float* __restrict__ PH,
                                               const float* __restrict__ Sb) {
    int t = blockIdx.x * 256 + threadIdx.x;
    float H = 0.f;
    for (int c = 0; c < NCHUNK; c++) {
        size_t idx = (size_t)c * (DI * Nst) + t;
        float P = PH[idx], S = Sb[idx];
        PH[idx] = H;
        H = S + P * H;
    }
}

// ---------------- Scan pass 3: rescan with init, emit gated y split bf16 ----------------
__global__ __launch_bounds__(256) void scan3_k(const float* __restrict__ delta,
                                               const u16* __restrict__ xcH,
                                               const u16* __restrict__ xcL,
                                               const float* __restrict__ bcd,
                                               const float* __restrict__ lmA,
                                               const float* __restrict__ Dp,
                                               const float* __restrict__ gate,
                                               const float* __restrict__ Hinit,
                                               u16* __restrict__ yH,
                                               u16* __restrict__ yL) {
    __shared__ float BCs[LCHUNK][32];
    const int tid = threadIdx.x;
    const int d = (blockIdx.x * 256 + tid) >> 1;
    const int half = tid & 1;
    const int c = blockIdx.y;
    const int l0 = c * LCHUNK;
    #pragma unroll
    for (int i = 0; i < 2; i++) {
        int idx = tid + 256 * i;
        int row = idx >> 3, q = (idx & 7) * 4;
        float4 v = *reinterpret_cast<const float4*>(&bcd[(size_t)(l0 + row) * 96 + DRr + q]);
        *reinterpret_cast<float4*>(&BCs[row][q]) = v;
    }
    __syncthreads();
    float negA[8], h[8];
    size_t hbase = ((size_t)c * DI + d) * Nst + half * 8;
    #pragma unroll
    for (int j = 0; j < 8; j++) {
        negA[j] = -__expf(lmA[(size_t)d * Nst + half * 8 + j]);
        h[j] = Hinit[hbase + j];
    }
    float Dpv = Dp[d];
    for (int l = 0; l < LCHUNK; ++l) {
        size_t o = (size_t)(l0 + l) * DI + d;
        float dv = delta[o];
        float xcv = bf2f(xcH[o]) + bf2f(xcL[o]);
        float dvx = dv * xcv;
        float yp = 0.f;
        #pragma unroll
        for (int j = 0; j < 8; j++) {
            float a = __expf(dv * negA[j]);
            h[j] = fmaf(a, h[j], dvx * BCs[l][half * 8 + j]);
            yp = fmaf(BCs[l][16 + half * 8 + j], h[j], yp);
        }
        yp += __shfl_xor(yp, 1);
        if (half == 0) {
            float yv = (yp + xcv * Dpv) * gate[o];
            u16 hq = f2bf(yv);
            yH[o] = hq;
            yL[o] = f2bf(yv - bf2f(hq));
        }
    }
}

extern "C" void kernel_launch(void* const* d_in, const int* in_sizes, int n_in,
                              void* d_out, int out_size, void* d_ws, size_t ws_size,
                              hipStream_t stream) {
    const float* x          = (const float*)d_in[0];
    const float* rms_w      = (const float*)d_in[1];
    const float* in_proj_w  = (const float*)d_in[2];
    const float* conv_w     = (const float*)d_in[3];
    const float* conv_b     = (const float*)d_in[4];
    const float* bcd_w      = (const float*)d_in[5];
    const float* dup_w      = (const float*)d_in[6];
    const float* dup_b      = (const float*)d_in[7];
    const float* lmA        = (const float*)d_in[8];
    const float* Dp         = (const float*)d_in[9];
    const float* out_proj_w = (const float*)d_in[10];
    float* out = (float*)d_out;
    char*  W   = (char*)d_ws;

    const size_t MB = 1ull << 20;
    // Region A: 0-16MB  : WiH/WiL -> delta
    u16*   WiH  = (u16*)(W + 0);
    u16*   WiL  = (u16*)(W + 8 * MB);
    float* delta= (float*)(W + 0);
    // Region B: 16-32MB : xs -> {part(12)+small wts} -> Sb(4) -> yH/yL(16)
    float* xs   = (float*)(W + 16 * MB);
    float* part = (float*)(W + 16 * MB);
    u16*   bwTH = (u16*)(W + 28 * MB);
    u16*   bwTL = (u16*)(W + 28 * MB + 384 * 1024);
    u16*   dwTH = (u16*)(W + 28 * MB + 768 * 1024);
    u16*   dwTL = (u16*)(W + 28 * MB + 1024 * 1024);
    u16*   bcdH = (u16*)(W + 28 * MB + 1280 * 1024);
    u16*   bcdL = (u16*)(W + 28 * MB + 1536 * 1024);
    float* Sb   = (float*)(W + 16 * MB);
    u16*   yH   = (u16*)(W + 16 * MB);
    u16*   yL   = (u16*)(W + 24 * MB);
    // Region C+D: 32-64MB : gate(16) + xcH/xcL(16) -> opart (32MB, split-K=4, post-scan3)
    float* gate = (float*)(W + 32 * MB);
    u16*   xcH  = (u16*)(W + 48 * MB);
    u16*   xcL  = (u16*)(W + 56 * MB);
    float* opart= (float*)(W + 32 * MB);
    // Region E: 64-72MB : xnH/xnL -> WoH/WoL
    u16*   xnH  = (u16*)(W + 64 * MB);
    u16*   xnL  = (u16*)(W + 68 * MB);
    u16*   WoH  = (u16*)(W + 64 * MB);
    u16*   WoL  = (u16*)(W + 68 * MB);
    // Region F: 72-77MB : bcd f32 + Pb (becomes Hinit)
    float* bcd  = (float*)(W + 72 * MB);
    float* Pb   = (float*)(W + 73 * MB);

    // 1. RMSNorm -> split bf16
    rmsnorm_split_k<<<Lseq, 256, 0, stream>>>(x, rms_w, xnH, xnL);
    // 2. in_proj_w -> WiT hi/lo
    wsplitT_k<<<dim3(4096 / 32, 1024 / 32), 256, 0, stream>>>(in_proj_w, 1024, 4096, WiH, WiL);
    // 3. in_proj: xs / gate  (128x128, pipelined dbuf)
    gemm_mfma3<128, 128, 4><<<dim3(4096 / 128, Lseq / 128), 256, 0, stream>>>(
        xnH, xnL, WiH, WiL, xs, gate, nullptr, Lseq, 2 * DI, Dmod);
    // 4. conv + silu -> xc split bf16
    conv_silu_k<<<dim3(DI / 256, Lseq), 256, 0, stream>>>(xs, conv_w, conv_b, xcH, xcL);
    // 5. combined prep: out_proj_w / bcd_w / dup_w (xn dead)
    wsplit3_k<<<2368, 256, 0, stream>>>(out_proj_w, bcd_w, dup_w,
                                        WoH, WoL, bwTH, bwTL, dwTH, dwTL);
    // 6. bcd = xc @ bcd_w (split-K MFMA + reduce)
    gemm_mfma3<128, 96, 5><<<dim3(1, Lseq / 128, SPLITK), 256, 0, stream>>>(
        xcH, xcL, bwTH, bwTL, part, nullptr, nullptr, Lseq, 96, DI);
    bcd_reduce_k<<<Lseq * 96 / 256, 256, 0, stream>>>(part, bcd, bcdH, bcdL);
    // 7. delta = softplus(bcd[:, :64] @ dup_w + dup_b)  (64x128 tile, 512 blocks)
    gemm_mfma3<64, 128, 2><<<dim3(DI / 128, Lseq / 64), 256, 0, stream>>>(
        bcdH, bcdL, dwTH, dwTL, delta, nullptr, dup_b, Lseq, DI, DRr);
    // 8-10. chunked selective scan
    scan1_k<<<dim3(16, NCHUNK), 256, 0, stream>>>(delta, xcH, xcL, bcd, lmA, Pb, Sb);
    scan2_k<<<dim3(DI * Nst / 256), 256, 0, stream>>>(Pb, Sb);
    scan3_k<<<dim3(16, NCHUNK), 256, 0, stream>>>(delta, xcH, xcL, bcd, lmA, Dp, gate, Pb, yH, yL);
    // 11. out_proj: 128x128 tile + split-K=4 (512 blocks), reduce + residual
    gemm_mfma3<128, 128, 5><<<dim3(Dmod / 128, Lseq / 128, OSPLIT), 256, 0, stream>>>(
        yH, yL, WoH, WoL, opart, nullptr, nullptr, Lseq, Dmod, DI);
    out_reduce_k<<<Lseq * Dmod / 1024, 256, 0, stream>>>(opart, x, out);
}

// Round 9
// 245.610 us; speedup vs baseline: 2.8996x; 1.0106x over previous
//
#include <hip/hip_runtime.h>
#include <hip/hip_bf16.h>
#include <math.h>

#define Lseq 2048
#define Dmod 1024
#define DI   2048
#define Nst  16
#define DRr  64
#define NCHUNK 32
#define LCHUNK 64
#define SPLITK 16
#define OSPLIT 4

typedef unsigned short u16;
typedef float  f32x4  __attribute__((ext_vector_type(4)));
typedef short  short8 __attribute__((ext_vector_type(8)));

__device__ __forceinline__ float sigmoidf_(float x) { return 1.f / (1.f + expf(-x)); }
__device__ __forceinline__ float softplusf_(float x) {
    return fmaxf(x, 0.f) + log1pf(expf(-fabsf(x)));
}
__device__ __forceinline__ u16 f2bf(float x) {
    union { float f; unsigned u; } v; v.f = x;
    unsigned r = (v.u + 0x7fffu + ((v.u >> 16) & 1u)) >> 16;
    return (u16)r;
}
__device__ __forceinline__ float bf2f(u16 h) {
    union { unsigned u; float f; } v; v.u = ((unsigned)h) << 16; return v.f;
}
__device__ __forceinline__ void async16(const void* g, void* l) {
    __builtin_amdgcn_global_load_lds((__attribute__((address_space(1))) void*)g,
                                     (__attribute__((address_space(3))) void*)l, 16, 0, 0);
}

struct __align__(8) u16x4 { u16 x, y, z, w; };

// ---------------- RMSNorm -> split bf16 hi/lo ----------------
__global__ __launch_bounds__(256) void rmsnorm_split_k(const float* __restrict__ x,
                                                       const float* __restrict__ w,
                                                       u16* __restrict__ xh,
                                                       u16* __restrict__ xl) {
    int row = blockIdx.x;
    int tid = threadIdx.x;
    float4 v = reinterpret_cast<const float4*>(x + (size_t)row * Dmod)[tid];
    float ss = v.x * v.x + v.y * v.y + v.z * v.z + v.w * v.w;
    #pragma unroll
    for (int m = 32; m >= 1; m >>= 1) ss += __shfl_xor(ss, m);
    __shared__ float s4[4];
    if ((tid & 63) == 0) s4[tid >> 6] = ss;
    __syncthreads();
    float tot = s4[0] + s4[1] + s4[2] + s4[3];
    float scale = rsqrtf(tot * (1.0f / Dmod) + 1e-5f);
    float4 wv = reinterpret_cast<const float4*>(w)[tid];
    float o[4] = {v.x * scale * wv.x, v.y * scale * wv.y,
                  v.z * scale * wv.z, v.w * scale * wv.w};
    u16x4 H, L;
    u16* hp = &H.x; u16* lp = &L.x;
    #pragma unroll
    for (int q = 0; q < 4; q++) {
        u16 h = f2bf(o[q]); hp[q] = h; lp[q] = f2bf(o[q] - bf2f(h));
    }
    reinterpret_cast<u16x4*>(xh + (size_t)row * Dmod)[tid] = H;
    reinterpret_cast<u16x4*>(xl + (size_t)row * Dmod)[tid] = L;
}

// ---------------- Weight transpose + split body ----------------
__device__ __forceinline__ void wsplit_body(const float* __restrict__ W, int R, int Cn,
                                            int bx, int by, float (*t)[33],
                                            u16* __restrict__ Th, u16* __restrict__ Tl) {
    int r0 = by * 32, c0 = bx * 32;
    int tr = threadIdx.x >> 3;
    int tc4 = (threadIdx.x & 7) * 4;
    float4 v = *reinterpret_cast<const float4*>(&W[(size_t)(r0 + tr) * Cn + c0 + tc4]);
    t[tr][tc4 + 0] = v.x; t[tr][tc4 + 1] = v.y;
    t[tr][tc4 + 2] = v.z; t[tr][tc4 + 3] = v.w;
    __syncthreads();
    u16x4 H, L;
    u16* hp = &H.x; u16* lp = &L.x;
    #pragma unroll
    for (int q = 0; q < 4; q++) {
        float xv = t[tc4 + q][tr];
        u16 h = f2bf(xv); hp[q] = h; lp[q] = f2bf(xv - bf2f(h));
    }
    size_t o = (size_t)(c0 + tr) * R + r0 + tc4;
    *reinterpret_cast<u16x4*>(&Th[o]) = H;
    *reinterpret_cast<u16x4*>(&Tl[o]) = L;
}

__global__ __launch_bounds__(256) void wsplitT_k(const float* __restrict__ W, int R, int Cn,
                                                 u16* __restrict__ Th, u16* __restrict__ Tl) {
    __shared__ float t[32][33];
    wsplit_body(W, R, Cn, blockIdx.x, blockIdx.y, t, Th, Tl);
}

// Combined prep for out_proj_w (2048 blk), bcd_w (192 blk), dup_w (128 blk)
__global__ __launch_bounds__(256) void wsplit3_k(const float* __restrict__ Wo,
                                                 const float* __restrict__ Wb,
                                                 const float* __restrict__ Wd,
                                                 u16* WoH, u16* WoL,
                                                 u16* bwTH, u16* bwTL,
                                                 u16* dwTH, u16* dwTL) {
    __shared__ float t[32][33];
    int b = blockIdx.x;
    if (b < 2048) {
        wsplit_body(Wo, 2048, 1024, b & 31, b >> 5, t, WoH, WoL);
    } else if (b < 2240) {
        int bb = b - 2048;
        wsplit_body(Wb, 2048, 96, bb % 3, bb / 3, t, bwTH, bwTL);
    } else {
        int bb = b - 2240;
        wsplit_body(Wd, 64, 2048, bb & 63, bb >> 6, t, dwTH, dwTL);
    }
}

// ---------------- Split-bf16 MFMA GEMM, dbuf pipeline + bank-swizzled staging ------
// C[M][N] = A[M][K] @ Bt[N][K]^T
// LDS tile rows are 64B (32 u16). Global source is pre-swizzled per-lane so linear
// global_load_lds lands global[r][cb^s(r)] at LDS[r][cb], s(r)=(r>>1)&3; the
// fragment read applies the same XOR -> 8-way bank conflict becomes 2-way (free).
// EPI: 2 C=softplus(acc+aux[col]); 4 dual in_proj; 5 split-K partial write.
template <int BM, int BN, int EPI>
__global__ __launch_bounds__(256) void gemm_mfma3(
    const u16* __restrict__ Ah, const u16* __restrict__ Al,
    const u16* __restrict__ Bh, const u16* __restrict__ Bl,
    float* __restrict__ C, float* __restrict__ C2, const float* __restrict__ aux,
    int M, int N, int K) {
    constexpr int BK = 32;
    constexpr int MF = BM / 32, NF = BN / 32;
    constexpr int CH_A = BM / 16, CH_B = BN / 16;
    __shared__ u16 AhT[2][BM][BK], AlT[2][BM][BK], BhT[2][BN][BK], BlT[2][BN][BK];
    const int tid = threadIdx.x, lane = tid & 63, wid = tid >> 6;
    const int wr = wid >> 1, wc = wid & 1;
    const int lr = lane & 15;
    const int sw = (lane >> 1) & 3;                      // = (lr>>1)&3 for all lanes
    const int lkq = ((lane >> 4) ^ sw) * 8;              // swizzled col-block (u16 idx)
    const int bm0 = blockIdx.y * BM, bn0 = blockIdx.x * BN;
    const int srow = lane >> 2;
    const int scol_ = ((lane & 3) ^ ((lane >> 3) & 3)) * 8;   // pre-swizzled source col

    int kbeg = 0, kend = K;
    if (EPI == 5) {
        int ks = K / gridDim.z;
        kbeg = blockIdx.z * ks;
        kend = kbeg + ks;
    }
    const int nt = (kend - kbeg) / BK;

    auto STAGE = [&](int buf, int k0) {
        int ci = 0;
        #pragma unroll
        for (int c = 0; c < CH_A; c++, ci++) if ((ci & 3) == wid) {
            size_t g = (size_t)(bm0 + c * 16 + srow) * K + (k0 + scol_);
            async16(Ah + g, (u16*)&AhT[buf][0][0] + c * 512 + lane * 8);
        }
        #pragma unroll
        for (int c = 0; c < CH_A; c++, ci++) if ((ci & 3) == wid) {
            size_t g = (size_t)(bm0 + c * 16 + srow) * K + (k0 + scol_);
            async16(Al + g, (u16*)&AlT[buf][0][0] + c * 512 + lane * 8);
        }
        #pragma unroll
        for (int c = 0; c < CH_B; c++, ci++) if ((ci & 3) == wid) {
            size_t g = (size_t)(bn0 + c * 16 + srow) * K + (k0 + scol_);
            async16(Bh + g, (u16*)&BhT[buf][0][0] + c * 512 + lane * 8);
        }
        #pragma unroll
        for (int c = 0; c < CH_B; c++, ci++) if ((ci & 3) == wid) {
            size_t g = (size_t)(bn0 + c * 16 + srow) * K + (k0 + scol_);
            async16(Bl + g, (u16*)&BlT[buf][0][0] + c * 512 + lane * 8);
        }
    };

    f32x4 acc[MF][NF];
    #pragma unroll
    for (int i = 0; i < MF; i++)
        #pragma unroll
        for (int j = 0; j < NF; j++) acc[i][j] = (f32x4){0.f, 0.f, 0.f, 0.f};

    STAGE(0, kbeg);
    asm volatile("s_waitcnt vmcnt(0)" ::: "memory");
    __builtin_amdgcn_s_barrier();

    for (int t = 0; t < nt; ++t) {
        const int cur = t & 1;
        if (t + 1 < nt) STAGE(cur ^ 1, kbeg + (t + 1) * BK);

        short8 ah[MF], al[MF], bh[NF], bl[NF];
        #pragma unroll
        for (int i = 0; i < MF; i++) {
            int r = wr * (MF * 16) + i * 16 + lr;
            ah[i] = *(const short8*)&AhT[cur][r][lkq];
            al[i] = *(const short8*)&AlT[cur][r][lkq];
        }
        #pragma unroll
        for (int j = 0; j < NF; j++) {
            int r = wc * (NF * 16) + j * 16 + lr;
            bh[j] = *(const short8*)&BhT[cur][r][lkq];
            bl[j] = *(const short8*)&BlT[cur][r][lkq];
        }
        asm volatile("s_waitcnt lgkmcnt(0)" ::: "memory");
        __builtin_amdgcn_sched_barrier(0);
        __builtin_amdgcn_s_setprio(1);
        #pragma unroll
        for (int i = 0; i < MF; i++)
            #pragma unroll
            for (int j = 0; j < NF; j++) {
                acc[i][j] = __builtin_amdgcn_mfma_f32_16x16x32_bf16(ah[i], bh[j], acc[i][j], 0, 0, 0);
                acc[i][j] = __builtin_amdgcn_mfma_f32_16x16x32_bf16(ah[i], bl[j], acc[i][j], 0, 0, 0);
                acc[i][j] = __builtin_amdgcn_mfma_f32_16x16x32_bf16(al[i], bh[j], acc[i][j], 0, 0, 0);
            }
        __builtin_amdgcn_s_setprio(0);
        if (t + 1 < nt) {
            asm volatile("s_waitcnt vmcnt(0)" ::: "memory");
            __builtin_amdgcn_s_barrier();
        }
    }

    float* Cp = C;
    if (EPI == 5) Cp = C + (size_t)blockIdx.z * M * N;
    #pragma unroll
    for (int i = 0; i < MF; i++)
        #pragma unroll
        for (int j = 0; j < NF; j++) {
            int rowg = bm0 + wr * (MF * 16) + i * 16 + (lane >> 4) * 4;
            int colg = bn0 + wc * (NF * 16) + j * 16 + lr;
            #pragma unroll
            for (int q = 0; q < 4; q++) {
                float v = acc[i][j][q];
                if (EPI == 5) {
                    Cp[(size_t)(rowg + q) * N + colg] = v;
                } else if (EPI == 2) {
                    C[(size_t)(rowg + q) * N + colg] = softplusf_(v + aux[colg]);
                } else if (EPI == 4) {
                    if (colg < DI) C[(size_t)(rowg + q) * DI + colg] = v;
                    else C2[(size_t)(rowg + q) * DI + (colg - DI)] = v * sigmoidf_(v);
                }
            }
        }
}

// ---------------- bcd split-K reduce ----------------
__global__ __launch_bounds__(256) void bcd_reduce_k(const float* __restrict__ partial,
                                                    float* __restrict__ bcd,
                                                    u16* __restrict__ bH,
                                                    u16* __restrict__ bL) {
    const int NT = Lseq * 96;
    int t = blockIdx.x * 256 + threadIdx.x;
    float s = 0.f;
    #pragma unroll
    for (int z = 0; z < SPLITK; z++) s += partial[(size_t)z * NT + t];
    bcd[t] = s;
    int col = t % 96, row = t / 96;
    if (col < DRr) {
        u16 h = f2bf(s);
        bH[(size_t)row * DRr + col] = h;
        bL[(size_t)row * DRr + col] = f2bf(s - bf2f(h));
    }
}

// ---------------- out split-K=4 reduce + residual: out = sum(p) + x ----------------
__global__ __launch_bounds__(256) void out_reduce_k(const float* __restrict__ part,
                                                    const float* __restrict__ x,
                                                    float* __restrict__ out) {
    int t = blockIdx.x * 256 + threadIdx.x;   // float4 index
    const size_t NT = (size_t)Lseq * Dmod;
    float4 xv = reinterpret_cast<const float4*>(x)[t];
    float4 o = xv;
    #pragma unroll
    for (int z = 0; z < OSPLIT; z++) {
        float4 p = reinterpret_cast<const float4*>(part + (size_t)z * NT)[t];
        o.x += p.x; o.y += p.y; o.z += p.z; o.w += p.w;
    }
    reinterpret_cast<float4*>(out)[t] = o;
}

// ---------------- Conv1d(K=4) + SiLU -> split bf16 ----------------
__global__ __launch_bounds__(256) void conv_silu_k(const float* __restrict__ xs,
                                                   const float* __restrict__ cw,
                                                   const float* __restrict__ cb,
                                                   u16* __restrict__ xcH,
                                                   u16* __restrict__ xcL) {
    int d = blockIdx.x * 256 + threadIdx.x;
    int l = blockIdx.y;
    float4 w = reinterpret_cast<const float4*>(cw)[d];
    float wk[4] = {w.x, w.y, w.z, w.w};
    float s = cb[d];
    #pragma unroll
    for (int k = 0; k < 4; k++) {
        int ls = l - 3 + k;
        if (ls >= 0) s = fmaf(xs[(size_t)ls * DI + d], wk[k], s);
    }
    float v = s * sigmoidf_(s);
    size_t o = (size_t)l * DI + d;
    u16 h = f2bf(v);
    xcH[o] = h;
    xcL[o] = f2bf(v - bf2f(h));
}

// ---------------- Scan pass 1: thread=(d,half), 8 states in registers ----------------
__global__ __launch_bounds__(256) void scan1_k(const float* __restrict__ delta,
                                               const u16* __restrict__ xcH,
                                               const u16* __restrict__ xcL,
                                               const float* __restrict__ bcd,
                                               const float* __restrict__ lmA,
                                               float* __restrict__ Pb,
                                               float* __restrict__ Sb) {
    __shared__ float Bs[LCHUNK][16];
    const int tid = threadIdx.x;
    const int d = (blockIdx.x * 256 + tid) >> 1;
    const int half = tid & 1;
    const int c = blockIdx.y;
    const int l0 = c * LCHUNK;
    {
        int row = tid >> 2, q = (tid & 3) * 4;
        float4 v = *reinterpret_cast<const float4*>(&bcd[(size_t)(l0 + row) * 96 + DRr + q]);
        *reinterpret_cast<float4*>(&Bs[row][q]) = v;
    }
    __syncthreads();
    float negA[8], h[8];
    #pragma unroll
    for (int j = 0; j < 8; j++) {
        negA[j] = -__expf(lmA[(size_t)d * Nst + half * 8 + j]);
        h[j] = 0.f;
    }
    float sdv = 0.f;
    for (int l = 0; l < LCHUNK; ++l) {
        size_t o = (size_t)(l0 + l) * DI + d;
        float dv = delta[o];
        float xcv = bf2f(xcH[o]) + bf2f(xcL[o]);
        sdv += dv;
        float dvx = dv * xcv;
        #pragma unroll
        for (int j = 0; j < 8; j++) {
            float a = __expf(dv * negA[j]);
            h[j] = fmaf(a, h[j], dvx * Bs[l][half * 8 + j]);
        }
    }
    size_t base = ((size_t)c * DI + d) * Nst + half * 8;
    #pragma unroll
    for (int j = 0; j < 8; j++) {
        Pb[base + j] = __expf(sdv * negA[j]);
        Sb[base + j] = h[j];
    }
}

// ---------------- Scan pass 2: combine in place (Pb -> Hinit) ----------------
__global__ __launch_bounds__(256) void scan2_k(float* __restrict__ PH,
                                               const float* __restrict__ Sb) {
    int t = blockIdx.x * 256 + threadIdx.x;
    float H = 0.f;
    for (int c = 0; c < NCHUNK; c++) {
        size_t idx = (size_t)c * (DI * Nst) + t;
        float P = PH[idx], S = Sb[idx];
        PH[idx] = H;
        H = S + P * H;
    }
}

// ---------------- Scan pass 3: rescan with init, emit gated y split bf16 ----------------
__global__ __launch_bounds__(256) void scan3_k(const float* __restrict__ delta,
                                               const u16* __restrict__ xcH,
                                               const u16* __restrict__ xcL,
                                               const float* __restrict__ bcd,
                                               const float* __restrict__ lmA,
                                               const float* __restrict__ Dp,
                                               const float* __restrict__ gate,
                                               const float* __restrict__ Hinit,
                                               u16* __restrict__ yH,
                                               u16* __restrict__ yL) {
    __shared__ float BCs[LCHUNK][32];
    const int tid = threadIdx.x;
    const int d = (blockIdx.x * 256 + tid) >> 1;
    const int half = tid & 1;
    const int c = blockIdx.y;
    const int l0 = c * LCHUNK;
    #pragma unroll
    for (int i = 0; i < 2; i++) {
        int idx = tid + 256 * i;
        int row = idx >> 3, q = (idx & 7) * 4;
        float4 v = *reinterpret_cast<const float4*>(&bcd[(size_t)(l0 + row) * 96 + DRr + q]);
        *reinterpret_cast<float4*>(&BCs[row][q]) = v;
    }
    __syncthreads();
    float negA[8], h[8];
    size_t hbase = ((size_t)c * DI + d) * Nst + half * 8;
    #pragma unroll
    for (int j = 0; j < 8; j++) {
        negA[j] = -__expf(lmA[(size_t)d * Nst + half * 8 + j]);
        h[j] = Hinit[hbase + j];
    }
    float Dpv = Dp[d];
    for (int l = 0; l < LCHUNK; ++l) {
        size_t o = (size_t)(l0 + l) * DI + d;
        float dv = delta[o];
        float xcv = bf2f(xcH[o]) + bf2f(xcL[o]);
        float dvx = dv * xcv;
        float yp = 0.f;
        #pragma unroll
        for (int j = 0; j < 8; j++) {
            float a = __expf(dv * negA[j]);
            h[j] = fmaf(a, h[j], dvx * BCs[l][half * 8 + j]);
            yp = fmaf(BCs[l][16 + half * 8 + j], h[j], yp);
        }
        yp += __shfl_xor(yp, 1);
        if (half == 0) {
            float yv = (yp + xcv * Dpv) * gate[o];
            u16 hq = f2bf(yv);
            yH[o] = hq;
            yL[o] = f2bf(yv - bf2f(hq));
        }
    }
}

extern "C" void kernel_launch(void* const* d_in, const int* in_sizes, int n_in,
                              void* d_out, int out_size, void* d_ws, size_t ws_size,
                              hipStream_t stream) {
    const float* x          = (const float*)d_in[0];
    const float* rms_w      = (const float*)d_in[1];
    const float* in_proj_w  = (const float*)d_in[2];
    const float* conv_w     = (const float*)d_in[3];
    const float* conv_b     = (const float*)d_in[4];
    const float* bcd_w      = (const float*)d_in[5];
    const float* dup_w      = (const float*)d_in[6];
    const float* dup_b      = (const float*)d_in[7];
    const float* lmA        = (const float*)d_in[8];
    const float* Dp         = (const float*)d_in[9];
    const float* out_proj_w = (const float*)d_in[10];
    float* out = (float*)d_out;
    char*  W   = (char*)d_ws;

    const size_t MB = 1ull << 20;
    // Region A: 0-16MB  : WiH/WiL -> delta
    u16*   WiH  = (u16*)(W + 0);
    u16*   WiL  = (u16*)(W + 8 * MB);
    float* delta= (float*)(W + 0);
    // Region B: 16-32MB : xs -> {part(12)+small wts} -> Sb(4) -> yH/yL(16)
    float* xs   = (float*)(W + 16 * MB);
    float* part = (float*)(W + 16 * MB);
    u16*   bwTH = (u16*)(W + 28 * MB);
    u16*   bwTL = (u16*)(W + 28 * MB + 384 * 1024);
    u16*   dwTH = (u16*)(W + 28 * MB + 768 * 1024);
    u16*   dwTL = (u16*)(W + 28 * MB + 1024 * 1024);
    u16*   bcdH = (u16*)(W + 28 * MB + 1280 * 1024);
    u16*   bcdL = (u16*)(W + 28 * MB + 1536 * 1024);
    float* Sb   = (float*)(W + 16 * MB);
    u16*   yH   = (u16*)(W + 16 * MB);
    u16*   yL   = (u16*)(W + 24 * MB);
    // Region C+D: 32-64MB : gate(16) + xcH/xcL(16) -> opart (32MB, split-K=4, post-scan3)
    float* gate = (float*)(W + 32 * MB);
    u16*   xcH  = (u16*)(W + 48 * MB);
    u16*   xcL  = (u16*)(W + 56 * MB);
    float* opart= (float*)(W + 32 * MB);
    // Region E: 64-72MB : xnH/xnL -> WoH/WoL
    u16*   xnH  = (u16*)(W + 64 * MB);
    u16*   xnL  = (u16*)(W + 68 * MB);
    u16*   WoH  = (u16*)(W + 64 * MB);
    u16*   WoL  = (u16*)(W + 68 * MB);
    // Region F: 72-77MB : bcd f32 + Pb (becomes Hinit)
    float* bcd  = (float*)(W + 72 * MB);
    float* Pb   = (float*)(W + 73 * MB);

    // 1. RMSNorm -> split bf16
    rmsnorm_split_k<<<Lseq, 256, 0, stream>>>(x, rms_w, xnH, xnL);
    // 2. in_proj_w -> WiT hi/lo
    wsplitT_k<<<dim3(4096 / 32, 1024 / 32), 256, 0, stream>>>(in_proj_w, 1024, 4096, WiH, WiL);
    // 3. in_proj: xs / gate  (128x128, dbuf + swizzle)
    gemm_mfma3<128, 128, 4><<<dim3(4096 / 128, Lseq / 128), 256, 0, stream>>>(
        xnH, xnL, WiH, WiL, xs, gate, nullptr, Lseq, 2 * DI, Dmod);
    // 4. conv + silu -> xc split bf16
    conv_silu_k<<<dim3(DI / 256, Lseq), 256, 0, stream>>>(xs, conv_w, conv_b, xcH, xcL);
    // 5. combined prep: out_proj_w / bcd_w / dup_w (xn dead)
    wsplit3_k<<<2368, 256, 0, stream>>>(out_proj_w, bcd_w, dup_w,
                                        WoH, WoL, bwTH, bwTL, dwTH, dwTL);
    // 6. bcd = xc @ bcd_w (split-K MFMA + reduce)
    gemm_mfma3<128, 96, 5><<<dim3(1, Lseq / 128, SPLITK), 256, 0, stream>>>(
        xcH, xcL, bwTH, bwTL, part, nullptr, nullptr, Lseq, 96, DI);
    bcd_reduce_k<<<Lseq * 96 / 256, 256, 0, stream>>>(part, bcd, bcdH, bcdL);
    // 7. delta = softplus(bcd[:, :64] @ dup_w + dup_b)  (64x128 tile, 512 blocks)
    gemm_mfma3<64, 128, 2><<<dim3(DI / 128, Lseq / 64), 256, 0, stream>>>(
        bcdH, bcdL, dwTH, dwTL, delta, nullptr, dup_b, Lseq, DI, DRr);
    // 8-10. chunked selective scan
    scan1_k<<<dim3(16, NCHUNK), 256, 0, stream>>>(delta, xcH, xcL, bcd, lmA, Pb, Sb);
    scan2_k<<<dim3(DI * Nst / 256), 256, 0, stream>>>(Pb, Sb);
    scan3_k<<<dim3(16, NCHUNK), 256, 0, stream>>>(delta, xcH, xcL, bcd, lmA, Dp, gate, Pb, yH, yL);
    // 11. out_proj: 128x128 tile + split-K=4 (512 blocks), reduce + residual
    gemm_mfma3<128, 128, 5><<<dim3(Dmod / 128, Lseq / 128, OSPLIT), 256, 0, stream>>>(
        yH, yL, WoH, WoL, opart, nullptr, nullptr, Lseq, Dmod, DI);
    out_reduce_k<<<Lseq * Dmod / 1024, 256, 0, stream>>>(opart, x, out);
}

// Round 10
// 238.195 us; speedup vs baseline: 2.9899x; 1.0311x over previous
//
#include <hip/hip_runtime.h>
#include <hip/hip_bf16.h>
#include <math.h>

#define Lseq 2048
#define Dmod 1024
#define DI   2048
#define Nst  16
#define DRr  64
#define NCHUNK 32
#define LCHUNK 64
#define SPLITK 16
#define OSPLIT 4

typedef unsigned short u16;
typedef float  f32x4  __attribute__((ext_vector_type(4)));
typedef short  short8 __attribute__((ext_vector_type(8)));

__device__ __forceinline__ float sigmoidf_(float x) { return 1.f / (1.f + expf(-x)); }
__device__ __forceinline__ float softplusf_(float x) {
    return fmaxf(x, 0.f) + log1pf(expf(-fabsf(x)));
}
__device__ __forceinline__ u16 f2bf(float x) {
    union { float f; unsigned u; } v; v.f = x;
    unsigned r = (v.u + 0x7fffu + ((v.u >> 16) & 1u)) >> 16;
    return (u16)r;
}
__device__ __forceinline__ float bf2f(u16 h) {
    union { unsigned u; float f; } v; v.u = ((unsigned)h) << 16; return v.f;
}
__device__ __forceinline__ void async16(const void* g, void* l) {
    __builtin_amdgcn_global_load_lds((__attribute__((address_space(1))) void*)g,
                                     (__attribute__((address_space(3))) void*)l, 16, 0, 0);
}
template <int N> __device__ __forceinline__ void vmwait() {
    if constexpr (N == 0)      asm volatile("s_waitcnt vmcnt(0)" ::: "memory");
    else if constexpr (N == 6) asm volatile("s_waitcnt vmcnt(6)" ::: "memory");
    else if constexpr (N == 7) asm volatile("s_waitcnt vmcnt(7)" ::: "memory");
    else                       asm volatile("s_waitcnt vmcnt(8)" ::: "memory");
}

struct __align__(8) u16x4 { u16 x, y, z, w; };

// ---------------- Weight transpose + split body ----------------
__device__ __forceinline__ void wsplit_body(const float* __restrict__ W, int R, int Cn,
                                            int bx, int by, float (*t)[33],
                                            u16* __restrict__ Th, u16* __restrict__ Tl) {
    int r0 = by * 32, c0 = bx * 32;
    int tr = threadIdx.x >> 3;
    int tc4 = (threadIdx.x & 7) * 4;
    float4 v = *reinterpret_cast<const float4*>(&W[(size_t)(r0 + tr) * Cn + c0 + tc4]);
    t[tr][tc4 + 0] = v.x; t[tr][tc4 + 1] = v.y;
    t[tr][tc4 + 2] = v.z; t[tr][tc4 + 3] = v.w;
    __syncthreads();
    u16x4 H, L;
    u16* hp = &H.x; u16* lp = &L.x;
    #pragma unroll
    for (int q = 0; q < 4; q++) {
        float xv = t[tc4 + q][tr];
        u16 h = f2bf(xv); hp[q] = h; lp[q] = f2bf(xv - bf2f(h));
    }
    size_t o = (size_t)(c0 + tr) * R + r0 + tc4;
    *reinterpret_cast<u16x4*>(&Th[o]) = H;
    *reinterpret_cast<u16x4*>(&Tl[o]) = L;
}

// ---------------- prep1: rmsnorm rows (b<2048) + in_proj_w transpose (b>=2048) ------
__global__ __launch_bounds__(256) void prep1_k(const float* __restrict__ x,
                                               const float* __restrict__ rms_w,
                                               u16* __restrict__ xnH, u16* __restrict__ xnL,
                                               const float* __restrict__ Wi,
                                               u16* __restrict__ WiH, u16* __restrict__ WiL) {
    __shared__ float t[32][33];
    __shared__ float s4[4];
    int b = blockIdx.x;
    if (b < 2048) {
        int row = b, tid = threadIdx.x;
        float4 v = reinterpret_cast<const float4*>(x + (size_t)row * Dmod)[tid];
        float ss = v.x * v.x + v.y * v.y + v.z * v.z + v.w * v.w;
        #pragma unroll
        for (int m = 32; m >= 1; m >>= 1) ss += __shfl_xor(ss, m);
        if ((tid & 63) == 0) s4[tid >> 6] = ss;
        __syncthreads();
        float tot = s4[0] + s4[1] + s4[2] + s4[3];
        float scale = rsqrtf(tot * (1.0f / Dmod) + 1e-5f);
        float4 wv = reinterpret_cast<const float4*>(rms_w)[tid];
        float o[4] = {v.x * scale * wv.x, v.y * scale * wv.y,
                      v.z * scale * wv.z, v.w * scale * wv.w};
        u16x4 H, L;
        u16* hp = &H.x; u16* lp = &L.x;
        #pragma unroll
        for (int q = 0; q < 4; q++) {
            u16 h = f2bf(o[q]); hp[q] = h; lp[q] = f2bf(o[q] - bf2f(h));
        }
        reinterpret_cast<u16x4*>(xnH + (size_t)row * Dmod)[tid] = H;
        reinterpret_cast<u16x4*>(xnL + (size_t)row * Dmod)[tid] = L;
    } else {
        int bb = b - 2048;                 // in_proj_w: (1024 x 4096), grid (128 x 32)
        wsplit_body(Wi, 1024, 4096, bb & 127, bb >> 7, t, WiH, WiL);
    }
}

// Combined prep for out_proj_w (2048 blk), bcd_w (192 blk), dup_w (128 blk)
__global__ __launch_bounds__(256) void wsplit3_k(const float* __restrict__ Wo,
                                                 const float* __restrict__ Wb,
                                                 const float* __restrict__ Wd,
                                                 u16* WoH, u16* WoL,
                                                 u16* bwTH, u16* bwTL,
                                                 u16* dwTH, u16* dwTL) {
    __shared__ float t[32][33];
    int b = blockIdx.x;
    if (b < 2048) {
        wsplit_body(Wo, 2048, 1024, b & 31, b >> 5, t, WoH, WoL);
    } else if (b < 2240) {
        int bb = b - 2048;
        wsplit_body(Wb, 2048, 96, bb % 3, bb / 3, t, bwTH, bwTL);
    } else {
        int bb = b - 2240;
        wsplit_body(Wd, 64, 2048, bb & 63, bb >> 6, t, dwTH, dwTL);
    }
}

// ---------------- Split-bf16 MFMA GEMM, depth-2 pipeline, counted vmcnt, swizzled ---
// C[M][N] = A[M][K] @ Bt[N][K]^T
// EPI: 2 C=softplus(acc+aux[col]); 4 dual in_proj; 5 split-K partial write.
template <int BM, int BN, int EPI>
__global__ __launch_bounds__(256) void gemm_mfma3(
    const u16* __restrict__ Ah, const u16* __restrict__ Al,
    const u16* __restrict__ Bh, const u16* __restrict__ Bl,
    float* __restrict__ C, float* __restrict__ C2, const float* __restrict__ aux,
    int M, int N, int K) {
    constexpr int BK = 32;
    constexpr int MF = BM / 32, NF = BN / 32;
    constexpr int CH_A = BM / 16, CH_B = BN / 16;
    constexpr int NLD = (2 * CH_A + 2 * CH_B) / 4;   // async16 per wave per STAGE
    __shared__ u16 AhT[2][BM][BK], AlT[2][BM][BK], BhT[2][BN][BK], BlT[2][BN][BK];
    const int tid = threadIdx.x, lane = tid & 63, wid = tid >> 6;
    const int wr = wid >> 1, wc = wid & 1;
    const int lr = lane & 15;
    const int sw = (lane >> 1) & 3;
    const int lkq = ((lane >> 4) ^ sw) * 8;              // swizzled read col-block
    const int bm0 = blockIdx.y * BM, bn0 = blockIdx.x * BN;
    const int srow = lane >> 2;
    const int scol_ = ((lane & 3) ^ ((lane >> 3) & 3)) * 8;   // pre-swizzled source col

    int kbeg = 0, kend = K;
    if (EPI == 5) {
        int ks = K / gridDim.z;
        kbeg = blockIdx.z * ks;
        kend = kbeg + ks;
    }
    const int nt = (kend - kbeg) / BK;

    auto STAGE = [&](int buf, int k0) {
        int ci = 0;
        #pragma unroll
        for (int c = 0; c < CH_A; c++, ci++) if ((ci & 3) == wid) {
            size_t g = (size_t)(bm0 + c * 16 + srow) * K + (k0 + scol_);
            async16(Ah + g, (u16*)&AhT[buf][0][0] + c * 512 + lane * 8);
        }
        #pragma unroll
        for (int c = 0; c < CH_A; c++, ci++) if ((ci & 3) == wid) {
            size_t g = (size_t)(bm0 + c * 16 + srow) * K + (k0 + scol_);
            async16(Al + g, (u16*)&AlT[buf][0][0] + c * 512 + lane * 8);
        }
        #pragma unroll
        for (int c = 0; c < CH_B; c++, ci++) if ((ci & 3) == wid) {
            size_t g = (size_t)(bn0 + c * 16 + srow) * K + (k0 + scol_);
            async16(Bh + g, (u16*)&BhT[buf][0][0] + c * 512 + lane * 8);
        }
        #pragma unroll
        for (int c = 0; c < CH_B; c++, ci++) if ((ci & 3) == wid) {
            size_t g = (size_t)(bn0 + c * 16 + srow) * K + (k0 + scol_);
            async16(Bl + g, (u16*)&BlT[buf][0][0] + c * 512 + lane * 8);
        }
    };

    f32x4 acc[MF][NF];
    #pragma unroll
    for (int i = 0; i < MF; i++)
        #pragma unroll
        for (int j = 0; j < NF; j++) acc[i][j] = (f32x4){0.f, 0.f, 0.f, 0.f};

    // prologue: two tiles in flight
    STAGE(0, kbeg);
    if (nt > 1) STAGE(1, kbeg + BK);

    for (int t = 0; t < nt; ++t) {
        const int cur = t & 1;
        // retire tile t's loads (issued >=1.5 K-steps ago); keep tile t+1 in flight
        if (t < nt - 1) vmwait<NLD>(); else vmwait<0>();
        __builtin_amdgcn_s_barrier();          // tile t fully resident (all waves)

        short8 ah[MF], al[MF], bh[NF], bl[NF];
        #pragma unroll
        for (int i = 0; i < MF; i++) {
            int r = wr * (MF * 16) + i * 16 + lr;
            ah[i] = *(const short8*)&AhT[cur][r][lkq];
            al[i] = *(const short8*)&AlT[cur][r][lkq];
        }
        #pragma unroll
        for (int j = 0; j < NF; j++) {
            int r = wc * (NF * 16) + j * 16 + lr;
            bh[j] = *(const short8*)&BhT[cur][r][lkq];
            bl[j] = *(const short8*)&BlT[cur][r][lkq];
        }
        asm volatile("s_waitcnt lgkmcnt(0)" ::: "memory");
        __builtin_amdgcn_sched_barrier(0);
        __builtin_amdgcn_s_barrier();          // all waves done reading buf[cur]
        if (t + 2 < nt) STAGE(cur, kbeg + (t + 2) * BK);   // reuse freed buffer

        __builtin_amdgcn_s_setprio(1);
        #pragma unroll
        for (int i = 0; i < MF; i++)
            #pragma unroll
            for (int j = 0; j < NF; j++) {
                acc[i][j] = __builtin_amdgcn_mfma_f32_16x16x32_bf16(ah[i], bh[j], acc[i][j], 0, 0, 0);
                acc[i][j] = __builtin_amdgcn_mfma_f32_16x16x32_bf16(ah[i], bl[j], acc[i][j], 0, 0, 0);
                acc[i][j] = __builtin_amdgcn_mfma_f32_16x16x32_bf16(al[i], bh[j], acc[i][j], 0, 0, 0);
            }
        __builtin_amdgcn_s_setprio(0);
    }

    float* Cp = C;
    if (EPI == 5) Cp = C + (size_t)blockIdx.z * M * N;
    #pragma unroll
    for (int i = 0; i < MF; i++)
        #pragma unroll
        for (int j = 0; j < NF; j++) {
            int rowg = bm0 + wr * (MF * 16) + i * 16 + (lane >> 4) * 4;
            int colg = bn0 + wc * (NF * 16) + j * 16 + lr;
            #pragma unroll
            for (int q = 0; q < 4; q++) {
                float v = acc[i][j][q];
                if (EPI == 5) {
                    Cp[(size_t)(rowg + q) * N + colg] = v;
                } else if (EPI == 2) {
                    C[(size_t)(rowg + q) * N + colg] = softplusf_(v + aux[colg]);
                } else if (EPI == 4) {
                    if (colg < DI) C[(size_t)(rowg + q) * DI + colg] = v;
                    else C2[(size_t)(rowg + q) * DI + (colg - DI)] = v * sigmoidf_(v);
                }
            }
        }
}

// ---------------- bcd split-K reduce ----------------
__global__ __launch_bounds__(256) void bcd_reduce_k(const float* __restrict__ partial,
                                                    float* __restrict__ bcd,
                                                    u16* __restrict__ bH,
                                                    u16* __restrict__ bL) {
    const int NT = Lseq * 96;
    int t = blockIdx.x * 256 + threadIdx.x;
    float s = 0.f;
    #pragma unroll
    for (int z = 0; z < SPLITK; z++) s += partial[(size_t)z * NT + t];
    bcd[t] = s;
    int col = t % 96, row = t / 96;
    if (col < DRr) {
        u16 h = f2bf(s);
        bH[(size_t)row * DRr + col] = h;
        bL[(size_t)row * DRr + col] = f2bf(s - bf2f(h));
    }
}

// ---------------- out split-K=4 reduce + residual ----------------
__global__ __launch_bounds__(256) void out_reduce_k(const float* __restrict__ part,
                                                    const float* __restrict__ x,
                                                    float* __restrict__ out) {
    int t = blockIdx.x * 256 + threadIdx.x;
    const size_t NT = (size_t)Lseq * Dmod;
    float4 xv = reinterpret_cast<const float4*>(x)[t];
    float4 o = xv;
    #pragma unroll
    for (int z = 0; z < OSPLIT; z++) {
        float4 p = reinterpret_cast<const float4*>(part + (size_t)z * NT)[t];
        o.x += p.x; o.y += p.y; o.z += p.z; o.w += p.w;
    }
    reinterpret_cast<float4*>(out)[t] = o;
}

// ---------------- Conv1d(K=4)+SiLU, rolling window: block = 256 d x 32 l ----------
__global__ __launch_bounds__(256) void conv_silu_k(const float* __restrict__ xs,
                                                   const float* __restrict__ cw,
                                                   const float* __restrict__ cb,
                                                   u16* __restrict__ xcH,
                                                   u16* __restrict__ xcL) {
    int d = blockIdx.x * 256 + threadIdx.x;
    int l0 = blockIdx.y * 32;
    float4 w = reinterpret_cast<const float4*>(cw)[d];
    float b = cb[d];
    float p0 = 0.f, p1 = 0.f, p2 = 0.f;
    if (l0 > 0) {
        p0 = xs[(size_t)(l0 - 3) * DI + d];
        p1 = xs[(size_t)(l0 - 2) * DI + d];
        p2 = xs[(size_t)(l0 - 1) * DI + d];
    }
    for (int l = l0; l < l0 + 32; ++l) {
        float c = xs[(size_t)l * DI + d];
        float s = b;
        s = fmaf(p0, w.x, s);
        s = fmaf(p1, w.y, s);
        s = fmaf(p2, w.z, s);
        s = fmaf(c,  w.w, s);
        float v = s * sigmoidf_(s);
        size_t o = (size_t)l * DI + d;
        u16 h = f2bf(v);
        xcH[o] = h;
        xcL[o] = f2bf(v - bf2f(h));
        p0 = p1; p1 = p2; p2 = c;
    }
}

// ---------------- Scan pass 1 ----------------
__global__ __launch_bounds__(256) void scan1_k(const float* __restrict__ delta,
                                               const u16* __restrict__ xcH,
                                               const u16* __restrict__ xcL,
                                               const float* __restrict__ bcd,
                                               const float* __restrict__ lmA,
                                               float* __restrict__ Pb,
                                               float* __restrict__ Sb) {
    __shared__ float Bs[LCHUNK][16];
    const int tid = threadIdx.x;
    const int d = (blockIdx.x * 256 + tid) >> 1;
    const int half = tid & 1;
    const int c = blockIdx.y;
    const int l0 = c * LCHUNK;
    {
        int row = tid >> 2, q = (tid & 3) * 4;
        float4 v = *reinterpret_cast<const float4*>(&bcd[(size_t)(l0 + row) * 96 + DRr + q]);
        *reinterpret_cast<float4*>(&Bs[row][q]) = v;
    }
    __syncthreads();
    float negA[8], h[8];
    #pragma unroll
    for (int j = 0; j < 8; j++) {
        negA[j] = -__expf(lmA[(size_t)d * Nst + half * 8 + j]);
        h[j] = 0.f;
    }
    float sdv = 0.f;
    for (int l = 0; l < LCHUNK; ++l) {
        size_t o = (size_t)(l0 + l) * DI + d;
        float dv = delta[o];
        float xcv = bf2f(xcH[o]) + bf2f(xcL[o]);
        sdv += dv;
        float dvx = dv * xcv;
        #pragma unroll
        for (int j = 0; j < 8; j++) {
            float a = __expf(dv * negA[j]);
            h[j] = fmaf(a, h[j], dvx * Bs[l][half * 8 + j]);
        }
    }
    size_t base = ((size_t)c * DI + d) * Nst + half * 8;
    #pragma unroll
    for (int j = 0; j < 8; j++) {
        Pb[base + j] = __expf(sdv * negA[j]);
        Sb[base + j] = h[j];
    }
}

// ---------------- Scan pass 2: combine in place (Pb -> Hinit) ----------------
__global__ __launch_bounds__(256) void scan2_k(float* __restrict__ PH,
                                               const float* __restrict__ Sb) {
    int t = blockIdx.x * 256 + threadIdx.x;
    float H = 0.f;
    for (int c = 0; c < NCHUNK; c++) {
        size_t idx = (size_t)c * (DI * Nst) + t;
        float P = PH[idx], S = Sb[idx];
        PH[idx] = H;
        H = S + P * H;
    }
}

// ---------------- Scan pass 3 ----------------
__global__ __launch_bounds__(256) void scan3_k(const float* __restrict__ delta,
                                               const u16* __restrict__ xcH,
                                               const u16* __restrict__ xcL,
                                               const float* __restrict__ bcd,
                                               const float* __restrict__ lmA,
                                               const float* __restrict__ Dp,
                                               const float* __restrict__ gate,
                                               const float* __restrict__ Hinit,
                                               u16* __restrict__ yH,
                                               u16* __restrict__ yL) {
    __shared__ float BCs[LCHUNK][32];
    const int tid = threadIdx.x;
    const int d = (blockIdx.x * 256 + tid) >> 1;
    const int half = tid & 1;
    const int c = blockIdx.y;
    const int l0 = c * LCHUNK;
    #pragma unroll
    for (int i = 0; i < 2; i++) {
        int idx = tid + 256 * i;
        int row = idx >> 3, q = (idx & 7) * 4;
        float4 v = *reinterpret_cast<const float4*>(&bcd[(size_t)(l0 + row) * 96 + DRr + q]);
        *reinterpret_cast<float4*>(&BCs[row][q]) = v;
    }
    __syncthreads();
    float negA[8], h[8];
    size_t hbase = ((size_t)c * DI + d) * Nst + half * 8;
    #pragma unroll
    for (int j = 0; j < 8; j++) {
        negA[j] = -__expf(lmA[(size_t)d * Nst + half * 8 + j]);
        h[j] = Hinit[hbase + j];
    }
    float Dpv = Dp[d];
    for (int l = 0; l < LCHUNK; ++l) {
        size_t o = (size_t)(l0 + l) * DI + d;
        float dv = delta[o];
        float xcv = bf2f(xcH[o]) + bf2f(xcL[o]);
        float dvx = dv * xcv;
        float yp = 0.f;
        #pragma unroll
        for (int j = 0; j < 8; j++) {
            float a = __expf(dv * negA[j]);
            h[j] = fmaf(a, h[j], dvx * BCs[l][half * 8 + j]);
            yp = fmaf(BCs[l][16 + half * 8 + j], h[j], yp);
        }
        yp += __shfl_xor(yp, 1);
        if (half == 0) {
            float yv = (yp + xcv * Dpv) * gate[o];
            u16 hq = f2bf(yv);
            yH[o] = hq;
            yL[o] = f2bf(yv - bf2f(hq));
        }
    }
}

extern "C" void kernel_launch(void* const* d_in, const int* in_sizes, int n_in,
                              void* d_out, int out_size, void* d_ws, size_t ws_size,
                              hipStream_t stream) {
    const float* x          = (const float*)d_in[0];
    const float* rms_w      = (const float*)d_in[1];
    const float* in_proj_w  = (const float*)d_in[2];
    const float* conv_w     = (const float*)d_in[3];
    const float* conv_b     = (const float*)d_in[4];
    const float* bcd_w      = (const float*)d_in[5];
    const float* dup_w      = (const float*)d_in[6];
    const float* dup_b      = (const float*)d_in[7];
    const float* lmA        = (const float*)d_in[8];
    const float* Dp         = (const float*)d_in[9];
    const float* out_proj_w = (const float*)d_in[10];
    float* out = (float*)d_out;
    char*  W   = (char*)d_ws;

    const size_t MB = 1ull << 20;
    // Region A: 0-16MB  : WiH/WiL -> delta
    u16*   WiH  = (u16*)(W + 0);
    u16*   WiL  = (u16*)(W + 8 * MB);
    float* delta= (float*)(W + 0);
    // Region B: 16-32MB : xs -> {part(12)+small wts} -> Sb(4) -> yH/yL(16)
    float* xs   = (float*)(W + 16 * MB);
    float* part = (float*)(W + 16 * MB);
    u16*   bwTH = (u16*)(W + 28 * MB);
    u16*   bwTL = (u16*)(W + 28 * MB + 384 * 1024);
    u16*   dwTH = (u16*)(W + 28 * MB + 768 * 1024);
    u16*   dwTL = (u16*)(W + 28 * MB + 1024 * 1024);
    u16*   bcdH = (u16*)(W + 28 * MB + 1280 * 1024);
    u16*   bcdL = (u16*)(W + 28 * MB + 1536 * 1024);
    float* Sb   = (float*)(W + 16 * MB);
    u16*   yH   = (u16*)(W + 16 * MB);
    u16*   yL   = (u16*)(W + 24 * MB);
    // Region C+D: 32-64MB : gate(16) + xcH/xcL(16) -> opart (32MB, post-scan3)
    float* gate = (float*)(W + 32 * MB);
    u16*   xcH  = (u16*)(W + 48 * MB);
    u16*   xcL  = (u16*)(W + 56 * MB);
    float* opart= (float*)(W + 32 * MB);
    // Region E: 64-72MB : xnH/xnL -> WoH/WoL
    u16*   xnH  = (u16*)(W + 64 * MB);
    u16*   xnL  = (u16*)(W + 68 * MB);
    u16*   WoH  = (u16*)(W + 64 * MB);
    u16*   WoL  = (u16*)(W + 68 * MB);
    // Region F: 72-77MB : bcd f32 + Pb (becomes Hinit)
    float* bcd  = (float*)(W + 72 * MB);
    float* Pb   = (float*)(W + 73 * MB);

    // 1. fused: RMSNorm + in_proj_w transpose/split
    prep1_k<<<2048 + 4096, 256, 0, stream>>>(x, rms_w, xnH, xnL, in_proj_w, WiH, WiL);
    // 2. in_proj: xs / gate  (128x128, depth-2 pipeline)
    gemm_mfma3<128, 128, 4><<<dim3(4096 / 128, Lseq / 128), 256, 0, stream>>>(
        xnH, xnL, WiH, WiL, xs, gate, nullptr, Lseq, 2 * DI, Dmod);
    // 3. conv + silu -> xc split bf16 (rolling window)
    conv_silu_k<<<dim3(DI / 256, Lseq / 32), 256, 0, stream>>>(xs, conv_w, conv_b, xcH, xcL);
    // 4. combined prep: out_proj_w / bcd_w / dup_w (xn dead)
    wsplit3_k<<<2368, 256, 0, stream>>>(out_proj_w, bcd_w, dup_w,
                                        WoH, WoL, bwTH, bwTL, dwTH, dwTL);
    // 5. bcd = xc @ bcd_w (split-K MFMA + reduce)
    gemm_mfma3<128, 96, 5><<<dim3(1, Lseq / 128, SPLITK), 256, 0, stream>>>(
        xcH, xcL, bwTH, bwTL, part, nullptr, nullptr, Lseq, 96, DI);
    bcd_reduce_k<<<Lseq * 96 / 256, 256, 0, stream>>>(part, bcd, bcdH, bcdL);
    // 6. delta = softplus(bcd[:, :64] @ dup_w + dup_b)
    gemm_mfma3<64, 128, 2><<<dim3(DI / 128, Lseq / 64), 256, 0, stream>>>(
        bcdH, bcdL, dwTH, dwTL, delta, nullptr, dup_b, Lseq, DI, DRr);
    // 7-9. chunked selective scan
    scan1_k<<<dim3(16, NCHUNK), 256, 0, stream>>>(delta, xcH, xcL, bcd, lmA, Pb, Sb);
    scan2_k<<<dim3(DI * Nst / 256), 256, 0, stream>>>(Pb, Sb);
    scan3_k<<<dim3(16, NCHUNK), 256, 0, stream>>>(delta, xcH, xcL, bcd, lmA, Dp, gate, Pb, yH, yL);
    // 10. out_proj: 128x128 + split-K=4, reduce + residual
    gemm_mfma3<128, 128, 5><<<dim3(Dmod / 128, Lseq / 128, OSPLIT), 256, 0, stream>>>(
        yH, yL, WoH, WoL, opart, nullptr, nullptr, Lseq, Dmod, DI);
    out_reduce_k<<<Lseq * Dmod / 1024, 256, 0, stream>>>(opart, x, out);
}

// Round 11
// 237.283 us; speedup vs baseline: 3.0014x; 1.0038x over previous
//
#include <hip/hip_runtime.h>
#include <hip/hip_bf16.h>
#include <math.h>

#define Lseq 2048
#define Dmod 1024
#define DI   2048
#define Nst  16
#define DRr  64
#define NCHUNK 32
#define LCHUNK 64
#define SPLITK 16
#define OSPLIT 4

typedef unsigned short u16;
typedef float  f32x4  __attribute__((ext_vector_type(4)));
typedef short  short8 __attribute__((ext_vector_type(8)));

__device__ __forceinline__ float sigmoidf_(float x) { return 1.f / (1.f + expf(-x)); }
__device__ __forceinline__ float softplusf_(float x) {
    return fmaxf(x, 0.f) + log1pf(expf(-fabsf(x)));
}
__device__ __forceinline__ u16 f2bf(float x) {
    union { float f; unsigned u; } v; v.f = x;
    unsigned r = (v.u + 0x7fffu + ((v.u >> 16) & 1u)) >> 16;
    return (u16)r;
}
__device__ __forceinline__ float bf2f(u16 h) {
    union { unsigned u; float f; } v; v.u = ((unsigned)h) << 16; return v.f;
}
__device__ __forceinline__ void async16(const void* g, void* l) {
    __builtin_amdgcn_global_load_lds((__attribute__((address_space(1))) void*)g,
                                     (__attribute__((address_space(3))) void*)l, 16, 0, 0);
}

struct __align__(8) u16x4 { u16 x, y, z, w; };

// ---------------- Weight transpose + split body ----------------
__device__ __forceinline__ void wsplit_body(const float* __restrict__ W, int R, int Cn,
                                            int bx, int by, float (*t)[33],
                                            u16* __restrict__ Th, u16* __restrict__ Tl) {
    int r0 = by * 32, c0 = bx * 32;
    int tr = threadIdx.x >> 3;
    int tc4 = (threadIdx.x & 7) * 4;
    float4 v = *reinterpret_cast<const float4*>(&W[(size_t)(r0 + tr) * Cn + c0 + tc4]);
    t[tr][tc4 + 0] = v.x; t[tr][tc4 + 1] = v.y;
    t[tr][tc4 + 2] = v.z; t[tr][tc4 + 3] = v.w;
    __syncthreads();
    u16x4 H, L;
    u16* hp = &H.x; u16* lp = &L.x;
    #pragma unroll
    for (int q = 0; q < 4; q++) {
        float xv = t[tc4 + q][tr];
        u16 h = f2bf(xv); hp[q] = h; lp[q] = f2bf(xv - bf2f(h));
    }
    size_t o = (size_t)(c0 + tr) * R + r0 + tc4;
    *reinterpret_cast<u16x4*>(&Th[o]) = H;
    *reinterpret_cast<u16x4*>(&Tl[o]) = L;
}

// ---------------- prep1: rmsnorm rows (b<2048) + in_proj_w transpose (b>=2048) ------
__global__ __launch_bounds__(256) void prep1_k(const float* __restrict__ x,
                                               const float* __restrict__ rms_w,
                                               u16* __restrict__ xnH, u16* __restrict__ xnL,
                                               const float* __restrict__ Wi,
                                               u16* __restrict__ WiH, u16* __restrict__ WiL) {
    __shared__ float t[32][33];
    __shared__ float s4[4];
    int b = blockIdx.x;
    if (b < 2048) {
        int row = b, tid = threadIdx.x;
        float4 v = reinterpret_cast<const float4*>(x + (size_t)row * Dmod)[tid];
        float ss = v.x * v.x + v.y * v.y + v.z * v.z + v.w * v.w;
        #pragma unroll
        for (int m = 32; m >= 1; m >>= 1) ss += __shfl_xor(ss, m);
        if ((tid & 63) == 0) s4[tid >> 6] = ss;
        __syncthreads();
        float tot = s4[0] + s4[1] + s4[2] + s4[3];
        float scale = rsqrtf(tot * (1.0f / Dmod) + 1e-5f);
        float4 wv = reinterpret_cast<const float4*>(rms_w)[tid];
        float o[4] = {v.x * scale * wv.x, v.y * scale * wv.y,
                      v.z * scale * wv.z, v.w * scale * wv.w};
        u16x4 H, L;
        u16* hp = &H.x; u16* lp = &L.x;
        #pragma unroll
        for (int q = 0; q < 4; q++) {
            u16 h = f2bf(o[q]); hp[q] = h; lp[q] = f2bf(o[q] - bf2f(h));
        }
        reinterpret_cast<u16x4*>(xnH + (size_t)row * Dmod)[tid] = H;
        reinterpret_cast<u16x4*>(xnL + (size_t)row * Dmod)[tid] = L;
    } else {
        int bb = b - 2048;                 // in_proj_w: (1024 x 4096), grid (128 x 32)
        wsplit_body(Wi, 1024, 4096, bb & 127, bb >> 7, t, WiH, WiL);
    }
}

// Combined prep for out_proj_w (2048 blk), bcd_w (192 blk), dup_w (128 blk)
__global__ __launch_bounds__(256) void wsplit3_k(const float* __restrict__ Wo,
                                                 const float* __restrict__ Wb,
                                                 const float* __restrict__ Wd,
                                                 u16* WoH, u16* WoL,
                                                 u16* bwTH, u16* bwTL,
                                                 u16* dwTH, u16* dwTL) {
    __shared__ float t[32][33];
    int b = blockIdx.x;
    if (b < 2048) {
        wsplit_body(Wo, 2048, 1024, b & 31, b >> 5, t, WoH, WoL);
    } else if (b < 2240) {
        int bb = b - 2048;
        wsplit_body(Wb, 2048, 96, bb % 3, bb / 3, t, bwTH, bwTL);
    } else {
        int bb = b - 2240;
        wsplit_body(Wd, 64, 2048, bb & 63, bb >> 6, t, dwTH, dwTL);
    }
}

// ---------------- Split-bf16 MFMA GEMM (R9 single-barrier pipeline, swizzled) ------
// C[M][N] = A[M][K] @ Bt[N][K]^T
// EPI: 2 C=softplus(acc+aux[col]); 4 dual in_proj (cols<DI -> U1/U2 split bf16,
//      cols>=DI -> C2=silu); 5 split-K partial write to C.
template <int BM, int BN, int EPI>
__global__ __launch_bounds__(256) void gemm_mfma3(
    const u16* __restrict__ Ah, const u16* __restrict__ Al,
    const u16* __restrict__ Bh, const u16* __restrict__ Bl,
    float* __restrict__ C, float* __restrict__ C2,
    u16* __restrict__ U1, u16* __restrict__ U2,
    const float* __restrict__ aux,
    int M, int N, int K) {
    constexpr int BK = 32;
    constexpr int MF = BM / 32, NF = BN / 32;
    constexpr int CH_A = BM / 16, CH_B = BN / 16;
    __shared__ u16 AhT[2][BM][BK], AlT[2][BM][BK], BhT[2][BN][BK], BlT[2][BN][BK];
    const int tid = threadIdx.x, lane = tid & 63, wid = tid >> 6;
    const int wr = wid >> 1, wc = wid & 1;
    const int lr = lane & 15;
    const int sw = (lane >> 1) & 3;
    const int lkq = ((lane >> 4) ^ sw) * 8;              // swizzled read col-block
    const int bm0 = blockIdx.y * BM, bn0 = blockIdx.x * BN;
    const int srow = lane >> 2;
    const int scol_ = ((lane & 3) ^ ((lane >> 3) & 3)) * 8;   // pre-swizzled source col

    int kbeg = 0, kend = K;
    if (EPI == 5) {
        int ks = K / gridDim.z;
        kbeg = blockIdx.z * ks;
        kend = kbeg + ks;
    }
    const int nt = (kend - kbeg) / BK;

    auto STAGE = [&](int buf, int k0) {
        int ci = 0;
        #pragma unroll
        for (int c = 0; c < CH_A; c++, ci++) if ((ci & 3) == wid) {
            size_t g = (size_t)(bm0 + c * 16 + srow) * K + (k0 + scol_);
            async16(Ah + g, (u16*)&AhT[buf][0][0] + c * 512 + lane * 8);
        }
        #pragma unroll
        for (int c = 0; c < CH_A; c++, ci++) if ((ci & 3) == wid) {
            size_t g = (size_t)(bm0 + c * 16 + srow) * K + (k0 + scol_);
            async16(Al + g, (u16*)&AlT[buf][0][0] + c * 512 + lane * 8);
        }
        #pragma unroll
        for (int c = 0; c < CH_B; c++, ci++) if ((ci & 3) == wid) {
            size_t g = (size_t)(bn0 + c * 16 + srow) * K + (k0 + scol_);
            async16(Bh + g, (u16*)&BhT[buf][0][0] + c * 512 + lane * 8);
        }
        #pragma unroll
        for (int c = 0; c < CH_B; c++, ci++) if ((ci & 3) == wid) {
            size_t g = (size_t)(bn0 + c * 16 + srow) * K + (k0 + scol_);
            async16(Bl + g, (u16*)&BlT[buf][0][0] + c * 512 + lane * 8);
        }
    };

    f32x4 acc[MF][NF];
    #pragma unroll
    for (int i = 0; i < MF; i++)
        #pragma unroll
        for (int j = 0; j < NF; j++) acc[i][j] = (f32x4){0.f, 0.f, 0.f, 0.f};

    // prologue: fill buffer 0
    STAGE(0, kbeg);
    asm volatile("s_waitcnt vmcnt(0)" ::: "memory");
    __builtin_amdgcn_s_barrier();

    for (int t = 0; t < nt; ++t) {
        const int cur = t & 1;
        // issue next tile's loads first — they fly under this tile's ds_read+MFMA
        if (t + 1 < nt) STAGE(cur ^ 1, kbeg + (t + 1) * BK);

        short8 ah[MF], al[MF], bh[NF], bl[NF];
        #pragma unroll
        for (int i = 0; i < MF; i++) {
            int r = wr * (MF * 16) + i * 16 + lr;
            ah[i] = *(const short8*)&AhT[cur][r][lkq];
            al[i] = *(const short8*)&AlT[cur][r][lkq];
        }
        #pragma unroll
        for (int j = 0; j < NF; j++) {
            int r = wc * (NF * 16) + j * 16 + lr;
            bh[j] = *(const short8*)&BhT[cur][r][lkq];
            bl[j] = *(const short8*)&BlT[cur][r][lkq];
        }
        asm volatile("s_waitcnt lgkmcnt(0)" ::: "memory");
        __builtin_amdgcn_sched_barrier(0);
        __builtin_amdgcn_s_setprio(1);
        #pragma unroll
        for (int i = 0; i < MF; i++)
            #pragma unroll
            for (int j = 0; j < NF; j++) {
                acc[i][j] = __builtin_amdgcn_mfma_f32_16x16x32_bf16(ah[i], bh[j], acc[i][j], 0, 0, 0);
                acc[i][j] = __builtin_amdgcn_mfma_f32_16x16x32_bf16(ah[i], bl[j], acc[i][j], 0, 0, 0);
                acc[i][j] = __builtin_amdgcn_mfma_f32_16x16x32_bf16(al[i], bh[j], acc[i][j], 0, 0, 0);
            }
        __builtin_amdgcn_s_setprio(0);
        if (t + 1 < nt) {
            // next buffer staged (own loads landed) + all waves done reading cur
            asm volatile("s_waitcnt vmcnt(0)" ::: "memory");
            __builtin_amdgcn_s_barrier();
        }
    }

    float* Cp = C;
    if (EPI == 5) Cp = C + (size_t)blockIdx.z * M * N;
    #pragma unroll
    for (int i = 0; i < MF; i++)
        #pragma unroll
        for (int j = 0; j < NF; j++) {
            int rowg = bm0 + wr * (MF * 16) + i * 16 + (lane >> 4) * 4;
            int colg = bn0 + wc * (NF * 16) + j * 16 + lr;
            #pragma unroll
            for (int q = 0; q < 4; q++) {
                float v = acc[i][j][q];
                if (EPI == 5) {
                    Cp[(size_t)(rowg + q) * N + colg] = v;
                } else if (EPI == 2) {
                    C[(size_t)(rowg + q) * N + colg] = softplusf_(v + aux[colg]);
                } else if (EPI == 4) {
                    if (colg < DI) {
                        size_t o = (size_t)(rowg + q) * DI + colg;
                        u16 hh = f2bf(v);
                        U1[o] = hh;
                        U2[o] = f2bf(v - bf2f(hh));
                    } else {
                        C2[(size_t)(rowg + q) * DI + (colg - DI)] = v * sigmoidf_(v);
                    }
                }
            }
        }
}

// ---------------- bcd split-K reduce ----------------
__global__ __launch_bounds__(256) void bcd_reduce_k(const float* __restrict__ partial,
                                                    float* __restrict__ bcd,
                                                    u16* __restrict__ bH,
                                                    u16* __restrict__ bL) {
    const int NT = Lseq * 96;
    int t = blockIdx.x * 256 + threadIdx.x;
    float s = 0.f;
    #pragma unroll
    for (int z = 0; z < SPLITK; z++) s += partial[(size_t)z * NT + t];
    bcd[t] = s;
    int col = t % 96, row = t / 96;
    if (col < DRr) {
        u16 h = f2bf(s);
        bH[(size_t)row * DRr + col] = h;
        bL[(size_t)row * DRr + col] = f2bf(s - bf2f(h));
    }
}

// ---------------- out split-K=4 reduce + residual ----------------
__global__ __launch_bounds__(256) void out_reduce_k(const float* __restrict__ part,
                                                    const float* __restrict__ x,
                                                    float* __restrict__ out) {
    int t = blockIdx.x * 256 + threadIdx.x;
    const size_t NT = (size_t)Lseq * Dmod;
    float4 xv = reinterpret_cast<const float4*>(x)[t];
    float4 o = xv;
    #pragma unroll
    for (int z = 0; z < OSPLIT; z++) {
        float4 p = reinterpret_cast<const float4*>(part + (size_t)z * NT)[t];
        o.x += p.x; o.y += p.y; o.z += p.z; o.w += p.w;
    }
    reinterpret_cast<float4*>(out)[t] = o;
}

// ---------------- Conv1d(K=4)+SiLU, rolling window, split-bf16 in/out ----------
__global__ __launch_bounds__(256) void conv_silu_k(const u16* __restrict__ xsH,
                                                   const u16* __restrict__ xsL,
                                                   const float* __restrict__ cw,
                                                   const float* __restrict__ cb,
                                                   u16* __restrict__ xcH,
                                                   u16* __restrict__ xcL) {
    int d = blockIdx.x * 256 + threadIdx.x;
    int l0 = blockIdx.y * 32;
    float4 w = reinterpret_cast<const float4*>(cw)[d];
    float b = cb[d];
    float p0 = 0.f, p1 = 0.f, p2 = 0.f;
    if (l0 > 0) {
        size_t o0 = (size_t)(l0 - 3) * DI + d;
        size_t o1 = (size_t)(l0 - 2) * DI + d;
        size_t o2 = (size_t)(l0 - 1) * DI + d;
        p0 = bf2f(xsH[o0]) + bf2f(xsL[o0]);
        p1 = bf2f(xsH[o1]) + bf2f(xsL[o1]);
        p2 = bf2f(xsH[o2]) + bf2f(xsL[o2]);
    }
    for (int l = l0; l < l0 + 32; ++l) {
        size_t o = (size_t)l * DI + d;
        float c = bf2f(xsH[o]) + bf2f(xsL[o]);
        float s = b;
        s = fmaf(p0, w.x, s);
        s = fmaf(p1, w.y, s);
        s = fmaf(p2, w.z, s);
        s = fmaf(c,  w.w, s);
        float v = s * sigmoidf_(s);
        u16 h = f2bf(v);
        xcH[o] = h;
        xcL[o] = f2bf(v - bf2f(h));
        p0 = p1; p1 = p2; p2 = c;
    }
}

// ---------------- Scan pass 1 ----------------
__global__ __launch_bounds__(256) void scan1_k(const float* __restrict__ delta,
                                               const u16* __restrict__ xcH,
                                               const u16* __restrict__ xcL,
                                               const float* __restrict__ bcd,
                                               const float* __restrict__ lmA,
                                               float* __restrict__ Pb,
                                               float* __restrict__ Sb) {
    __shared__ float Bs[LCHUNK][16];
    const int tid = threadIdx.x;
    const int d = (blockIdx.x * 256 + tid) >> 1;
    const int half = tid & 1;
    const int c = blockIdx.y;
    const int l0 = c * LCHUNK;
    {
        int row = tid >> 2, q = (tid & 3) * 4;
        float4 v = *reinterpret_cast<const float4*>(&bcd[(size_t)(l0 + row) * 96 + DRr + q]);
        *reinterpret_cast<float4*>(&Bs[row][q]) = v;
    }
    __syncthreads();
    float negA[8], h[8];
    #pragma unroll
    for (int j = 0; j < 8; j++) {
        negA[j] = -__expf(lmA[(size_t)d * Nst + half * 8 + j]);
        h[j] = 0.f;
    }
    float sdv = 0.f;
    for (int l = 0; l < LCHUNK; ++l) {
        size_t o = (size_t)(l0 + l) * DI + d;
        float dv = delta[o];
        float xcv = bf2f(xcH[o]) + bf2f(xcL[o]);
        sdv += dv;
        float dvx = dv * xcv;
        #pragma unroll
        for (int j = 0; j < 8; j++) {
            float a = __expf(dv * negA[j]);
            h[j] = fmaf(a, h[j], dvx * Bs[l][half * 8 + j]);
        }
    }
    size_t base = ((size_t)c * DI + d) * Nst + half * 8;
    #pragma unroll
    for (int j = 0; j < 8; j++) {
        Pb[base + j] = __expf(sdv * negA[j]);
        Sb[base + j] = h[j];
    }
}

// ---------------- Scan pass 2: combine in place (Pb -> Hinit) ----------------
__global__ __launch_bounds__(256) void scan2_k(float* __restrict__ PH,
                                               const float* __restrict__ Sb) {
    int t = blockIdx.x * 256 + threadIdx.x;
    float H = 0.f;
    for (int c = 0; c < NCHUNK; c++) {
        size_t idx = (size_t)c * (DI * Nst) + t;
        float P = PH[idx], S = Sb[idx];
        PH[idx] = H;
        H = S + P * H;
    }
}

// ---------------- Scan pass 3 ----------------
__global__ __launch_bounds__(256) void scan3_k(const float* __restrict__ delta,
                                               const u16* __restrict__ xcH,
                                               const u16* __restrict__ xcL,
                                               const float* __restrict__ bcd,
                                               const float* __restrict__ lmA,
                                               const float* __restrict__ Dp,
                                               const float* __restrict__ gate,
                                               const float* __restrict__ Hinit,
                                               u16* __restrict__ yH,
                                               u16* __restrict__ yL) {
    __shared__ float BCs[LCHUNK][32];
    const int tid = threadIdx.x;
    const int d = (blockIdx.x * 256 + tid) >> 1;
    const int half = tid & 1;
    const int c = blockIdx.y;
    const int l0 = c * LCHUNK;
    #pragma unroll
    for (int i = 0; i < 2; i++) {
        int idx = tid + 256 * i;
        int row = idx >> 3, q = (idx & 7) * 4;
        float4 v = *reinterpret_cast<const float4*>(&bcd[(size_t)(l0 + row) * 96 + DRr + q]);
        *reinterpret_cast<float4*>(&BCs[row][q]) = v;
    }
    __syncthreads();
    float negA[8], h[8];
    size_t hbase = ((size_t)c * DI + d) * Nst + half * 8;
    #pragma unroll
    for (int j = 0; j < 8; j++) {
        negA[j] = -__expf(lmA[(size_t)d * Nst + half * 8 + j]);
        h[j] = Hinit[hbase + j];
    }
    float Dpv = Dp[d];
    for (int l = 0; l < LCHUNK; ++l) {
        size_t o = (size_t)(l0 + l) * DI + d;
        float dv = delta[o];
        float xcv = bf2f(xcH[o]) + bf2f(xcL[o]);
        float dvx = dv * xcv;
        float yp = 0.f;
        #pragma unroll
        for (int j = 0; j < 8; j++) {
            float a = __expf(dv * negA[j]);
            h[j] = fmaf(a, h[j], dvx * BCs[l][half * 8 + j]);
            yp = fmaf(BCs[l][16 + half * 8 + j], h[j], yp);
        }
        yp += __shfl_xor(yp, 1);
        if (half == 0) {
            float yv = (yp + xcv * Dpv) * gate[o];
            u16 hq = f2bf(yv);
            yH[o] = hq;
            yL[o] = f2bf(yv - bf2f(hq));
        }
    }
}

extern "C" void kernel_launch(void* const* d_in, const int* in_sizes, int n_in,
                              void* d_out, int out_size, void* d_ws, size_t ws_size,
                              hipStream_t stream) {
    const float* x          = (const float*)d_in[0];
    const float* rms_w      = (const float*)d_in[1];
    const float* in_proj_w  = (const float*)d_in[2];
    const float* conv_w     = (const float*)d_in[3];
    const float* conv_b     = (const float*)d_in[4];
    const float* bcd_w      = (const float*)d_in[5];
    const float* dup_w      = (const float*)d_in[6];
    const float* dup_b      = (const float*)d_in[7];
    const float* lmA        = (const float*)d_in[8];
    const float* Dp         = (const float*)d_in[9];
    const float* out_proj_w = (const float*)d_in[10];
    float* out = (float*)d_out;
    char*  W   = (char*)d_ws;

    const size_t MB = 1ull << 20;
    // Region A: 0-16MB  : WiH/WiL -> delta
    u16*   WiH  = (u16*)(W + 0);
    u16*   WiL  = (u16*)(W + 8 * MB);
    float* delta= (float*)(W + 0);
    // Region B: 16-32MB : xsH/xsL -> {part(12)+small wts} -> Sb(4) -> yH/yL(16)
    u16*   xsH  = (u16*)(W + 16 * MB);
    u16*   xsL  = (u16*)(W + 24 * MB);
    float* part = (float*)(W + 16 * MB);
    u16*   bwTH = (u16*)(W + 28 * MB);
    u16*   bwTL = (u16*)(W + 28 * MB + 384 * 1024);
    u16*   dwTH = (u16*)(W + 28 * MB + 768 * 1024);
    u16*   dwTL = (u16*)(W + 28 * MB + 1024 * 1024);
    u16*   bcdH = (u16*)(W + 28 * MB + 1280 * 1024);
    u16*   bcdL = (u16*)(W + 28 * MB + 1536 * 1024);
    float* Sb   = (float*)(W + 16 * MB);
    u16*   yH   = (u16*)(W + 16 * MB);
    u16*   yL   = (u16*)(W + 24 * MB);
    // Region C+D: 32-64MB : gate(16) + xcH/xcL(16) -> opart (32MB, post-scan3)
    float* gate = (float*)(W + 32 * MB);
    u16*   xcH  = (u16*)(W + 48 * MB);
    u16*   xcL  = (u16*)(W + 56 * MB);
    float* opart= (float*)(W + 32 * MB);
    // Region E: 64-72MB : xnH/xnL -> WoH/WoL
    u16*   xnH  = (u16*)(W + 64 * MB);
    u16*   xnL  = (u16*)(W + 68 * MB);
    u16*   WoH  = (u16*)(W + 64 * MB);
    u16*   WoL  = (u16*)(W + 68 * MB);
    // Region F: 72-77MB : bcd f32 + Pb (becomes Hinit)
    float* bcd  = (float*)(W + 72 * MB);
    float* Pb   = (float*)(W + 73 * MB);

    // 1. fused: RMSNorm + in_proj_w transpose/split
    prep1_k<<<2048 + 4096, 256, 0, stream>>>(x, rms_w, xnH, xnL, in_proj_w, WiH, WiL);
    // 2. in_proj: xs (split bf16) / gate  (128x128, R9 pipeline)
    gemm_mfma3<128, 128, 4><<<dim3(4096 / 128, Lseq / 128), 256, 0, stream>>>(
        xnH, xnL, WiH, WiL, nullptr, gate, xsH, xsL, nullptr, Lseq, 2 * DI, Dmod);
    // 3. conv + silu -> xc split bf16 (rolling window, split input)
    conv_silu_k<<<dim3(DI / 256, Lseq / 32), 256, 0, stream>>>(xsH, xsL, conv_w, conv_b, xcH, xcL);
    // 4. combined prep: out_proj_w / bcd_w / dup_w (xn dead)
    wsplit3_k<<<2368, 256, 0, stream>>>(out_proj_w, bcd_w, dup_w,
                                        WoH, WoL, bwTH, bwTL, dwTH, dwTL);
    // 5. bcd = xc @ bcd_w (split-K MFMA + reduce)
    gemm_mfma3<128, 96, 5><<<dim3(1, Lseq / 128, SPLITK), 256, 0, stream>>>(
        xcH, xcL, bwTH, bwTL, part, nullptr, nullptr, nullptr, nullptr, Lseq, 96, DI);
    bcd_reduce_k<<<Lseq * 96 / 256, 256, 0, stream>>>(part, bcd, bcdH, bcdL);
    // 6. delta = softplus(bcd[:, :64] @ dup_w + dup_b)
    gemm_mfma3<64, 128, 2><<<dim3(DI / 128, Lseq / 64), 256, 0, stream>>>(
        bcdH, bcdL, dwTH, dwTL, delta, nullptr, nullptr, nullptr, dup_b, Lseq, DI, DRr);
    // 7-9. chunked selective scan
    scan1_k<<<dim3(16, NCHUNK), 256, 0, stream>>>(delta, xcH, xcL, bcd, lmA, Pb, Sb);
    scan2_k<<<dim3(DI * Nst / 256), 256, 0, stream>>>(Pb, Sb);
    scan3_k<<<dim3(16, NCHUNK), 256, 0, stream>>>(delta, xcH, xcL, bcd, lmA, Dp, gate, Pb, yH, yL);
    // 10. out_proj: 128x128 + split-K=4, reduce + residual
    gemm_mfma3<128, 128, 5><<<dim3(Dmod / 128, Lseq / 128, OSPLIT), 256, 0, stream>>>(
        yH, yL, WoH, WoL, opart, nullptr, nullptr, nullptr, nullptr, Lseq, Dmod, DI);
    out_reduce_k<<<Lseq * Dmod / 1024, 256, 0, stream>>>(opart, x, out);
}